// Round 1
// baseline (6569.251 us; speedup 1.0000x reference)
//
#include <hip/hip_runtime.h>

#define NN 512

__device__ __forceinline__ float silu_f(float x) { return x / (1.0f + __expf(-x)); }
__device__ __forceinline__ float sigm_f(float x) { return 1.0f / (1.0f + __expf(-x)); }

// ---------------- init: mean-center x, broadcast v0, h0 = 1 ----------------
__global__ void k_init(const float* __restrict__ x, float* __restrict__ vec_in,
                       float* __restrict__ v, float* __restrict__ h)
{
    const int b = (int)blockIdx.x;
    const int tid = (int)threadIdx.x;
    __shared__ float red[3 * 256];
    float s0 = 0.f, s1 = 0.f, s2 = 0.f;
    for (int n = tid; n < NN; n += 256) {
        s0 += x[(b * NN + n) * 3 + 0];
        s1 += x[(b * NN + n) * 3 + 1];
        s2 += x[(b * NN + n) * 3 + 2];
    }
    red[tid] = s0; red[256 + tid] = s1; red[512 + tid] = s2;
    __syncthreads();
    for (int off = 128; off; off >>= 1) {
        if (tid < off) {
            red[tid] += red[tid + off];
            red[256 + tid] += red[256 + tid + off];
            red[512 + tid] += red[512 + tid + off];
        }
        __syncthreads();
    }
    const float m0 = red[0] * (1.f / 512.f);
    const float m1 = red[256] * (1.f / 512.f);
    const float m2 = red[512] * (1.f / 512.f);
    for (int n = tid; n < NN; n += 256) {
        const size_t base = (size_t)b * NN + n;
        float d0 = x[base * 3 + 0] - m0;
        float d1 = x[base * 3 + 1] - m1;
        float d2 = x[base * 3 + 2] - m2;
        vec_in[base * 3 + 0] = d0;
        vec_in[base * 3 + 1] = d1;
        vec_in[base * 3 + 2] = d2;
        #pragma unroll
        for (int c = 0; c < 16; ++c) {
            v[base * 48 + c * 3 + 0] = d0;
            v[base * 48 + c * 3 + 1] = d1;
            v[base * 48 + c * 3 + 2] = d2;
        }
    }
    for (int q = tid; q < NN * 64; q += 256) h[(size_t)b * NN * 64 + q] = 1.0f;
}

// ---------------- per-node precompute: h @ we1 send/recv parts ----------------
__global__ __launch_bounds__(128) void k_node_pre(
    const float* __restrict__ h, const float* __restrict__ we1,
    float* __restrict__ pST, float* __restrict__ pR)
{
    const int nx = (int)blockIdx.x;       // b*512 + n
    const int b = nx >> 9, n = nx & 511;
    const int tid = (int)threadIdx.x;     // u
    __shared__ float hl[64];
    if (tid < 64) hl[tid] = h[(size_t)nx * 64 + tid];
    __syncthreads();
    float a = 0.f, c = 0.f;
    for (int f = 0; f < 64; ++f) {
        const float hv = hl[f];
        a = fmaf(hv, we1[(16 + f) * 128 + tid], a);   // h[SEND] rows
        c = fmaf(hv, we1[(80 + f) * 128 + tid], c);   // h[RECV] rows
    }
    pST[((size_t)b * 128 + tid) * NN + n] = a;  // transposed [b][u][node]
    pR[(size_t)nx * 128 + tid] = c;             // [b][node][u]
}

// ---------------- edge kernel: one WG per (batch, receiver) ----------------
__global__ __launch_bounds__(256, 1) void k_edge(
    const float* __restrict__ v, const float* __restrict__ pST,
    const float* __restrict__ pR, const float* __restrict__ we1,
    const float* __restrict__ we2, const float* __restrict__ wx1,
    const float* __restrict__ wx2, const float* __restrict__ winf,
    const float* __restrict__ wtp, float* __restrict__ m_i,
    float* __restrict__ v_agg)
{
    extern __shared__ float lds[];
    float* A   = lds;            // 16384 floats: [feat 128][sender 128]
    float* Wl  = lds + 16384;    // 8192 floats: stage weights / e,red overlay
    float* SHm = lds + 24576;    // 6144 floats: sh1 [w*3+k][sender]
    float* MS  = lds + 30720;    // 2048 floats: len2 [c][sender]

    const int tid = (int)threadIdx.x;
    const int bx = (int)blockIdx.x;
    const int b = bx >> 9, r = bx & 511;
    const int ty = tid >> 4, tx = tid & 15;

    float G[8][3] = {};           // G[u=ty*8+j][k] for w = tx
    float macc = 0.f;             // m_i partial for u = u_m, sender-half sh_m
    const int u_m = tid >> 1, sh_m = tid & 1;

    const float* vb  = v   + (size_t)b * NN * 48;
    const float* pSb = pST + (size_t)b * 128 * NN;
    const float* pRn = pR  + ((size_t)b * NN + r) * 128;

    for (int T = 0; T < 4; ++T) {
        const int sbase = T * 128;

        // ---- geometry: vec, len2, sh1 ----
        {
            const int s = tid >> 1, hf = tid & 1;
            int i = sbase + s;
            int sid = i + (i >= r);
            if (i >= 511) sid = r;   // pad slot: self-edge, sh1 = 0, gated out
            const float* vs = vb + sid * 48 + hf * 24;
            const float* vr = vb + r   * 48 + hf * 24;
            float sv[24], rv[24];
            #pragma unroll
            for (int q = 0; q < 6; ++q) {
                *(float4*)&sv[q * 4] = *(const float4*)&vs[q * 4];
                *(float4*)&rv[q * 4] = *(const float4*)&vr[q * 4];
            }
            #pragma unroll
            for (int cl = 0; cl < 8; ++cl) {
                float d0 = rv[cl * 3 + 0] - sv[cl * 3 + 0];
                float d1 = rv[cl * 3 + 1] - sv[cl * 3 + 1];
                float d2 = rv[cl * 3 + 2] - sv[cl * 3 + 2];
                float l2 = d0 * d0 + d1 * d1 + d2 * d2;
                float len = sqrtf(fmaxf(l2, 1e-20f));
                float fs = 1.7320508f / (1.0f + len);
                int c = hf * 8 + cl;
                SHm[(c * 3 + 0) * 128 + s] = d0 * fs;
                SHm[(c * 3 + 1) * 128 + s] = d1 * fs;
                SHm[(c * 3 + 2) * 128 + s] = d2 * fs;
                MS[c * 128 + s] = l2;
            }
            // stage we1 len2-rows (16x128 = first 2048 floats) into Wl
            #pragma unroll
            for (int p = 0; p < 2; ++p) {
                int q = p * 256 + tid;
                *(float4*)&Wl[q * 4] = *(const float4*)&we1[q * 4];
            }
        }
        __syncthreads();

        // ---- stage 1: a1 = silu((len2@we1_len + preS[s] + preR[r]) / 12) ----
        {
            const int s = tid & 127, uh = tid >> 7;
            int i = sbase + s;
            int sid = i + (i >= r);
            if (i >= 511) sid = r;
            float l2r[16];
            #pragma unroll
            for (int c = 0; c < 16; ++c) l2r[c] = MS[c * 128 + s];
            for (int uu = 0; uu < 64; ++uu) {
                int u = uh * 64 + uu;
                float acc = pSb[(size_t)u * NN + sid] + pRn[u];
                #pragma unroll
                for (int c = 0; c < 16; ++c) acc = fmaf(l2r[c], Wl[c * 128 + u], acc);
                A[u * 128 + s] = silu_f(acc * (1.0f / 12.0f));
            }
        }
        __syncthreads();

        // ---- register-blocked f32 GEMM: A(new) = silu(A^T @ W / sqrt(128)) ----
        float cf[2][8][4];
        auto gemm_silu = [&](const float* __restrict__ gw) {
            #pragma unroll
            for (int half = 0; half < 2; ++half) {
                __syncthreads();           // prior Wl users done
                #pragma unroll
                for (int p = 0; p < 8; ++p) {
                    int q = p * 256 + tid;           // 2048 float4s
                    int k = q >> 4, c4 = q & 15;
                    *(float4*)&Wl[k * 64 + c4 * 4] =
                        *(const float4*)&gw[k * 128 + half * 64 + c4 * 4];
                }
                __syncthreads();
                #pragma unroll
                for (int j = 0; j < 8; ++j)
                    #pragma unroll
                    for (int i2 = 0; i2 < 4; ++i2) cf[half][j][i2] = 0.f;
                #pragma unroll 8
                for (int k = 0; k < 128; ++k) {
                    float av[8], wv4[4];
                    *(float4*)&av[0] = *(const float4*)&A[k * 128 + ty * 8];
                    *(float4*)&av[4] = *(const float4*)&A[k * 128 + ty * 8 + 4];
                    *(float4*)&wv4[0] = *(const float4*)&Wl[k * 64 + tx * 4];
                    #pragma unroll
                    for (int j = 0; j < 8; ++j)
                        #pragma unroll
                        for (int i2 = 0; i2 < 4; ++i2)
                            cf[half][j][i2] = fmaf(av[j], wv4[i2], cf[half][j][i2]);
                }
            }
            __syncthreads();   // all reads of A done -> safe to overwrite
            #pragma unroll
            for (int half = 0; half < 2; ++half) {
                #pragma unroll
                for (int i2 = 0; i2 < 4; ++i2) {
                    int u = half * 64 + tx * 4 + i2;
                    float4 lo, hi;
                    lo.x = silu_f(cf[half][0][i2] * 0.088388348f);
                    lo.y = silu_f(cf[half][1][i2] * 0.088388348f);
                    lo.z = silu_f(cf[half][2][i2] * 0.088388348f);
                    lo.w = silu_f(cf[half][3][i2] * 0.088388348f);
                    hi.x = silu_f(cf[half][4][i2] * 0.088388348f);
                    hi.y = silu_f(cf[half][5][i2] * 0.088388348f);
                    hi.z = silu_f(cf[half][6][i2] * 0.088388348f);
                    hi.w = silu_f(cf[half][7][i2] * 0.088388348f);
                    *(float4*)&A[u * 128 + ty * 8]     = lo;
                    *(float4*)&A[u * 128 + ty * 8 + 4] = hi;
                }
            }
            __syncthreads();
        };

        gemm_silu(we2);   // A = m_ij

        // ---- gate e = sigmoid(m @ winf / sqrt(128)); m_acc += m * e ----
        {
            const int s = tid & 127, part = tid >> 7;
            float p = 0.f;
            for (int j = 0; j < 64; ++j) {
                int u = part * 64 + j;
                p = fmaf(A[u * 128 + s], winf[u], p);
            }
            Wl[128 + part * 128 + s] = p;
            __syncthreads();
            if (tid < 128) {
                int i = sbase + tid;
                float tot = Wl[128 + tid] + Wl[256 + tid];
                Wl[tid] = (i < 511) ? sigm_f(tot * 0.088388348f) : 0.f;  // pad masked
            }
            __syncthreads();
            for (int j = 0; j < 64; ++j) {
                int s2 = sh_m * 64 + ((j + u_m) & 63);   // diagonal: bank-conflict-free
                macc = fmaf(A[u_m * 128 + s2], Wl[s2], macc);
            }
        }

        gemm_silu(wx1);   // A = b1   (leading sync protects Wl overlay)
        gemm_silu(wx2);   // A = phi_x

        // ---- G[u][w][k] += phi[u][s] * sh1[w][k][s]  (rank-1 accumulation) ----
        #pragma unroll 2
        for (int cb = 0; cb < 32; ++cb) {
            int s4 = ((tid + cb) & 31) * 4;   // rotated: conflict-free
            float sh0[4], sh1v[4], sh2[4];
            *(float4*)&sh0[0]  = *(const float4*)&SHm[(tx * 3 + 0) * 128 + s4];
            *(float4*)&sh1v[0] = *(const float4*)&SHm[(tx * 3 + 1) * 128 + s4];
            *(float4*)&sh2[0]  = *(const float4*)&SHm[(tx * 3 + 2) * 128 + s4];
            #pragma unroll
            for (int j = 0; j < 8; ++j) {
                float pa[4];
                *(float4*)&pa[0] = *(const float4*)&A[(ty * 8 + j) * 128 + s4];
                #pragma unroll
                for (int i2 = 0; i2 < 4; ++i2) {
                    G[j][0] = fmaf(pa[i2], sh0[i2],  G[j][0]);
                    G[j][1] = fmaf(pa[i2], sh1v[i2], G[j][1]);
                    G[j][2] = fmaf(pa[i2], sh2[i2],  G[j][2]);
                }
            }
        }
        __syncthreads();   // before next tile overwrites SHm/MS/A
    }

    // ---- finalize m_i ----
    Wl[sh_m * 128 + u_m] = macc;
    __syncthreads();
    if (tid < 128) m_i[(size_t)bx * 128 + tid] = Wl[tid] + Wl[128 + tid];

    // ---- v_agg[v][k] = sum_{u,w} wtp[u][w][v] * G[u][w][k] (scaled) ----
    #pragma unroll
    for (int j = 0; j < 8; ++j) {
        A[(ty * 8 + j) * 48 + tx * 3 + 0] = G[j][0];
        A[(ty * 8 + j) * 48 + tx * 3 + 1] = G[j][1];
        A[(ty * 8 + j) * 48 + tx * 3 + 2] = G[j][2];
    }
    __syncthreads();
    if (tid < 240) {
        int vk = tid % 48, ug = tid / 48;
        int vv = vk / 3, kk = vk - vv * 3;
        int u0 = (ug * 128) / 5, u1 = ((ug + 1) * 128) / 5;
        float acc = 0.f;
        for (int u = u0; u < u1; ++u) {
            #pragma unroll
            for (int w = 0; w < 16; ++w)
                acc = fmaf(wtp[(u * 16 + w) * 16 + vv], A[u * 48 + w * 3 + kk], acc);
        }
        Wl[ug * 48 + vk] = acc;
    }
    __syncthreads();
    if (tid < 48) {
        float tot = Wl[tid] + Wl[48 + tid] + Wl[96 + tid] + Wl[144 + tid] + Wl[192 + tid];
        v_agg[(size_t)bx * 48 + tid] = tot * 4.3242827e-05f;  // 1/(sqrt(2048)*511)
    }
}

// ---------------- per-node update: ph MLP, residuals ----------------
__global__ __launch_bounds__(128) void k_node_upd(
    const float* __restrict__ m_i, const float* __restrict__ v_agg,
    const float* __restrict__ wh1, const float* __restrict__ wh2,
    const float* __restrict__ wh_out, float* __restrict__ h, float* __restrict__ v)
{
    const int nx = (int)blockIdx.x;
    const int tid = (int)threadIdx.x;
    __shared__ float cat[192], t1[128], t2[128];
    if (tid < 128) cat[tid] = m_i[(size_t)nx * 128 + tid];
    if (tid < 64) cat[128 + tid] = h[(size_t)nx * 64 + tid];
    __syncthreads();
    {
        float acc = 0.f;
        for (int j = 0; j < 192; ++j) acc = fmaf(cat[j], wh1[j * 128 + tid], acc);
        t1[tid] = silu_f(acc * 0.072168784f);   // 1/sqrt(192)
    }
    __syncthreads();
    {
        float acc = 0.f;
        for (int j = 0; j < 128; ++j) acc = fmaf(t1[j], wh2[j * 128 + tid], acc);
        t2[tid] = silu_f(acc * 0.088388348f);   // 1/sqrt(128)
    }
    __syncthreads();
    if (tid < 64) {
        float acc = 0.f;
        for (int j = 0; j < 128; ++j) acc = fmaf(t2[j], wh_out[j * 64 + tid], acc);
        h[(size_t)nx * 64 + tid] = acc * 0.088388348f + cat[128 + tid];
    }
    if (tid < 48) v[(size_t)nx * 48 + tid] += v_agg[(size_t)nx * 48 + tid];
}

// ---------------- readout ----------------
__global__ __launch_bounds__(64) void k_readout(
    const float* __restrict__ v, const float* __restrict__ h,
    const float* __restrict__ vec_in, const float* __restrict__ wsM,
    const float* __restrict__ wvM, const float* __restrict__ w_out,
    const float* __restrict__ b_out, float* __restrict__ out)
{
    const int nx = (int)blockIdx.x;
    const int j = (int)threadIdx.x;   // 64 threads = 1 wave
    __shared__ float sm[64];
    const float* hn = h + (size_t)nx * 64;
    float acc = 0.f;
    for (int f = 0; f < 64; ++f) acc = fmaf(hn[f], wsM[f * 64 + j], acc);
    acc *= 0.125f;   // 1/sqrt(64)
    float mx = acc;
    #pragma unroll
    for (int off = 32; off; off >>= 1) mx = fmaxf(mx, __shfl_xor(mx, off));
    float e = __expf(acc - mx);
    float ssum = e;
    #pragma unroll
    for (int off = 32; off; off >>= 1) ssum += __shfl_xor(ssum, off);
    sm[j] = e / ssum;
    __syncthreads();
    float o = b_out[j];
    for (int i = 0; i < 64; ++i) o = fmaf(sm[i], w_out[i * 64 + j], o);
    out[2 * 512 * 24 + (size_t)nx * 64 + j] = o;
    if (j < 24) {
        int w = j / 3, k = j - w * 3;
        float a2 = 0.f;
        #pragma unroll
        for (int c = 0; c < 16; ++c)
            a2 = fmaf(v[(size_t)nx * 48 + c * 3 + k], wvM[c * 8 + w], a2);
        out[(size_t)nx * 24 + j] = a2 * 0.25f - vec_in[(size_t)nx * 3 + k];
    }
}

// ---------------- launch ----------------
extern "C" void kernel_launch(void* const* d_in, const int* in_sizes, int n_in,
                              void* d_out, int out_size, void* d_ws, size_t ws_size,
                              hipStream_t stream)
{
    (void)in_sizes; (void)n_in; (void)out_size; (void)ws_size;
    const float* x      = (const float*)d_in[0];
    const float* we1    = (const float*)d_in[1];
    const float* we2    = (const float*)d_in[2];
    const float* wx1    = (const float*)d_in[3];
    const float* wx2    = (const float*)d_in[4];
    const float* winf   = (const float*)d_in[5];
    const float* wtp    = (const float*)d_in[6];
    const float* wh1    = (const float*)d_in[7];
    const float* wh2    = (const float*)d_in[8];
    const float* wh_out = (const float*)d_in[9];
    const float* wsM    = (const float*)d_in[10];
    const float* wvM    = (const float*)d_in[11];
    const float* w_out  = (const float*)d_in[12];
    const float* b_out  = (const float*)d_in[13];
    float* out = (float*)d_out;
    float* W = (float*)d_ws;

    float* VEC_IN = W;             // 3072 floats
    float* V      = W + 4096;      // 49152
    float* H      = W + 53248;     // 65536
    float* PST    = W + 118784;    // 131072  [b][u][node]
    float* PR     = W + 249856;    // 131072  [b][node][u]
    float* MI     = W + 380928;    // 131072
    float* VAGG   = W + 512000;    // 49152

    // allow 128KB dynamic LDS for k_edge (idempotent; capture-safe host config)
    hipFuncSetAttribute((const void*)k_edge,
                        hipFuncAttributeMaxDynamicSharedMemorySize, 131072);

    k_init<<<2, 256, 0, stream>>>(x, VEC_IN, V, H);
    for (int l = 0; l < 3; ++l) {
        k_node_pre<<<1024, 128, 0, stream>>>(H, we1 + l * 18432, PST, PR);
        k_edge<<<1024, 256, 131072, stream>>>(V, PST, PR, we1 + l * 18432,
            we2 + l * 16384, wx1 + l * 16384, wx2 + l * 16384, winf + l * 128,
            wtp + l * 32768, MI, VAGG);
        k_node_upd<<<1024, 128, 0, stream>>>(MI, VAGG, wh1 + l * 24576,
            wh2 + l * 16384, wh_out + l * 8192, H, V);
    }
    k_readout<<<1024, 64, 0, stream>>>(V, H, VEC_IN, wsM, wvM, w_out, b_out, out);
}

// Round 2
// 4858.409 us; speedup vs baseline: 1.3521x; 1.3521x over previous
//
#include <hip/hip_runtime.h>

#define NN 512

__device__ __forceinline__ float silu_f(float x) { return x / (1.0f + __expf(-x)); }
__device__ __forceinline__ float sigm_f(float x) { return 1.0f / (1.0f + __expf(-x)); }

// ---------------- init: mean-center x, broadcast v0, h0 = 1 ----------------
__global__ void k_init(const float* __restrict__ x, float* __restrict__ vec_in,
                       float* __restrict__ v, float* __restrict__ h)
{
    const int b = (int)blockIdx.x;
    const int tid = (int)threadIdx.x;
    __shared__ float red[3 * 256];
    float s0 = 0.f, s1 = 0.f, s2 = 0.f;
    for (int n = tid; n < NN; n += 256) {
        s0 += x[(b * NN + n) * 3 + 0];
        s1 += x[(b * NN + n) * 3 + 1];
        s2 += x[(b * NN + n) * 3 + 2];
    }
    red[tid] = s0; red[256 + tid] = s1; red[512 + tid] = s2;
    __syncthreads();
    for (int off = 128; off; off >>= 1) {
        if (tid < off) {
            red[tid] += red[tid + off];
            red[256 + tid] += red[256 + tid + off];
            red[512 + tid] += red[512 + tid + off];
        }
        __syncthreads();
    }
    const float m0 = red[0] * (1.f / 512.f);
    const float m1 = red[256] * (1.f / 512.f);
    const float m2 = red[512] * (1.f / 512.f);
    for (int n = tid; n < NN; n += 256) {
        const size_t base = (size_t)b * NN + n;
        float d0 = x[base * 3 + 0] - m0;
        float d1 = x[base * 3 + 1] - m1;
        float d2 = x[base * 3 + 2] - m2;
        vec_in[base * 3 + 0] = d0;
        vec_in[base * 3 + 1] = d1;
        vec_in[base * 3 + 2] = d2;
        #pragma unroll
        for (int c = 0; c < 16; ++c) {
            v[base * 48 + c * 3 + 0] = d0;
            v[base * 48 + c * 3 + 1] = d1;
            v[base * 48 + c * 3 + 2] = d2;
        }
    }
    for (int q = tid; q < NN * 64; q += 256) h[(size_t)b * NN * 64 + q] = 1.0f;
}

// ---------------- per-node precompute: h @ we1 send/recv parts ----------------
__global__ __launch_bounds__(128) void k_node_pre(
    const float* __restrict__ h, const float* __restrict__ we1,
    float* __restrict__ pST, float* __restrict__ pR)
{
    const int nx = (int)blockIdx.x;       // b*512 + n
    const int b = nx >> 9, n = nx & 511;
    const int tid = (int)threadIdx.x;     // u
    __shared__ float hl[64];
    if (tid < 64) hl[tid] = h[(size_t)nx * 64 + tid];
    __syncthreads();
    float a = 0.f, c = 0.f;
    for (int f = 0; f < 64; ++f) {
        const float hv = hl[f];
        a = fmaf(hv, we1[(16 + f) * 128 + tid], a);   // h[SEND] rows
        c = fmaf(hv, we1[(80 + f) * 128 + tid], c);   // h[RECV] rows
    }
    pST[((size_t)b * 128 + tid) * NN + n] = a;  // transposed [b][u][node]
    pR[(size_t)nx * 128 + tid] = c;             // [b][node][u]
}

// ---------------- edge kernel: one WG per (batch, receiver) ----------------
// LDS 80KB -> 2 WG/CU (2 waves/SIMD). Sender tile = 64, 8 tiles.
__global__ __launch_bounds__(256, 2) void k_edge(
    const float* __restrict__ v, const float* __restrict__ pST,
    const float* __restrict__ pR, const float* __restrict__ we1,
    const float* __restrict__ we2, const float* __restrict__ wx1,
    const float* __restrict__ wx2, const float* __restrict__ winf,
    const float* __restrict__ wtp, float* __restrict__ m_i,
    float* __restrict__ v_agg)
{
    extern __shared__ float lds[];
    float* A   = lds;            // 8192 floats: [row 128][sender 64]
    float* Wl  = lds + 8192;     // 8192 floats: weight stage / we1len+pR / scratch
    float* SHm = lds + 16384;    // 3072 floats: sh1 [w*3+k][sender 64]
    float* MS  = lds + 19456;    // 1024 floats: len2 [c][sender 64]

    const int tid = (int)threadIdx.x;
    const int bx = (int)blockIdx.x;
    const int b = bx >> 9, r = bx & 511;
    const int ty = tid >> 4, tx = tid & 15;   // ty: u-group (broadcast reads), tx: sender quad
    const int u_m = tid >> 1, sh_m = tid & 1;

    float G[8][3] = {};           // G[u=ty*8+j][k] for w = tx
    float macc = 0.f;             // m_i partial for u = u_m, sender-half sh_m

    const float* vb  = v   + (size_t)b * NN * 48;
    const float* pSb = pST + (size_t)b * 128 * NN;
    const float* pRn = pR  + ((size_t)b * NN + r) * 128;

    float cf[2][4][4];

    // GEMM: A(out[u][s]) = silu(A(in[k][s])^T-contracted @ W / sqrt(128))
    auto gemm_silu = [&](const float* __restrict__ gw) {
        #pragma unroll
        for (int half = 0; half < 2; ++half) {
            __syncthreads();           // prior Wl/A users done
            #pragma unroll
            for (int p = 0; p < 8; ++p) {
                int q = p * 256 + tid;            // 2048 float4s
                int k = q >> 4, c4 = q & 15;
                *(float4*)&Wl[k * 64 + c4 * 4] =
                    *(const float4*)&gw[k * 128 + half * 64 + c4 * 4];
            }
            __syncthreads();
            #pragma unroll
            for (int j = 0; j < 4; ++j)
                #pragma unroll
                for (int i2 = 0; i2 < 4; ++i2) cf[half][j][i2] = 0.f;
            #pragma unroll 8
            for (int k = 0; k < 128; ++k) {
                float wv[4], av[4];
                *(float4*)&wv[0] = *(const float4*)&Wl[k * 64 + ty * 4];  // broadcast x16
                *(float4*)&av[0] = *(const float4*)&A[k * 64 + tx * 4];   // 2-way, free
                #pragma unroll
                for (int j = 0; j < 4; ++j)
                    #pragma unroll
                    for (int i2 = 0; i2 < 4; ++i2)
                        cf[half][j][i2] = fmaf(wv[j], av[i2], cf[half][j][i2]);
            }
        }
        __syncthreads();   // all reads of A done -> safe to overwrite
        #pragma unroll
        for (int half = 0; half < 2; ++half) {
            #pragma unroll
            for (int j = 0; j < 4; ++j) {
                int u = half * 64 + ty * 4 + j;
                float4 o;
                o.x = silu_f(cf[half][j][0] * 0.088388348f);
                o.y = silu_f(cf[half][j][1] * 0.088388348f);
                o.z = silu_f(cf[half][j][2] * 0.088388348f);
                o.w = silu_f(cf[half][j][3] * 0.088388348f);
                *(float4*)&A[u * 64 + tx * 4] = o;   // bank = tx*4: conflict-free
            }
        }
        __syncthreads();
    };

    for (int T = 0; T < 8; ++T) {
        const int sbase = T * 64;

        // ---- geometry: vec, len2, sh1 (4 channels per thread) ----
        {
            const int s = tid >> 2, qp = tid & 3;
            int i = sbase + s;
            int sid = i + (i >= r);
            if (i >= 511) sid = r;   // pad slot: self-edge, sh1 = 0, gated out
            const float* vs = vb + sid * 48 + qp * 12;
            const float* vr = vb + r   * 48 + qp * 12;
            float sv[12], rv[12];
            #pragma unroll
            for (int q = 0; q < 3; ++q) {
                *(float4*)&sv[q * 4] = *(const float4*)&vs[q * 4];
                *(float4*)&rv[q * 4] = *(const float4*)&vr[q * 4];
            }
            #pragma unroll
            for (int cl = 0; cl < 4; ++cl) {
                float d0 = rv[cl * 3 + 0] - sv[cl * 3 + 0];
                float d1 = rv[cl * 3 + 1] - sv[cl * 3 + 1];
                float d2 = rv[cl * 3 + 2] - sv[cl * 3 + 2];
                float l2 = d0 * d0 + d1 * d1 + d2 * d2;
                float len = sqrtf(fmaxf(l2, 1e-20f));
                float fs = 1.7320508f / (1.0f + len);
                int c = qp * 4 + cl;
                SHm[(c * 3 + 0) * 64 + s] = d0 * fs;
                SHm[(c * 3 + 1) * 64 + s] = d1 * fs;
                SHm[(c * 3 + 2) * 64 + s] = d2 * fs;
                MS[c * 64 + s] = l2;
            }
            // stage we1 len2-rows (16x128) into Wl[0..2047], pR into Wl[2048..2175]
            #pragma unroll
            for (int p = 0; p < 2; ++p) {
                int q = p * 256 + tid;
                *(float4*)&Wl[q * 4] = *(const float4*)&we1[q * 4];
            }
            if (tid < 128) Wl[2048 + tid] = pRn[tid];
        }
        __syncthreads();

        // ---- stage 1: a1 = silu((len2@we1_len + preS[s] + preR[r]) / 12) ----
        {
            const int s = tid & 63, uq = tid >> 6;
            int i = sbase + s;
            int sid = i + (i >= r);
            if (i >= 511) sid = r;
            float l2r[16];
            #pragma unroll
            for (int c = 0; c < 16; ++c) l2r[c] = MS[c * 64 + s];
            for (int uu = 0; uu < 32; ++uu) {
                int u = uq * 32 + uu;
                float acc = pSb[(size_t)u * NN + sid] + Wl[2048 + u];
                #pragma unroll
                for (int c = 0; c < 16; ++c) acc = fmaf(l2r[c], Wl[c * 128 + u], acc);
                A[u * 64 + s] = silu_f(acc * (1.0f / 12.0f));
            }
        }

        gemm_silu(we2);   // A = m_ij   (leading sync protects Wl/A)

        // ---- gate e = sigmoid(m @ winf / sqrt(128)); m_acc += m * e ----
        {
            const int s = tid & 63, part = tid >> 6;
            float p = 0.f;
            for (int j = 0; j < 32; ++j) {
                int u = part * 32 + j;
                p = fmaf(A[u * 64 + s], winf[u], p);
            }
            Wl[part * 64 + s] = p;
            __syncthreads();
            if (tid < 64) {
                int i = sbase + tid;
                float tot = Wl[tid] + Wl[64 + tid] + Wl[128 + tid] + Wl[192 + tid];
                Wl[256 + tid] = (i < 511) ? sigm_f(tot * 0.088388348f) : 0.f;  // pad masked
            }
            __syncthreads();
            for (int j = 0; j < 32; ++j) {
                int s2 = sh_m * 32 + ((j + u_m) & 31);   // diagonal: conflict-free
                macc = fmaf(A[u_m * 64 + s2], Wl[256 + s2], macc);
            }
        }

        gemm_silu(wx1);   // A = b1
        gemm_silu(wx2);   // A = phi_x

        // ---- G[u][w][k] += phi[u][s] * sh1[w][k][s]  (rank-1 accumulation) ----
        #pragma unroll 2
        for (int cb = 0; cb < 16; ++cb) {
            int s4 = ((tid + cb) & 15) * 4;   // rotated
            float sh0[4], sh1v[4], sh2[4];
            *(float4*)&sh0[0]  = *(const float4*)&SHm[(tx * 3 + 0) * 64 + s4];
            *(float4*)&sh1v[0] = *(const float4*)&SHm[(tx * 3 + 1) * 64 + s4];
            *(float4*)&sh2[0]  = *(const float4*)&SHm[(tx * 3 + 2) * 64 + s4];
            #pragma unroll
            for (int j = 0; j < 8; ++j) {
                float pa[4];
                *(float4*)&pa[0] = *(const float4*)&A[(ty * 8 + j) * 64 + s4];
                #pragma unroll
                for (int i2 = 0; i2 < 4; ++i2) {
                    G[j][0] = fmaf(pa[i2], sh0[i2],  G[j][0]);
                    G[j][1] = fmaf(pa[i2], sh1v[i2], G[j][1]);
                    G[j][2] = fmaf(pa[i2], sh2[i2],  G[j][2]);
                }
            }
        }
        __syncthreads();   // before next tile overwrites SHm/MS/A/Wl
    }

    // ---- finalize m_i ----
    Wl[sh_m * 128 + u_m] = macc;
    __syncthreads();
    if (tid < 128) m_i[(size_t)bx * 128 + tid] = Wl[tid] + Wl[128 + tid];
    // ---- dump G to LDS for wtp contraction ----
    #pragma unroll
    for (int j = 0; j < 8; ++j) {
        A[(ty * 8 + j) * 48 + tx * 3 + 0] = G[j][0];
        A[(ty * 8 + j) * 48 + tx * 3 + 1] = G[j][1];
        A[(ty * 8 + j) * 48 + tx * 3 + 2] = G[j][2];
    }
    __syncthreads();   // m_i reads of Wl done; G dump visible

    // ---- v_agg[v][k] = sum_{u,w} wtp[u][w][v] * G[u][w][k] (scaled) ----
    if (tid < 240) {
        int vk = tid % 48, ug = tid / 48;
        int vv = vk / 3, kk = vk - vv * 3;
        int u0 = (ug * 128) / 5, u1 = ((ug + 1) * 128) / 5;
        float acc = 0.f;
        for (int u = u0; u < u1; ++u) {
            #pragma unroll
            for (int w = 0; w < 16; ++w)
                acc = fmaf(wtp[(u * 16 + w) * 16 + vv], A[u * 48 + w * 3 + kk], acc);
        }
        Wl[ug * 48 + vk] = acc;
    }
    __syncthreads();
    if (tid < 48) {
        float tot = Wl[tid] + Wl[48 + tid] + Wl[96 + tid] + Wl[144 + tid] + Wl[192 + tid];
        v_agg[(size_t)bx * 48 + tid] = tot * 4.3242827e-05f;  // 1/(sqrt(2048)*511)
    }
}

// ---------------- per-node update: ph MLP, residuals ----------------
__global__ __launch_bounds__(128) void k_node_upd(
    const float* __restrict__ m_i, const float* __restrict__ v_agg,
    const float* __restrict__ wh1, const float* __restrict__ wh2,
    const float* __restrict__ wh_out, float* __restrict__ h, float* __restrict__ v)
{
    const int nx = (int)blockIdx.x;
    const int tid = (int)threadIdx.x;
    __shared__ float cat[192], t1[128], t2[128];
    if (tid < 128) cat[tid] = m_i[(size_t)nx * 128 + tid];
    if (tid < 64) cat[128 + tid] = h[(size_t)nx * 64 + tid];
    __syncthreads();
    {
        float acc = 0.f;
        for (int j = 0; j < 192; ++j) acc = fmaf(cat[j], wh1[j * 128 + tid], acc);
        t1[tid] = silu_f(acc * 0.072168784f);   // 1/sqrt(192)
    }
    __syncthreads();
    {
        float acc = 0.f;
        for (int j = 0; j < 128; ++j) acc = fmaf(t1[j], wh2[j * 128 + tid], acc);
        t2[tid] = silu_f(acc * 0.088388348f);   // 1/sqrt(128)
    }
    __syncthreads();
    if (tid < 64) {
        float acc = 0.f;
        for (int j = 0; j < 128; ++j) acc = fmaf(t2[j], wh_out[j * 64 + tid], acc);
        h[(size_t)nx * 64 + tid] = acc * 0.088388348f + cat[128 + tid];
    }
    if (tid < 48) v[(size_t)nx * 48 + tid] += v_agg[(size_t)nx * 48 + tid];
}

// ---------------- readout ----------------
__global__ __launch_bounds__(64) void k_readout(
    const float* __restrict__ v, const float* __restrict__ h,
    const float* __restrict__ vec_in, const float* __restrict__ wsM,
    const float* __restrict__ wvM, const float* __restrict__ w_out,
    const float* __restrict__ b_out, float* __restrict__ out)
{
    const int nx = (int)blockIdx.x;
    const int j = (int)threadIdx.x;   // 64 threads = 1 wave
    __shared__ float sm[64];
    const float* hn = h + (size_t)nx * 64;
    float acc = 0.f;
    for (int f = 0; f < 64; ++f) acc = fmaf(hn[f], wsM[f * 64 + j], acc);
    acc *= 0.125f;   // 1/sqrt(64)
    float mx = acc;
    #pragma unroll
    for (int off = 32; off; off >>= 1) mx = fmaxf(mx, __shfl_xor(mx, off));
    float e = __expf(acc - mx);
    float ssum = e;
    #pragma unroll
    for (int off = 32; off; off >>= 1) ssum += __shfl_xor(ssum, off);
    sm[j] = e / ssum;
    __syncthreads();
    float o = b_out[j];
    for (int i = 0; i < 64; ++i) o = fmaf(sm[i], w_out[i * 64 + j], o);
    out[2 * 512 * 24 + (size_t)nx * 64 + j] = o;
    if (j < 24) {
        int w = j / 3, k = j - w * 3;
        float a2 = 0.f;
        #pragma unroll
        for (int c = 0; c < 16; ++c)
            a2 = fmaf(v[(size_t)nx * 48 + c * 3 + k], wvM[c * 8 + w], a2);
        out[(size_t)nx * 24 + j] = a2 * 0.25f - vec_in[(size_t)nx * 3 + k];
    }
}

// ---------------- launch ----------------
extern "C" void kernel_launch(void* const* d_in, const int* in_sizes, int n_in,
                              void* d_out, int out_size, void* d_ws, size_t ws_size,
                              hipStream_t stream)
{
    (void)in_sizes; (void)n_in; (void)out_size; (void)ws_size;
    const float* x      = (const float*)d_in[0];
    const float* we1    = (const float*)d_in[1];
    const float* we2    = (const float*)d_in[2];
    const float* wx1    = (const float*)d_in[3];
    const float* wx2    = (const float*)d_in[4];
    const float* winf   = (const float*)d_in[5];
    const float* wtp    = (const float*)d_in[6];
    const float* wh1    = (const float*)d_in[7];
    const float* wh2    = (const float*)d_in[8];
    const float* wh_out = (const float*)d_in[9];
    const float* wsM    = (const float*)d_in[10];
    const float* wvM    = (const float*)d_in[11];
    const float* w_out  = (const float*)d_in[12];
    const float* b_out  = (const float*)d_in[13];
    float* out = (float*)d_out;
    float* W = (float*)d_ws;

    float* VEC_IN = W;             // 3072 floats
    float* V      = W + 4096;      // 49152
    float* H      = W + 53248;     // 65536
    float* PST    = W + 118784;    // 131072  [b][u][node]
    float* PR     = W + 249856;    // 131072  [b][node][u]
    float* MI     = W + 380928;    // 131072
    float* VAGG   = W + 512000;    // 49152

    // 80KB dynamic LDS for k_edge -> 2 WG/CU (capture-safe host config)
    hipFuncSetAttribute((const void*)k_edge,
                        hipFuncAttributeMaxDynamicSharedMemorySize, 81920);

    k_init<<<2, 256, 0, stream>>>(x, VEC_IN, V, H);
    for (int l = 0; l < 3; ++l) {
        k_node_pre<<<1024, 128, 0, stream>>>(H, we1 + l * 18432, PST, PR);
        k_edge<<<1024, 256, 81920, stream>>>(V, PST, PR, we1 + l * 18432,
            we2 + l * 16384, wx1 + l * 16384, wx2 + l * 16384, winf + l * 128,
            wtp + l * 32768, MI, VAGG);
        k_node_upd<<<1024, 128, 0, stream>>>(MI, VAGG, wh1 + l * 24576,
            wh2 + l * 16384, wh_out + l * 8192, H, V);
    }
    k_readout<<<1024, 64, 0, stream>>>(V, H, VEC_IN, wsM, wvM, w_out, b_out, out);
}

// Round 4
// 1378.664 us; speedup vs baseline: 4.7649x; 3.5240x over previous
//
#include <hip/hip_runtime.h>
#include <hip/hip_bf16.h>

#define NN 512

typedef short short8v __attribute__((ext_vector_type(8)));
typedef short short4v __attribute__((ext_vector_type(4)));
typedef float f32x4 __attribute__((ext_vector_type(4)));
typedef _Float16 h8 __attribute__((ext_vector_type(8)));

__device__ __forceinline__ float silu_f(float x) { return x / (1.0f + __expf(-x)); }
__device__ __forceinline__ float sigm_f(float x) { return 1.0f / (1.0f + __expf(-x)); }
__device__ __forceinline__ unsigned short f2h(float f) {
    union { _Float16 h; unsigned short s; } u; u.h = (_Float16)f; return u.s;
}
__device__ __forceinline__ float h2f(unsigned short s) {
    union { unsigned short s; _Float16 h; } u; u.s = s; return (float)u.h;
}

// LDS byte-address helpers (XOR swizzle on bits 4-6 breaks row-aligned bank conflicts)
__device__ __forceinline__ int actA(int s, int kbyte) {  // [s 64][u 128] f16, 256B rows
    return s * 256 + (kbyte ^ ((s & 7) << 4));
}
__device__ __forceinline__ int actP(int u, int sbyte) {  // [u 128][s 64] f16, 128B rows
    return u * 128 + (sbyte ^ ((u & 7) << 4));
}
__device__ __forceinline__ int shA(int wk, int sbyte) {  // [wk 48][s 64] f16, 128B rows
    return wk * 128 + (sbyte ^ ((wk & 7) << 4));
}
__device__ __forceinline__ int l2A(int s, int cbyte) {   // [s 64][c 32] f16, 64B rows
    return s * 64 + (cbyte ^ ((s & 3) << 4));
}

// ---------------- init: mean-center x, broadcast v0, h0 = 1 ----------------
__global__ void k_init(const float* __restrict__ x, float* __restrict__ vec_in,
                       float* __restrict__ v, float* __restrict__ h)
{
    const int b = (int)blockIdx.x;
    const int tid = (int)threadIdx.x;
    __shared__ float red[3 * 256];
    float s0 = 0.f, s1 = 0.f, s2 = 0.f;
    for (int n = tid; n < NN; n += 256) {
        s0 += x[(b * NN + n) * 3 + 0];
        s1 += x[(b * NN + n) * 3 + 1];
        s2 += x[(b * NN + n) * 3 + 2];
    }
    red[tid] = s0; red[256 + tid] = s1; red[512 + tid] = s2;
    __syncthreads();
    for (int off = 128; off; off >>= 1) {
        if (tid < off) {
            red[tid] += red[tid + off];
            red[256 + tid] += red[256 + tid + off];
            red[512 + tid] += red[512 + tid + off];
        }
        __syncthreads();
    }
    const float m0 = red[0] * (1.f / 512.f);
    const float m1 = red[256] * (1.f / 512.f);
    const float m2 = red[512] * (1.f / 512.f);
    for (int n = tid; n < NN; n += 256) {
        const size_t base = (size_t)b * NN + n;
        float d0 = x[base * 3 + 0] - m0;
        float d1 = x[base * 3 + 1] - m1;
        float d2 = x[base * 3 + 2] - m2;
        vec_in[base * 3 + 0] = d0;
        vec_in[base * 3 + 1] = d1;
        vec_in[base * 3 + 2] = d2;
        #pragma unroll
        for (int c = 0; c < 16; ++c) {
            v[base * 48 + c * 3 + 0] = d0;
            v[base * 48 + c * 3 + 1] = d1;
            v[base * 48 + c * 3 + 2] = d2;
        }
    }
    for (int q = tid; q < NN * 64; q += 256) h[(size_t)b * NN * 64 + q] = 1.0f;
}

// ------- prep: transpose + cvt weights to f16  WT[l][g][u][k], W1T[l][u][32] -------
__global__ __launch_bounds__(256) void k_prep(
    const float* __restrict__ we1, const float* __restrict__ we2,
    const float* __restrict__ wx1, const float* __restrict__ wx2,
    unsigned short* __restrict__ WT, unsigned short* __restrict__ W1T)
{
    int idx = (int)blockIdx.x * 256 + (int)threadIdx.x;
    if (idx < 3 * 3 * 16384) {
        int l = idx / 49152, r2 = idx % 49152;
        int g = r2 / 16384;
        int u = (r2 >> 7) & 127, k = r2 & 127;
        const float* src = (g == 0 ? we2 : g == 1 ? wx1 : wx2) + l * 16384;
        WT[idx] = f2h(src[k * 128 + u]);
        return;
    }
    int j = idx - 3 * 3 * 16384;
    if (j < 3 * 128 * 32) {
        int l = j >> 12;
        int u = (j >> 5) & 127, c = j & 31;
        W1T[j] = (c < 16) ? f2h(we1[l * 18432 + c * 128 + u]) : (unsigned short)0;
    }
}

// ---------------- per-node precompute: h @ we1 send/recv parts ----------------
__global__ __launch_bounds__(128) void k_node_pre(
    const float* __restrict__ h, const float* __restrict__ we1,
    float* __restrict__ pS, float* __restrict__ pR)
{
    const int nx = (int)blockIdx.x;       // b*512 + n
    const int tid = (int)threadIdx.x;     // u
    __shared__ float hl[64];
    if (tid < 64) hl[tid] = h[(size_t)nx * 64 + tid];
    __syncthreads();
    float a = 0.f, c = 0.f;
    for (int f = 0; f < 64; ++f) {
        const float hv = hl[f];
        a = fmaf(hv, we1[(16 + f) * 128 + tid], a);   // h[SEND] rows
        c = fmaf(hv, we1[(80 + f) * 128 + tid], c);   // h[RECV] rows
    }
    pS[(size_t)nx * 128 + tid] = a;   // [b][node][u]
    pR[(size_t)nx * 128 + tid] = c;   // [b][node][u]
}

// ---------------- edge kernel: f16-MFMA path, one WG per (batch, receiver) ----------------
// Scaling: len2 stored x2^-10 (bias enters C pre-scaled in f32), activations x2^-8.
__global__ __launch_bounds__(256, 3) void k_edge(
    const float* __restrict__ v, const float* __restrict__ pS,
    const float* __restrict__ pR, const unsigned short* __restrict__ WTl,
    const unsigned short* __restrict__ W1Tl, const float* __restrict__ winf,
    const float* __restrict__ wtp, float* __restrict__ m_i,
    float* __restrict__ v_agg)
{
    extern __shared__ char ldsb[];
    char* ACT0 = ldsb;                      // 16384 B  [s][u] f16 swz
    char* ACT1 = ldsb + 16384;              // 16384 B  [s][u] or phi [u][s]
    char* SHB  = ldsb + 32768;              // 6144 B   [wk 48][s 64] f16 swz
    char* L2B  = ldsb + 38912;              // 4096 B   [s][c 32] f16 swz
    float* ERED = (float*)(ldsb + 43008);   // 256 f32
    float* ES   = (float*)(ldsb + 44032);   // 64 f32

    const int tid = (int)threadIdx.x;
    const int bx = (int)blockIdx.x;
    const int b = bx >> 9, r = bx & 511;
    const int wv = tid >> 6, l = tid & 63;
    const int lr = l & 15, lg = l >> 4;

    const float S_L2  = 0x1p-10f;           // len2 storage scale
    const float S_ACT = 0x1p-8f;            // activation storage scale
    const float E1    = 0x1p+10f / 12.0f;   // stage-1 epilogue unscale
    const float EG    = 0x1p+8f * 0.088388348f;  // GEMM epilogue unscale (2^8/sqrt(128))

    const float* vb  = v  + (size_t)b * NN * 48;
    const float* pSb = pS + (size_t)b * NN * 128;
    const float* pRn = pR + ((size_t)b * NN + r) * 128;

    const int uA0 = wv * 32 + lr;        // A-frag row (m adds 16)
    const int uD0 = wv * 32 + lg * 4;    // D/C row    (m adds 16, reg adds 1)

    f32x4 g0[3], g1[3];                  // G acc: m=0/1, n=0..2 (wk)
    f32x4 mc0 = {0,0,0,0}, mc1 = {0,0,0,0};
    #pragma unroll
    for (int n = 0; n < 3; ++n) { g0[n] = f32x4{0,0,0,0}; g1[n] = f32x4{0,0,0,0}; }

    // persistent preloads (pR pre-scaled for the C-operand)
    f32x4 pRv[2], winfv[2];
    h8 w1f[2];
    #pragma unroll
    for (int m = 0; m < 2; ++m) {
        pRv[m]   = *(const f32x4*)(pRn + uD0 + m * 16) * S_L2;
        winfv[m] = *(const f32x4*)(winf + uD0 + m * 16);
        w1f[m]   = *(const h8*)(W1Tl + (uA0 + m * 16) * 32 + lg * 8);
    }

    // zero-fill len2 pad channels c=16..31 (never overwritten)
    if (tid < 128) {
        int s = tid >> 1, cc = 2 + (tid & 1);
        *(f32x4*)(L2B + (s * 64 + ((cc * 16) ^ ((s & 3) << 4)))) = f32x4{0, 0, 0, 0};
    }

    float pe[4];

    for (int T = 0; T < 8; ++T) {
        const int sbase = T * 64;

        // ---- stage-1 bias loads (issued early, consumed after barrier) ----
        f32x4 psv0[4], psv1[4];
        #pragma unroll
        for (int n = 0; n < 4; ++n) {
            int i = sbase + n * 16 + lr;
            int sid = i + (i >= r);
            if (i >= 511) sid = r;
            psv0[n] = *(const f32x4*)(pSb + (size_t)sid * 128 + uD0);
            psv1[n] = *(const f32x4*)(pSb + (size_t)sid * 128 + uD0 + 16);
        }

        // ---- geometry: vec, len2(f16 x2^-10), sh1(f16) ----
        {
            const int s = tid >> 2, qp = tid & 3;
            int i = sbase + s;
            int sid = i + (i >= r);
            if (i >= 511) sid = r;   // pad: self-edge, sh1=0, gated out
            const float* vs = vb + sid * 48 + qp * 12;
            const float* vr = vb + r   * 48 + qp * 12;
            float sv[12], rv[12];
            #pragma unroll
            for (int q = 0; q < 3; ++q) {
                *(float4*)&sv[q * 4] = *(const float4*)&vs[q * 4];
                *(float4*)&rv[q * 4] = *(const float4*)&vr[q * 4];
            }
            short4v l2p;
            #pragma unroll
            for (int cl = 0; cl < 4; ++cl) {
                float d0 = rv[cl * 3 + 0] - sv[cl * 3 + 0];
                float d1 = rv[cl * 3 + 1] - sv[cl * 3 + 1];
                float d2 = rv[cl * 3 + 2] - sv[cl * 3 + 2];
                float l2 = d0 * d0 + d1 * d1 + d2 * d2;
                float len = sqrtf(fmaxf(l2, 1e-20f));
                float fs = 1.7320508f / (1.0f + len);
                int wk = (qp * 4 + cl) * 3;
                *(unsigned short*)(SHB + shA(wk + 0, s * 2)) = f2h(d0 * fs);
                *(unsigned short*)(SHB + shA(wk + 1, s * 2)) = f2h(d1 * fs);
                *(unsigned short*)(SHB + shA(wk + 2, s * 2)) = f2h(d2 * fs);
                l2p[cl] = (short)f2h(l2 * S_L2);
            }
            *(short4v*)(L2B + l2A(s, qp * 8)) = l2p;
        }
        __syncthreads();

        // ---- stage 1: a1 = silu((len2@we1len + pS + pR)/12)  (f16 MFMA, f32 C bias) ----
        {
            f32x4 d0[4], d1[4];
            #pragma unroll
            for (int n = 0; n < 4; ++n) {
                h8 bl = *(const h8*)(L2B + l2A(n * 16 + lr, lg * 16));
                d0[n] = __builtin_amdgcn_mfma_f32_16x16x32_f16(w1f[0], bl, psv0[n] * S_L2 + pRv[0], 0, 0, 0);
                d1[n] = __builtin_amdgcn_mfma_f32_16x16x32_f16(w1f[1], bl, psv1[n] * S_L2 + pRv[1], 0, 0, 0);
            }
            #pragma unroll
            for (int n = 0; n < 4; ++n) {
                int s = n * 16 + lr;
                short4v o0, o1;
                #pragma unroll
                for (int j2 = 0; j2 < 4; ++j2) {
                    o0[j2] = (short)f2h(silu_f(d0[n][j2] * E1) * S_ACT);
                    o1[j2] = (short)f2h(silu_f(d1[n][j2] * E1) * S_ACT);
                }
                *(short4v*)(ACT0 + actA(s, uD0 * 2))        = o0;
                *(short4v*)(ACT0 + actA(s, (uD0 + 16) * 2)) = o1;
            }
        }
        __syncthreads();

        // ---- gemm we2: ACT0 -> ACT1 (m_ij), plus phi_inf partials ----
        {
            const unsigned short* Wg = WTl;
            h8 wf0[4], wf1[4];
            #pragma unroll
            for (int kt = 0; kt < 4; ++kt) {
                wf0[kt] = *(const h8*)(Wg + uA0 * 128 + kt * 32 + lg * 8);
                wf1[kt] = *(const h8*)(Wg + (uA0 + 16) * 128 + kt * 32 + lg * 8);
            }
            f32x4 cf0[4], cf1[4];
            #pragma unroll
            for (int n = 0; n < 4; ++n) { cf0[n] = f32x4{0,0,0,0}; cf1[n] = f32x4{0,0,0,0}; }
            #pragma unroll
            for (int n = 0; n < 4; ++n) {
                #pragma unroll
                for (int kt = 0; kt < 4; ++kt) {
                    h8 bfr = *(const h8*)(ACT0 + actA(n * 16 + lr, kt * 64 + lg * 16));
                    cf0[n] = __builtin_amdgcn_mfma_f32_16x16x32_f16(wf0[kt], bfr, cf0[n], 0, 0, 0);
                    cf1[n] = __builtin_amdgcn_mfma_f32_16x16x32_f16(wf1[kt], bfr, cf1[n], 0, 0, 0);
                }
            }
            #pragma unroll
            for (int n = 0; n < 4; ++n) {
                int s = n * 16 + lr;
                float p = 0.f;
                short4v o0, o1;
                #pragma unroll
                for (int j2 = 0; j2 < 4; ++j2) {
                    float a0 = silu_f(cf0[n][j2] * EG);
                    float a1 = silu_f(cf1[n][j2] * EG);
                    p += a0 * winfv[0][j2] + a1 * winfv[1][j2];
                    o0[j2] = (short)f2h(a0 * S_ACT);
                    o1[j2] = (short)f2h(a1 * S_ACT);
                }
                pe[n] = p;
                *(short4v*)(ACT1 + actA(s, uD0 * 2))        = o0;
                *(short4v*)(ACT1 + actA(s, (uD0 + 16) * 2)) = o1;
            }
        }
        __syncthreads();

        // ---- gate: e = sigmoid(sum_u m*winf / sqrt(128)); mc += m_f16 * e ----
        #pragma unroll
        for (int n = 0; n < 4; ++n) {
            pe[n] += __shfl_xor(pe[n], 16);
            pe[n] += __shfl_xor(pe[n], 32);
        }
        if (l < 16) {
            #pragma unroll
            for (int n = 0; n < 4; ++n) ERED[wv * 64 + n * 16 + l] = pe[n];
        }
        __syncthreads();
        if (tid < 64) {
            float tot = ERED[tid] + ERED[64 + tid] + ERED[128 + tid] + ERED[192 + tid];
            int i = sbase + tid;
            ES[tid] = (i < 511) ? sigm_f(tot * 0.088388348f) : 0.f;  // pad masked
        }
        __syncthreads();
        #pragma unroll
        for (int n = 0; n < 4; ++n) {
            float en = ES[n * 16 + lr];
            short4v m0 = *(const short4v*)(ACT1 + actA(n * 16 + lr, uD0 * 2));
            short4v m1 = *(const short4v*)(ACT1 + actA(n * 16 + lr, (uD0 + 16) * 2));
            #pragma unroll
            for (int j2 = 0; j2 < 4; ++j2) {
                mc0[j2] += h2f((unsigned short)m0[j2]) * en;
                mc1[j2] += h2f((unsigned short)m1[j2]) * en;
            }
        }

        // ---- gemm wx1: ACT1 -> ACT0 (b1) ----
        {
            const unsigned short* Wg = WTl + 16384;
            h8 wf0[4], wf1[4];
            #pragma unroll
            for (int kt = 0; kt < 4; ++kt) {
                wf0[kt] = *(const h8*)(Wg + uA0 * 128 + kt * 32 + lg * 8);
                wf1[kt] = *(const h8*)(Wg + (uA0 + 16) * 128 + kt * 32 + lg * 8);
            }
            f32x4 cf0[4], cf1[4];
            #pragma unroll
            for (int n = 0; n < 4; ++n) { cf0[n] = f32x4{0,0,0,0}; cf1[n] = f32x4{0,0,0,0}; }
            #pragma unroll
            for (int n = 0; n < 4; ++n) {
                #pragma unroll
                for (int kt = 0; kt < 4; ++kt) {
                    h8 bfr = *(const h8*)(ACT1 + actA(n * 16 + lr, kt * 64 + lg * 16));
                    cf0[n] = __builtin_amdgcn_mfma_f32_16x16x32_f16(wf0[kt], bfr, cf0[n], 0, 0, 0);
                    cf1[n] = __builtin_amdgcn_mfma_f32_16x16x32_f16(wf1[kt], bfr, cf1[n], 0, 0, 0);
                }
            }
            #pragma unroll
            for (int n = 0; n < 4; ++n) {
                int s = n * 16 + lr;
                short4v o0, o1;
                #pragma unroll
                for (int j2 = 0; j2 < 4; ++j2) {
                    o0[j2] = (short)f2h(silu_f(cf0[n][j2] * EG) * S_ACT);
                    o1[j2] = (short)f2h(silu_f(cf1[n][j2] * EG) * S_ACT);
                }
                *(short4v*)(ACT0 + actA(s, uD0 * 2))        = o0;
                *(short4v*)(ACT0 + actA(s, (uD0 + 16) * 2)) = o1;
            }
        }
        __syncthreads();

        // ---- gemm wx2: ACT0 -> ACT1 as phi [u][s] ----
        {
            const unsigned short* Wg = WTl + 32768;
            h8 wf0[4], wf1[4];
            #pragma unroll
            for (int kt = 0; kt < 4; ++kt) {
                wf0[kt] = *(const h8*)(Wg + uA0 * 128 + kt * 32 + lg * 8);
                wf1[kt] = *(const h8*)(Wg + (uA0 + 16) * 128 + kt * 32 + lg * 8);
            }
            f32x4 cf0[4], cf1[4];
            #pragma unroll
            for (int n = 0; n < 4; ++n) { cf0[n] = f32x4{0,0,0,0}; cf1[n] = f32x4{0,0,0,0}; }
            #pragma unroll
            for (int n = 0; n < 4; ++n) {
                #pragma unroll
                for (int kt = 0; kt < 4; ++kt) {
                    h8 bfr = *(const h8*)(ACT0 + actA(n * 16 + lr, kt * 64 + lg * 16));
                    cf0[n] = __builtin_amdgcn_mfma_f32_16x16x32_f16(wf0[kt], bfr, cf0[n], 0, 0, 0);
                    cf1[n] = __builtin_amdgcn_mfma_f32_16x16x32_f16(wf1[kt], bfr, cf1[n], 0, 0, 0);
                }
            }
            __syncthreads();   // all wx1-phase ACT1 reads done before phi overwrite
            #pragma unroll
            for (int n = 0; n < 4; ++n) {
                int s2 = (n * 16 + lr) * 2;
                #pragma unroll
                for (int j2 = 0; j2 < 4; ++j2) {
                    *(unsigned short*)(ACT1 + actP(uD0 + j2, s2)) =
                        f2h(silu_f(cf0[n][j2] * EG) * S_ACT);
                    *(unsigned short*)(ACT1 + actP(uD0 + 16 + j2, s2)) =
                        f2h(silu_f(cf1[n][j2] * EG) * S_ACT);
                }
            }
        }
        __syncthreads();

        // ---- G-gemm: G[u][wk] += phi[u][s] @ SH[s][wk]  (phi carries 2^-8) ----
        {
            h8 af0[2], af1[2];
            #pragma unroll
            for (int t = 0; t < 2; ++t) {
                af0[t] = *(const h8*)(ACT1 + actP(wv * 32 + lr,      t * 64 + lg * 16));
                af1[t] = *(const h8*)(ACT1 + actP(wv * 32 + 16 + lr, t * 64 + lg * 16));
            }
            #pragma unroll
            for (int n = 0; n < 3; ++n) {
                #pragma unroll
                for (int t = 0; t < 2; ++t) {
                    h8 bh = *(const h8*)(SHB + shA(n * 16 + lr, t * 64 + lg * 16));
                    g0[n] = __builtin_amdgcn_mfma_f32_16x16x32_f16(af0[t], bh, g0[n], 0, 0, 0);
                    g1[n] = __builtin_amdgcn_mfma_f32_16x16x32_f16(af1[t], bh, g1[n], 0, 0, 0);
                }
            }
        }
        __syncthreads();   // protects SHB/L2B/ACT* for next tile
    }

    // ---- m_i: reduce over the 16 s-lanes, unscale (x2^8), store ----
    #pragma unroll
    for (int j2 = 0; j2 < 4; ++j2) {
        float v0 = mc0[j2], v1 = mc1[j2];
        v0 += __shfl_xor(v0, 1); v0 += __shfl_xor(v0, 2);
        v0 += __shfl_xor(v0, 4); v0 += __shfl_xor(v0, 8);
        v1 += __shfl_xor(v1, 1); v1 += __shfl_xor(v1, 2);
        v1 += __shfl_xor(v1, 4); v1 += __shfl_xor(v1, 8);
        mc0[j2] = v0; mc1[j2] = v1;
    }
    if (lr == 0) {
        float4 s0, s1;
        s0.x = mc0[0] * 256.f; s0.y = mc0[1] * 256.f; s0.z = mc0[2] * 256.f; s0.w = mc0[3] * 256.f;
        s1.x = mc1[0] * 256.f; s1.y = mc1[1] * 256.f; s1.z = mc1[2] * 256.f; s1.w = mc1[3] * 256.f;
        *(float4*)(m_i + (size_t)bx * 128 + uD0)      = s0;
        *(float4*)(m_i + (size_t)bx * 128 + uD0 + 16) = s1;
    }

    // ---- dump G to LDS f32 [u][48] (overlays ACT0+ACT1) ----
    float* Gd = (float*)ldsb;
    #pragma unroll
    for (int n = 0; n < 3; ++n) {
        #pragma unroll
        for (int j2 = 0; j2 < 4; ++j2) {
            Gd[(uD0 + j2) * 48 + n * 16 + lr]      = g0[n][j2];
            Gd[(uD0 + 16 + j2) * 48 + n * 16 + lr] = g1[n][j2];
        }
    }
    __syncthreads();

    // ---- v_agg[v][k] = sum_{u,w} wtp[u][w][v] * G[u][w*3+k]  (scaled, x2^8 unscale) ----
    float* scr = (float*)(ldsb + 32768);
    if (tid < 240) {
        int vk = tid % 48, ug = tid / 48;
        int vv = vk / 3, kk = vk - vv * 3;
        int u0 = (ug * 128) / 5, u1 = ((ug + 1) * 128) / 5;
        float acc = 0.f;
        for (int u = u0; u < u1; ++u) {
            #pragma unroll
            for (int w = 0; w < 16; ++w)
                acc = fmaf(wtp[(u * 16 + w) * 16 + vv], Gd[u * 48 + w * 3 + kk], acc);
        }
        scr[ug * 48 + vk] = acc;
    }
    __syncthreads();
    if (tid < 48) {
        float tot = scr[tid] + scr[48 + tid] + scr[96 + tid] + scr[144 + tid] + scr[192 + tid];
        v_agg[(size_t)bx * 48 + tid] = tot * 1.1070164e-02f;  // 2^8 / (sqrt(2048)*511)
    }
}

// ---------------- per-node update: ph MLP, residuals ----------------
__global__ __launch_bounds__(128) void k_node_upd(
    const float* __restrict__ m_i, const float* __restrict__ v_agg,
    const float* __restrict__ wh1, const float* __restrict__ wh2,
    const float* __restrict__ wh_out, float* __restrict__ h, float* __restrict__ v)
{
    const int nx = (int)blockIdx.x;
    const int tid = (int)threadIdx.x;
    __shared__ float cat[192], t1[128], t2[128];
    if (tid < 128) cat[tid] = m_i[(size_t)nx * 128 + tid];
    if (tid < 64) cat[128 + tid] = h[(size_t)nx * 64 + tid];
    __syncthreads();
    {
        float acc = 0.f;
        for (int j = 0; j < 192; ++j) acc = fmaf(cat[j], wh1[j * 128 + tid], acc);
        t1[tid] = silu_f(acc * 0.072168784f);   // 1/sqrt(192)
    }
    __syncthreads();
    {
        float acc = 0.f;
        for (int j = 0; j < 128; ++j) acc = fmaf(t1[j], wh2[j * 128 + tid], acc);
        t2[tid] = silu_f(acc * 0.088388348f);   // 1/sqrt(128)
    }
    __syncthreads();
    if (tid < 64) {
        float acc = 0.f;
        for (int j = 0; j < 128; ++j) acc = fmaf(t2[j], wh_out[j * 64 + tid], acc);
        h[(size_t)nx * 64 + tid] = acc * 0.088388348f + cat[128 + tid];
    }
    if (tid < 48) v[(size_t)nx * 48 + tid] += v_agg[(size_t)nx * 48 + tid];
}

// ---------------- readout ----------------
__global__ __launch_bounds__(64) void k_readout(
    const float* __restrict__ v, const float* __restrict__ h,
    const float* __restrict__ vec_in, const float* __restrict__ wsM,
    const float* __restrict__ wvM, const float* __restrict__ w_out,
    const float* __restrict__ b_out, float* __restrict__ out)
{
    const int nx = (int)blockIdx.x;
    const int j = (int)threadIdx.x;   // 64 threads = 1 wave
    __shared__ float sm[64];
    const float* hn = h + (size_t)nx * 64;
    float acc = 0.f;
    for (int f = 0; f < 64; ++f) acc = fmaf(hn[f], wsM[f * 64 + j], acc);
    acc *= 0.125f;   // 1/sqrt(64)
    float mx = acc;
    #pragma unroll
    for (int off = 32; off; off >>= 1) mx = fmaxf(mx, __shfl_xor(mx, off));
    float e = __expf(acc - mx);
    float ssum = e;
    #pragma unroll
    for (int off = 32; off; off >>= 1) ssum += __shfl_xor(ssum, off);
    sm[j] = e / ssum;
    __syncthreads();
    float o = b_out[j];
    for (int i = 0; i < 64; ++i) o = fmaf(sm[i], w_out[i * 64 + j], o);
    out[2 * 512 * 24 + (size_t)nx * 64 + j] = o;
    if (j < 24) {
        int w = j / 3, k = j - w * 3;
        float a2 = 0.f;
        #pragma unroll
        for (int c = 0; c < 16; ++c)
            a2 = fmaf(v[(size_t)nx * 48 + c * 3 + k], wvM[c * 8 + w], a2);
        out[(size_t)nx * 24 + j] = a2 * 0.25f - vec_in[(size_t)nx * 3 + k];
    }
}

// ---------------- launch ----------------
extern "C" void kernel_launch(void* const* d_in, const int* in_sizes, int n_in,
                              void* d_out, int out_size, void* d_ws, size_t ws_size,
                              hipStream_t stream)
{
    (void)in_sizes; (void)n_in; (void)out_size; (void)ws_size;
    const float* x      = (const float*)d_in[0];
    const float* we1    = (const float*)d_in[1];
    const float* we2    = (const float*)d_in[2];
    const float* wx1    = (const float*)d_in[3];
    const float* wx2    = (const float*)d_in[4];
    const float* winf   = (const float*)d_in[5];
    const float* wtp    = (const float*)d_in[6];
    const float* wh1    = (const float*)d_in[7];
    const float* wh2    = (const float*)d_in[8];
    const float* wh_out = (const float*)d_in[9];
    const float* wsM    = (const float*)d_in[10];
    const float* wvM    = (const float*)d_in[11];
    const float* w_out  = (const float*)d_in[12];
    const float* b_out  = (const float*)d_in[13];
    float* out = (float*)d_out;
    float* W = (float*)d_ws;

    float* VEC_IN = W;              // 3072 used
    float* V      = W + 4096;       // 49152
    float* H      = W + 53248;      // 65536
    float* PSp    = W + 118784;     // 131072  [b][node][u]
    float* PRp    = W + 249856;     // 131072  [b][node][u]
    float* MI     = W + 380928;     // 131072
    float* VAGG   = W + 512000;     // 49152
    unsigned short* WT  = (unsigned short*)(W + 561152);  // 147456 f16
    unsigned short* W1T = WT + 147456;                    // 12288 f16

    hipFuncSetAttribute((const void*)k_edge,
                        hipFuncAttributeMaxDynamicSharedMemorySize, 45056);

    k_init<<<2, 256, 0, stream>>>(x, VEC_IN, V, H);
    k_prep<<<624, 256, 0, stream>>>(we1, we2, wx1, wx2, WT, W1T);
    for (int l = 0; l < 3; ++l) {
        k_node_pre<<<1024, 128, 0, stream>>>(H, we1 + l * 18432, PSp, PRp);
        k_edge<<<1024, 256, 45056, stream>>>(V, PSp, PRp,
            WT + l * 49152, W1T + l * 4096, winf + l * 128,
            wtp + l * 32768, MI, VAGG);
        k_node_upd<<<1024, 128, 0, stream>>>(MI, VAGG, wh1 + l * 24576,
            wh2 + l * 16384, wh_out + l * 8192, H, V);
    }
    k_readout<<<1024, 64, 0, stream>>>(V, H, VEC_IN, wsM, wvM, w_out, b_out, out);
}

// Round 5
// 1204.697 us; speedup vs baseline: 5.4530x; 1.1444x over previous
//
#include <hip/hip_runtime.h>

#define NN 512

typedef short short4v __attribute__((ext_vector_type(4)));
typedef short short8v __attribute__((ext_vector_type(8)));
typedef float f32x4 __attribute__((ext_vector_type(4)));
typedef _Float16 h8 __attribute__((ext_vector_type(8)));

__device__ __forceinline__ float silu_f(float x) { return x / (1.0f + __expf(-x)); }
__device__ __forceinline__ float sigm_f(float x) { return 1.0f / (1.0f + __expf(-x)); }
__device__ __forceinline__ unsigned short f2h(float f) {
    union { _Float16 h; unsigned short s; } u; u.h = (_Float16)f; return u.s;
}
__device__ __forceinline__ float h2f(unsigned short s) {
    union { unsigned short s; _Float16 h; } u; u.s = s; return (float)u.h;
}

// LDS byte-address helpers (XOR swizzle: bank-conflict-free MFMA frag reads)
__device__ __forceinline__ int actA(int s, int kbyte) {  // [s 64][k 128] f16, 256B rows
    return s * 256 + (kbyte ^ ((s & 7) << 4));
}
__device__ __forceinline__ int actP(int u, int sbyte) {  // [u 128][s 64] f16, 128B rows
    return u * 128 + (sbyte ^ ((u & 7) << 4));
}
__device__ __forceinline__ int shA(int wk, int sbyte) {  // [wk 48][s 64] f16, 128B rows
    return wk * 128 + (sbyte ^ ((wk & 7) << 4));
}

// ---------------- init: mean-center x, broadcast v0, h0 = 1 (f32 + f16) ----------------
__global__ void k_init(const float* __restrict__ x, float* __restrict__ vec_in,
                       float* __restrict__ v, float* __restrict__ h,
                       unsigned short* __restrict__ hf)
{
    const int b = (int)blockIdx.x;
    const int tid = (int)threadIdx.x;
    __shared__ float red[3 * 256];
    float s0 = 0.f, s1 = 0.f, s2 = 0.f;
    for (int n = tid; n < NN; n += 256) {
        s0 += x[(b * NN + n) * 3 + 0];
        s1 += x[(b * NN + n) * 3 + 1];
        s2 += x[(b * NN + n) * 3 + 2];
    }
    red[tid] = s0; red[256 + tid] = s1; red[512 + tid] = s2;
    __syncthreads();
    for (int off = 128; off; off >>= 1) {
        if (tid < off) {
            red[tid] += red[tid + off];
            red[256 + tid] += red[256 + tid + off];
            red[512 + tid] += red[512 + tid + off];
        }
        __syncthreads();
    }
    const float m0 = red[0] * (1.f / 512.f);
    const float m1 = red[256] * (1.f / 512.f);
    const float m2 = red[512] * (1.f / 512.f);
    for (int n = tid; n < NN; n += 256) {
        const size_t base = (size_t)b * NN + n;
        float d0 = x[base * 3 + 0] - m0;
        float d1 = x[base * 3 + 1] - m1;
        float d2 = x[base * 3 + 2] - m2;
        vec_in[base * 3 + 0] = d0;
        vec_in[base * 3 + 1] = d1;
        vec_in[base * 3 + 2] = d2;
        #pragma unroll
        for (int c = 0; c < 16; ++c) {
            v[base * 48 + c * 3 + 0] = d0;
            v[base * 48 + c * 3 + 1] = d1;
            v[base * 48 + c * 3 + 2] = d2;
        }
    }
    for (int q = tid; q < NN * 64; q += 256) {
        h[(size_t)b * NN * 64 + q] = 1.0f;
        hf[(size_t)b * NN * 64 + q] = 0x3C00;  // f16 1.0
    }
}

// ------- prep: f16 weights. WT[l][g][u][128]; W1Tp[l][u][96] (l2-rows x 2^10); wtpH copy ----
__global__ __launch_bounds__(256) void k_prep(
    const float* __restrict__ we1, const float* __restrict__ we2,
    const float* __restrict__ wx1, const float* __restrict__ wx2,
    const float* __restrict__ wtp,
    unsigned short* __restrict__ WT, unsigned short* __restrict__ W1Tp,
    unsigned short* __restrict__ WTPH)
{
    int idx = (int)blockIdx.x * 256 + (int)threadIdx.x;
    if (idx < 147456) {                      // 3 layers x 3 gemms x 128x128, transposed
        int l = idx / 49152, r2 = idx % 49152;
        int g = r2 / 16384;
        int u = (r2 >> 7) & 127, k = r2 & 127;
        const float* src = (g == 0 ? we2 : g == 1 ? wx1 : wx2) + l * 16384;
        WT[idx] = f2h(src[k * 128 + u]);
        return;
    }
    int j = idx - 147456;
    if (j < 36864) {                         // 3 x 128 x 96: [l2(16) x1024 | h_send(64) | 0]
        int l = j / 12288, r2 = j % 12288;
        int u = r2 / 96, k = r2 % 96;
        float val = 0.f;
        if (k < 80) val = we1[l * 18432 + k * 128 + u] * (k < 16 ? 1024.0f : 1.0f);
        W1Tp[j] = f2h(val);
        return;
    }
    int q = j - 36864;
    if (q < 98304) WTPH[q] = f2h(wtp[q]);    // 3 x 2048 x 16 straight copy
}

// ---------------- per-node precompute: pR = h @ we1 recv rows ----------------
__global__ __launch_bounds__(128) void k_node_pre(
    const float* __restrict__ h, const float* __restrict__ we1,
    float* __restrict__ pR)
{
    const int nx = (int)blockIdx.x;
    const int tid = (int)threadIdx.x;     // u
    __shared__ float hl[64];
    if (tid < 64) hl[tid] = h[(size_t)nx * 64 + tid];
    __syncthreads();
    float c = 0.f;
    for (int f = 0; f < 64; ++f)
        c = fmaf(hl[f], we1[(80 + f) * 128 + tid], c);
    pR[(size_t)nx * 128 + tid] = c;
}

// ---------------- edge kernel: 8 waves, weights in VGPRs, h-as-K-channels ----------------
__global__ __launch_bounds__(512, 4) void k_edge(
    const float* __restrict__ v, const float* __restrict__ pR,
    const unsigned short* __restrict__ hf, const unsigned short* __restrict__ WTl,
    const unsigned short* __restrict__ W1Tl, const float* __restrict__ winf,
    float* __restrict__ m_i, unsigned short* __restrict__ GB)
{
    extern __shared__ char ldsb[];
    char* B1   = ldsb;                      // 16384: [s][K=96 of 128] f16 swz (l2|h|0)
    char* ACT0 = ldsb + 16384;              // 16384
    char* ACT1 = ldsb + 32768;              // 16384 (also phi [u][s])
    char* SHB  = ldsb + 49152;              // 6144: [wk 48][s 64]
    float* ERED = (float*)(ldsb + 55296);   // 8 x 64 f32
    float* ES   = (float*)(ldsb + 57344);   // 64 f32

    const int tid = (int)threadIdx.x;
    const int bx = (int)blockIdx.x;
    const int b = bx >> 9, r = bx & 511;
    const int wv = tid >> 6, l = tid & 63;
    const int lr = l & 15, lg = l >> 4;
    const int uW = wv * 16;                 // wave's 16-row u-slice
    const int sg = tid >> 3, sub = tid & 7; // geometry: sender row, 1/8 slice

    const float S_L2  = 0x1p-10f;
    const float S_ACT = 0x1p-8f;
    const float EG    = 0x1p+8f * 0.088388348f;   // 2^8 / sqrt(128)

    const float* vb = v + (size_t)b * NN * 48;
    const unsigned short* hb = hf + (size_t)b * NN * 64;

    // ---- persistent weight slices (once per kernel) ----
    h8 w1f[3], wf0[4], wf1[4], wf2[4];
    #pragma unroll
    for (int kt = 0; kt < 3; ++kt)
        w1f[kt] = *(const h8*)(W1Tl + (uW + lr) * 96 + kt * 32 + lg * 8);
    #pragma unroll
    for (int kt = 0; kt < 4; ++kt) {
        wf0[kt] = *(const h8*)(WTl +         (uW + lr) * 128 + kt * 32 + lg * 8);
        wf1[kt] = *(const h8*)(WTl + 16384 + (uW + lr) * 128 + kt * 32 + lg * 8);
        wf2[kt] = *(const h8*)(WTl + 32768 + (uW + lr) * 128 + kt * 32 + lg * 8);
    }
    f32x4 pRv   = *(const f32x4*)(pR + (size_t)bx * 128 + uW + lg * 4);
    f32x4 winfv = *(const f32x4*)(winf + uW + lg * 4);
    float vr6[6];
    #pragma unroll
    for (int q = 0; q < 3; ++q)
        *(float2*)&vr6[q * 2] = *(const float2*)(vb + r * 48 + sub * 6 + q * 2);

    // zero B1 K-pad cols 80..96 (bytes 160..192), written once
    *(float*)(B1 + sg * 256 + ((160 + sub * 4) ^ ((sg & 7) << 4))) = 0.f;

    f32x4 g[3];
    f32x4 mc = {0.f, 0.f, 0.f, 0.f};
    #pragma unroll
    for (int n = 0; n < 3; ++n) g[n] = f32x4{0.f, 0.f, 0.f, 0.f};

    for (int T = 0; T < 8; ++T) {
        const int sbase = T * 64;
        const int sid = sbase + sg;

        // ---- geometry + h staging (self-edge kept: sh=0 naturally, e masked) ----
        {
            float sv[6];
            #pragma unroll
            for (int q = 0; q < 3; ++q)
                *(float2*)&sv[q * 2] = *(const float2*)(vb + sid * 48 + sub * 6 + q * 2);
            h8 hv = *(const h8*)(hb + sid * 64 + sub * 8);
            unsigned short lh[2];
            #pragma unroll
            for (int cl = 0; cl < 2; ++cl) {
                float d0 = vr6[cl * 3 + 0] - sv[cl * 3 + 0];
                float d1 = vr6[cl * 3 + 1] - sv[cl * 3 + 1];
                float d2 = vr6[cl * 3 + 2] - sv[cl * 3 + 2];
                float l2 = d0 * d0 + d1 * d1 + d2 * d2;
                float len = sqrtf(fmaxf(l2, 1e-20f));
                float fs = 1.7320508f / (1.0f + len);
                int wk = (sub * 2 + cl) * 3;
                *(unsigned short*)(SHB + shA(wk + 0, sg * 2)) = f2h(d0 * fs);
                *(unsigned short*)(SHB + shA(wk + 1, sg * 2)) = f2h(d1 * fs);
                *(unsigned short*)(SHB + shA(wk + 2, sg * 2)) = f2h(d2 * fs);
                lh[cl] = f2h(l2 * S_L2);
            }
            *(unsigned*)(B1 + sg * 256 + ((sub * 4) ^ ((sg & 7) << 4))) =
                (unsigned)lh[0] | ((unsigned)lh[1] << 16);
            *(h8*)(B1 + sg * 256 + ((32 + sub * 16) ^ ((sg & 7) << 4))) = hv;
        }
        __syncthreads();   // (1)

        // ---- stage 1: a1 = silu((l2@we1l2 + h_s@we1h + pR)/12), K=96 MFMA ----
        {
            f32x4 d[4];
            #pragma unroll
            for (int n = 0; n < 4; ++n) {
                f32x4 acc = pRv;
                #pragma unroll
                for (int kt = 0; kt < 3; ++kt) {
                    h8 bl = *(const h8*)(B1 + actA(n * 16 + lr, kt * 64 + lg * 16));
                    acc = __builtin_amdgcn_mfma_f32_16x16x32_f16(w1f[kt], bl, acc, 0, 0, 0);
                }
                d[n] = acc;
            }
            #pragma unroll
            for (int n = 0; n < 4; ++n) {
                short4v o;
                #pragma unroll
                for (int j2 = 0; j2 < 4; ++j2)
                    o[j2] = (short)f2h(silu_f(d[n][j2] * (1.0f / 12.0f)) * S_ACT);
                *(short4v*)(ACT0 + actA(n * 16 + lr, (uW + lg * 4) * 2)) = o;
            }
        }
        __syncthreads();   // (2)

        float pe[4];
        // ---- gemm we2: ACT0 -> ACT1 (m_ij) + phi_inf partials ----
        {
            f32x4 cf[4];
            #pragma unroll
            for (int n = 0; n < 4; ++n) cf[n] = f32x4{0.f, 0.f, 0.f, 0.f};
            #pragma unroll
            for (int n = 0; n < 4; ++n)
                #pragma unroll
                for (int kt = 0; kt < 4; ++kt) {
                    h8 bfr = *(const h8*)(ACT0 + actA(n * 16 + lr, kt * 64 + lg * 16));
                    cf[n] = __builtin_amdgcn_mfma_f32_16x16x32_f16(wf0[kt], bfr, cf[n], 0, 0, 0);
                }
            #pragma unroll
            for (int n = 0; n < 4; ++n) {
                float p = 0.f;
                short4v o;
                #pragma unroll
                for (int j2 = 0; j2 < 4; ++j2) {
                    float a = silu_f(cf[n][j2] * EG);
                    p += a * winfv[j2];
                    o[j2] = (short)f2h(a * S_ACT);
                }
                pe[n] = p;
                *(short4v*)(ACT1 + actA(n * 16 + lr, (uW + lg * 4) * 2)) = o;
            }
        }
        __syncthreads();   // (3) ACT1 visible

        // ---- gate reduce ----
        #pragma unroll
        for (int n = 0; n < 4; ++n) {
            pe[n] += __shfl_xor(pe[n], 16);
            pe[n] += __shfl_xor(pe[n], 32);
        }
        if (l < 16) {
            #pragma unroll
            for (int n = 0; n < 4; ++n) ERED[wv * 64 + n * 16 + l] = pe[n];
        }
        __syncthreads();   // (4)
        if (tid < 64) {
            float tot = 0.f;
            #pragma unroll
            for (int w = 0; w < 8; ++w) tot += ERED[w * 64 + tid];
            ES[tid] = (sbase + tid == r) ? 0.f : sigm_f(tot * 0.088388348f);
        }
        __syncthreads();   // (5)

        // ---- mc += m*e ; gemm wx1 (reads ACT1) ----
        #pragma unroll
        for (int n = 0; n < 4; ++n) {
            float en = ES[n * 16 + lr];
            short4v m = *(const short4v*)(ACT1 + actA(n * 16 + lr, (uW + lg * 4) * 2));
            #pragma unroll
            for (int j2 = 0; j2 < 4; ++j2)
                mc[j2] += h2f((unsigned short)m[j2]) * en;
        }
        {
            f32x4 cf[4];
            #pragma unroll
            for (int n = 0; n < 4; ++n) cf[n] = f32x4{0.f, 0.f, 0.f, 0.f};
            #pragma unroll
            for (int n = 0; n < 4; ++n)
                #pragma unroll
                for (int kt = 0; kt < 4; ++kt) {
                    h8 bfr = *(const h8*)(ACT1 + actA(n * 16 + lr, kt * 64 + lg * 16));
                    cf[n] = __builtin_amdgcn_mfma_f32_16x16x32_f16(wf1[kt], bfr, cf[n], 0, 0, 0);
                }
            #pragma unroll
            for (int n = 0; n < 4; ++n) {
                short4v o;
                #pragma unroll
                for (int j2 = 0; j2 < 4; ++j2)
                    o[j2] = (short)f2h(silu_f(cf[n][j2] * EG) * S_ACT);
                *(short4v*)(ACT0 + actA(n * 16 + lr, (uW + lg * 4) * 2)) = o;
            }
        }
        __syncthreads();   // (6) ACT0 visible, ACT1 free

        // ---- gemm wx2: ACT0 -> phi in ACT1 [u][s] ----
        {
            f32x4 cf[4];
            #pragma unroll
            for (int n = 0; n < 4; ++n) cf[n] = f32x4{0.f, 0.f, 0.f, 0.f};
            #pragma unroll
            for (int n = 0; n < 4; ++n)
                #pragma unroll
                for (int kt = 0; kt < 4; ++kt) {
                    h8 bfr = *(const h8*)(ACT0 + actA(n * 16 + lr, kt * 64 + lg * 16));
                    cf[n] = __builtin_amdgcn_mfma_f32_16x16x32_f16(wf2[kt], bfr, cf[n], 0, 0, 0);
                }
            #pragma unroll
            for (int n = 0; n < 4; ++n) {
                int s2 = (n * 16 + lr) * 2;
                #pragma unroll
                for (int j2 = 0; j2 < 4; ++j2)
                    *(unsigned short*)(ACT1 + actP(uW + lg * 4 + j2, s2)) =
                        f2h(silu_f(cf[n][j2] * EG) * S_ACT);
            }
        }
        __syncthreads();   // (7)

        // ---- G-gemm: G[u][wk] += phi[u][s] @ sh[wk][s] ----
        {
            h8 af[2];
            #pragma unroll
            for (int t = 0; t < 2; ++t)
                af[t] = *(const h8*)(ACT1 + actP(uW + lr, t * 64 + lg * 16));
            #pragma unroll
            for (int n = 0; n < 3; ++n)
                #pragma unroll
                for (int t = 0; t < 2; ++t) {
                    h8 bh = *(const h8*)(SHB + shA(n * 16 + lr, t * 64 + lg * 16));
                    g[n] = __builtin_amdgcn_mfma_f32_16x16x32_f16(af[t], bh, g[n], 0, 0, 0);
                }
        }
        __syncthreads();   // (8) end of tile
    }

    // ---- m_i: reduce mc over the 16 s-lanes, unscale 2^8, store ----
    #pragma unroll
    for (int j2 = 0; j2 < 4; ++j2) {
        float x = mc[j2];
        x += __shfl_xor(x, 1); x += __shfl_xor(x, 2);
        x += __shfl_xor(x, 4); x += __shfl_xor(x, 8);
        mc[j2] = x;
    }
    if (lr == 0) {
        float4 s;
        s.x = mc[0] * 256.f; s.y = mc[1] * 256.f;
        s.z = mc[2] * 256.f; s.w = mc[3] * 256.f;
        *(float4*)(m_i + (size_t)bx * 128 + uW + lg * 4) = s;
    }

    // ---- G dump to global (f16, carries phi's 2^-8) ----
    unsigned short* GBl = GB + (size_t)bx * 6144;
    #pragma unroll
    for (int n = 0; n < 3; ++n)
        #pragma unroll
        for (int j2 = 0; j2 < 4; ++j2)
            GBl[(uW + lg * 4 + j2) * 48 + n * 16 + lr] = f2h(g[n][j2]);
}

// ---------------- v_agg = wtp (x) G contraction, wtp LDS-resident ----------------
__global__ __launch_bounds__(256) void k_vagg(
    const unsigned short* __restrict__ GB, const unsigned short* __restrict__ wtpHl,
    float* __restrict__ v_agg)
{
    extern __shared__ char lds2[];
    unsigned short* WL = (unsigned short*)lds2;       // 32768 halves = 64 KB
    float* Gr  = (float*)(lds2 + 65536);              // 6144 f32 = 24 KB
    float* scr = (float*)(lds2 + 90112);              // 240 f32

    const int tid = (int)threadIdx.x;
    const int wg = (int)blockIdx.x;

    for (int i = tid; i < 4096; i += 256)
        ((short8v*)WL)[i] = ((const short8v*)wtpHl)[i];
    __syncthreads();

    const int vk = tid % 48, ug = tid / 48;
    const int vv = vk / 3, kk = vk - vv * 3;
    const int u0 = (ug * 128) / 5, u1 = ((ug + 1) * 128) / 5;

    for (int rr = 0; rr < 8; ++rr) {
        const int row = wg * 8 + rr;
        const unsigned short* Gs = GB + (size_t)row * 6144;
        for (int i = tid; i < 6144; i += 256) Gr[i] = h2f(Gs[i]);
        __syncthreads();
        if (tid < 240) {
            float acc = 0.f;
            for (int u = u0; u < u1; ++u) {
                #pragma unroll
                for (int w = 0; w < 16; ++w)
                    acc = fmaf(h2f(WL[(u * 16 + w) * 16 + vv]), Gr[u * 48 + w * 3 + kk], acc);
            }
            scr[ug * 48 + vk] = acc;
        }
        __syncthreads();
        if (tid < 48) {
            float tot = scr[tid] + scr[48 + tid] + scr[96 + tid] + scr[144 + tid] + scr[192 + tid];
            v_agg[(size_t)row * 48 + tid] = tot * 1.1070164e-02f;  // 2^8/(sqrt(2048)*511)
        }
        __syncthreads();
    }
}

// ---------------- per-node update: ph MLP, residuals, f16 h mirror ----------------
__global__ __launch_bounds__(128) void k_node_upd(
    const float* __restrict__ m_i, const float* __restrict__ v_agg,
    const float* __restrict__ wh1, const float* __restrict__ wh2,
    const float* __restrict__ wh_out, float* __restrict__ h,
    unsigned short* __restrict__ hfm, float* __restrict__ v)
{
    const int nx = (int)blockIdx.x;
    const int tid = (int)threadIdx.x;
    __shared__ float cat[192], t1[128], t2[128];
    if (tid < 128) cat[tid] = m_i[(size_t)nx * 128 + tid];
    if (tid < 64) cat[128 + tid] = h[(size_t)nx * 64 + tid];
    __syncthreads();
    {
        float acc = 0.f;
        for (int j = 0; j < 192; ++j) acc = fmaf(cat[j], wh1[j * 128 + tid], acc);
        t1[tid] = silu_f(acc * 0.072168784f);
    }
    __syncthreads();
    {
        float acc = 0.f;
        for (int j = 0; j < 128; ++j) acc = fmaf(t1[j], wh2[j * 128 + tid], acc);
        t2[tid] = silu_f(acc * 0.088388348f);
    }
    __syncthreads();
    if (tid < 64) {
        float acc = 0.f;
        for (int j = 0; j < 128; ++j) acc = fmaf(t2[j], wh_out[j * 64 + tid], acc);
        float hn = acc * 0.088388348f + cat[128 + tid];
        h[(size_t)nx * 64 + tid] = hn;
        hfm[(size_t)nx * 64 + tid] = f2h(hn);
    }
    if (tid < 48) v[(size_t)nx * 48 + tid] += v_agg[(size_t)nx * 48 + tid];
}

// ---------------- readout ----------------
__global__ __launch_bounds__(64) void k_readout(
    const float* __restrict__ v, const float* __restrict__ h,
    const float* __restrict__ vec_in, const float* __restrict__ wsM,
    const float* __restrict__ wvM, const float* __restrict__ w_out,
    const float* __restrict__ b_out, float* __restrict__ out)
{
    const int nx = (int)blockIdx.x;
    const int j = (int)threadIdx.x;
    __shared__ float sm[64];
    const float* hn = h + (size_t)nx * 64;
    float acc = 0.f;
    for (int f = 0; f < 64; ++f) acc = fmaf(hn[f], wsM[f * 64 + j], acc);
    acc *= 0.125f;
    float mx = acc;
    #pragma unroll
    for (int off = 32; off; off >>= 1) mx = fmaxf(mx, __shfl_xor(mx, off));
    float e = __expf(acc - mx);
    float ssum = e;
    #pragma unroll
    for (int off = 32; off; off >>= 1) ssum += __shfl_xor(ssum, off);
    sm[j] = e / ssum;
    __syncthreads();
    float o = b_out[j];
    for (int i = 0; i < 64; ++i) o = fmaf(sm[i], w_out[i * 64 + j], o);
    out[2 * 512 * 24 + (size_t)nx * 64 + j] = o;
    if (j < 24) {
        int w = j / 3, k = j - w * 3;
        float a2 = 0.f;
        #pragma unroll
        for (int c = 0; c < 16; ++c)
            a2 = fmaf(v[(size_t)nx * 48 + c * 3 + k], wvM[c * 8 + w], a2);
        out[(size_t)nx * 24 + j] = a2 * 0.25f - vec_in[(size_t)nx * 3 + k];
    }
}

// ---------------- launch ----------------
extern "C" void kernel_launch(void* const* d_in, const int* in_sizes, int n_in,
                              void* d_out, int out_size, void* d_ws, size_t ws_size,
                              hipStream_t stream)
{
    (void)in_sizes; (void)n_in; (void)out_size; (void)ws_size;
    const float* x      = (const float*)d_in[0];
    const float* we1    = (const float*)d_in[1];
    const float* we2    = (const float*)d_in[2];
    const float* wx1    = (const float*)d_in[3];
    const float* wx2    = (const float*)d_in[4];
    const float* winf   = (const float*)d_in[5];
    const float* wtp    = (const float*)d_in[6];
    const float* wh1    = (const float*)d_in[7];
    const float* wh2    = (const float*)d_in[8];
    const float* wh_out = (const float*)d_in[9];
    const float* wsM    = (const float*)d_in[10];
    const float* wvM    = (const float*)d_in[11];
    const float* w_out  = (const float*)d_in[12];
    const float* b_out  = (const float*)d_in[13];
    float* out = (float*)d_out;
    float* W = (float*)d_ws;

    float* VEC_IN = W;                                       // 3072 used
    float* V      = W + 4096;                                // 49152
    float* H      = W + 53248;                               // 65536
    float* PR     = W + 118784;                              // 131072
    float* MI     = W + 249856;                              // 131072
    float* VAGG   = W + 380928;                              // 49152
    unsigned short* GB   = (unsigned short*)(W + 430080);    // 6,291,456 halves (12 MB)
    unsigned short* HF16 = (unsigned short*)(W + 3575808);   // 65536 halves
    unsigned short* WT   = (unsigned short*)(W + 3608576);   // 147456 halves
    unsigned short* W1Tp = (unsigned short*)(W + 3682304);   // 36864 halves
    unsigned short* WTPH = (unsigned short*)(W + 3700736);   // 98304 halves

    hipFuncSetAttribute((const void*)k_edge,
                        hipFuncAttributeMaxDynamicSharedMemorySize, 57600);
    hipFuncSetAttribute((const void*)k_vagg,
                        hipFuncAttributeMaxDynamicSharedMemorySize, 91072);

    k_init<<<2, 256, 0, stream>>>(x, VEC_IN, V, H, HF16);
    k_prep<<<1104, 256, 0, stream>>>(we1, we2, wx1, wx2, wtp, WT, W1Tp, WTPH);
    for (int l = 0; l < 3; ++l) {
        k_node_pre<<<1024, 128, 0, stream>>>(H, we1 + l * 18432, PR);
        k_edge<<<1024, 512, 57600, stream>>>(V, PR, HF16,
            WT + l * 49152, W1Tp + l * 12288, winf + l * 128, MI, GB);
        k_vagg<<<128, 256, 91072, stream>>>(GB, WTPH + l * 32768, VAGG);
        k_node_upd<<<1024, 128, 0, stream>>>(MI, VAGG, wh1 + l * 24576,
            wh2 + l * 16384, wh_out + l * 8192, H, HF16, V);
    }
    k_readout<<<1024, 64, 0, stream>>>(V, H, VEC_IN, wsM, wvM, w_out, b_out, out);
}

// Round 6
// 1117.820 us; speedup vs baseline: 5.8768x; 1.0777x over previous
//
#include <hip/hip_runtime.h>

#define NN 512

typedef short short4v __attribute__((ext_vector_type(4)));
typedef short short8v __attribute__((ext_vector_type(8)));
typedef float f32x4 __attribute__((ext_vector_type(4)));
typedef _Float16 h8 __attribute__((ext_vector_type(8)));

__device__ __forceinline__ float silu_f(float x) { return x / (1.0f + __expf(-x)); }
__device__ __forceinline__ float sigm_f(float x) { return 1.0f / (1.0f + __expf(-x)); }
__device__ __forceinline__ unsigned short f2h(float f) {
    union { _Float16 h; unsigned short s; } u; u.h = (_Float16)f; return u.s;
}
__device__ __forceinline__ float h2f(unsigned short s) {
    union { unsigned short s; _Float16 h; } u; u.s = s; return (float)u.h;
}

// LDS byte-address helpers (XOR swizzle: bank-conflict-free MFMA frag reads)
__device__ __forceinline__ int actA(int s, int kbyte) {  // [s 64][k 128] f16, 256B rows
    return s * 256 + (kbyte ^ ((s & 7) << 4));
}
__device__ __forceinline__ int actP(int u, int sbyte) {  // [u 128][s 64] f16, 128B rows
    return u * 128 + (sbyte ^ ((u & 7) << 4));
}
__device__ __forceinline__ int shA(int wk, int sbyte) {  // [wk 48][s 64] f16, 128B rows
    return wk * 128 + (sbyte ^ ((wk & 7) << 4));
}

// ---------------- init: mean-center x, broadcast v0, h0 = 1 (f32 + f16) ----------------
__global__ void k_init(const float* __restrict__ x, float* __restrict__ vec_in,
                       float* __restrict__ v, float* __restrict__ h,
                       unsigned short* __restrict__ hf)
{
    const int b = (int)blockIdx.x;
    const int tid = (int)threadIdx.x;
    __shared__ float red[3 * 256];
    float s0 = 0.f, s1 = 0.f, s2 = 0.f;
    for (int n = tid; n < NN; n += 256) {
        s0 += x[(b * NN + n) * 3 + 0];
        s1 += x[(b * NN + n) * 3 + 1];
        s2 += x[(b * NN + n) * 3 + 2];
    }
    red[tid] = s0; red[256 + tid] = s1; red[512 + tid] = s2;
    __syncthreads();
    for (int off = 128; off; off >>= 1) {
        if (tid < off) {
            red[tid] += red[tid + off];
            red[256 + tid] += red[256 + tid + off];
            red[512 + tid] += red[512 + tid + off];
        }
        __syncthreads();
    }
    const float m0 = red[0] * (1.f / 512.f);
    const float m1 = red[256] * (1.f / 512.f);
    const float m2 = red[512] * (1.f / 512.f);
    for (int n = tid; n < NN; n += 256) {
        const size_t base = (size_t)b * NN + n;
        float d0 = x[base * 3 + 0] - m0;
        float d1 = x[base * 3 + 1] - m1;
        float d2 = x[base * 3 + 2] - m2;
        vec_in[base * 3 + 0] = d0;
        vec_in[base * 3 + 1] = d1;
        vec_in[base * 3 + 2] = d2;
        #pragma unroll
        for (int c = 0; c < 16; ++c) {
            v[base * 48 + c * 3 + 0] = d0;
            v[base * 48 + c * 3 + 1] = d1;
            v[base * 48 + c * 3 + 2] = d2;
        }
    }
    for (int q = tid; q < NN * 64; q += 256) {
        h[(size_t)b * NN * 64 + q] = 1.0f;
        hf[(size_t)b * NN * 64 + q] = 0x3C00;  // f16 1.0
    }
}

// ------- prep: f16 weights + layer-0 pR (h = 1) ----------------------------------------
__global__ __launch_bounds__(256) void k_prep(
    const float* __restrict__ we1, const float* __restrict__ we2,
    const float* __restrict__ wx1, const float* __restrict__ wx2,
    const float* __restrict__ wtp,
    unsigned short* __restrict__ WT, unsigned short* __restrict__ W1Tp,
    unsigned short* __restrict__ WTPH, float* __restrict__ pR)
{
    int idx = (int)blockIdx.x * 256 + (int)threadIdx.x;
    if (idx < 147456) {                      // 3 layers x 3 gemms x 128x128, transposed
        int l = idx / 49152, r2 = idx % 49152;
        int g = r2 / 16384;
        int u = (r2 >> 7) & 127, k = r2 & 127;
        const float* src = (g == 0 ? we2 : g == 1 ? wx1 : wx2) + l * 16384;
        WT[idx] = f2h(src[k * 128 + u]);
        return;
    }
    int j = idx - 147456;
    if (j < 36864) {                         // 3 x 128 x 96: [l2(16) x1024 | h_send(64) | 0]
        int l = j / 12288, r2 = j % 12288;
        int u = r2 / 96, k = r2 % 96;
        float val = 0.f;
        if (k < 80) val = we1[l * 18432 + k * 128 + u] * (k < 16 ? 1024.0f : 1.0f);
        W1Tp[j] = f2h(val);
        return;
    }
    int q = j - 36864;
    if (q < 98304) { WTPH[q] = f2h(wtp[q]); return; }   // 3 x 2048 x 16 copy
    int t = q - 98304;
    if (t < 16384) {                         // layer-0 pR: h = 1 -> row-sum of recv rows
        int u = t & 127, g = t >> 7;         // g in [0,128), covers 8 nodes each
        float s = 0.f;
        for (int f = 0; f < 64; ++f) s += we1[(80 + f) * 128 + u];
        #pragma unroll
        for (int p = 0; p < 8; ++p) pR[(size_t)(g * 8 + p) * 128 + u] = s;
    }
}

// ---------------- edge kernel: 8 waves, weights in VGPRs, pinned 4 waves/EU ----------------
__global__ __launch_bounds__(512)
__attribute__((amdgpu_waves_per_eu(4, 4)))
void k_edge(
    const float* __restrict__ v, const float* __restrict__ pR,
    const unsigned short* __restrict__ hf, const unsigned short* __restrict__ WTl,
    const unsigned short* __restrict__ W1Tl, const float* __restrict__ winf,
    float* __restrict__ m_i, unsigned short* __restrict__ GB)
{
    extern __shared__ char ldsb[];
    char* B1   = ldsb;                      // 16384: [s][K=96 of 128] f16 swz (l2|h|0)
    char* ACT0 = ldsb + 16384;              // 16384
    char* ACT1 = ldsb + 32768;              // 16384 (also phi [u][s])
    char* SHB  = ldsb + 49152;              // 6144: [wk 48][s 64]
    float* ERED = (float*)(ldsb + 55296);   // 8 x 64 f32
    float* ES   = (float*)(ldsb + 57344);   // 64 f32

    const int tid = (int)threadIdx.x;
    const int bx = (int)blockIdx.x;
    const int b = bx >> 9, r = bx & 511;
    const int wv = tid >> 6, l = tid & 63;
    const int lr = l & 15, lg = l >> 4;
    const int uW = wv * 16;                 // wave's 16-row u-slice
    const int sg = tid >> 3, sub = tid & 7; // geometry: sender row, 1/8 slice

    const float S_L2  = 0x1p-10f;
    const float S_ACT = 0x1p-8f;
    const float EG    = 0x1p+8f * 0.088388348f;   // 2^8 / sqrt(128)

    const float* vb = v + (size_t)b * NN * 48;
    const unsigned short* hb = hf + (size_t)b * NN * 64;

    // ---- persistent weight slices (once per kernel) ----
    h8 w1f[3], wf0[4], wf1[4], wf2[4];
    #pragma unroll
    for (int kt = 0; kt < 3; ++kt)
        w1f[kt] = *(const h8*)(W1Tl + (uW + lr) * 96 + kt * 32 + lg * 8);
    #pragma unroll
    for (int kt = 0; kt < 4; ++kt) {
        wf0[kt] = *(const h8*)(WTl +         (uW + lr) * 128 + kt * 32 + lg * 8);
        wf1[kt] = *(const h8*)(WTl + 16384 + (uW + lr) * 128 + kt * 32 + lg * 8);
        wf2[kt] = *(const h8*)(WTl + 32768 + (uW + lr) * 128 + kt * 32 + lg * 8);
    }
    f32x4 pRv   = *(const f32x4*)(pR + (size_t)bx * 128 + uW + lg * 4);
    f32x4 winfv = *(const f32x4*)(winf + uW + lg * 4);
    float vr6[6];
    #pragma unroll
    for (int q = 0; q < 3; ++q)
        *(float2*)&vr6[q * 2] = *(const float2*)(vb + r * 48 + sub * 6 + q * 2);

    // zero B1 K-pad cols 80..96 (bytes 160..192), written once
    *(float*)(B1 + sg * 256 + ((160 + sub * 4) ^ ((sg & 7) << 4))) = 0.f;

    f32x4 g[3];
    f32x4 mc = {0.f, 0.f, 0.f, 0.f};
    #pragma unroll
    for (int n = 0; n < 3; ++n) g[n] = f32x4{0.f, 0.f, 0.f, 0.f};

    for (int T = 0; T < 8; ++T) {
        const int sbase = T * 64;
        const int sid = sbase + sg;

        // ---- geometry + h staging (self-edge: sh=0 naturally, e masked) ----
        {
            float sv[6];
            #pragma unroll
            for (int q = 0; q < 3; ++q)
                *(float2*)&sv[q * 2] = *(const float2*)(vb + sid * 48 + sub * 6 + q * 2);
            h8 hv = *(const h8*)(hb + sid * 64 + sub * 8);
            unsigned short lh[2];
            #pragma unroll
            for (int cl = 0; cl < 2; ++cl) {
                float d0 = vr6[cl * 3 + 0] - sv[cl * 3 + 0];
                float d1 = vr6[cl * 3 + 1] - sv[cl * 3 + 1];
                float d2 = vr6[cl * 3 + 2] - sv[cl * 3 + 2];
                float l2 = d0 * d0 + d1 * d1 + d2 * d2;
                float len = sqrtf(fmaxf(l2, 1e-20f));
                float fs = 1.7320508f / (1.0f + len);
                int wk = (sub * 2 + cl) * 3;
                *(unsigned short*)(SHB + shA(wk + 0, sg * 2)) = f2h(d0 * fs);
                *(unsigned short*)(SHB + shA(wk + 1, sg * 2)) = f2h(d1 * fs);
                *(unsigned short*)(SHB + shA(wk + 2, sg * 2)) = f2h(d2 * fs);
                lh[cl] = f2h(l2 * S_L2);
            }
            *(unsigned*)(B1 + sg * 256 + ((sub * 4) ^ ((sg & 7) << 4))) =
                (unsigned)lh[0] | ((unsigned)lh[1] << 16);
            *(h8*)(B1 + sg * 256 + ((32 + sub * 16) ^ ((sg & 7) << 4))) = hv;
        }
        __syncthreads();   // (1)

        // ---- stage 1: a1 = silu((l2@we1l2 + h_s@we1h + pR)/12), K=96 MFMA ----
        #pragma unroll
        for (int n = 0; n < 4; ++n) {
            f32x4 acc = pRv;
            #pragma unroll
            for (int kt = 0; kt < 3; ++kt) {
                h8 bl = *(const h8*)(B1 + actA(n * 16 + lr, kt * 64 + lg * 16));
                acc = __builtin_amdgcn_mfma_f32_16x16x32_f16(w1f[kt], bl, acc, 0, 0, 0);
            }
            short4v o;
            #pragma unroll
            for (int j2 = 0; j2 < 4; ++j2)
                o[j2] = (short)f2h(silu_f(acc[j2] * (1.0f / 12.0f)) * S_ACT);
            *(short4v*)(ACT0 + actA(n * 16 + lr, (uW + lg * 4) * 2)) = o;
        }
        __syncthreads();   // (2)

        float pe[4];
        // ---- gemm we2: ACT0 -> ACT1 (m_ij) + phi_inf partials ----
        #pragma unroll
        for (int n = 0; n < 4; ++n) {
            f32x4 cf = {0.f, 0.f, 0.f, 0.f};
            #pragma unroll
            for (int kt = 0; kt < 4; ++kt) {
                h8 bfr = *(const h8*)(ACT0 + actA(n * 16 + lr, kt * 64 + lg * 16));
                cf = __builtin_amdgcn_mfma_f32_16x16x32_f16(wf0[kt], bfr, cf, 0, 0, 0);
            }
            float p = 0.f;
            short4v o;
            #pragma unroll
            for (int j2 = 0; j2 < 4; ++j2) {
                float a = silu_f(cf[j2] * EG);
                p += a * winfv[j2];
                o[j2] = (short)f2h(a * S_ACT);
            }
            pe[n] = p;
            *(short4v*)(ACT1 + actA(n * 16 + lr, (uW + lg * 4) * 2)) = o;
        }
        // gate partials (register-only path, no barrier needed yet)
        #pragma unroll
        for (int n = 0; n < 4; ++n) {
            pe[n] += __shfl_xor(pe[n], 16);
            pe[n] += __shfl_xor(pe[n], 32);
        }
        if (l < 16) {
            #pragma unroll
            for (int n = 0; n < 4; ++n) ERED[wv * 64 + n * 16 + l] = pe[n];
        }
        __syncthreads();   // (3) ACT1 + ERED visible
        if (tid < 64) {
            float tot = 0.f;
            #pragma unroll
            for (int w = 0; w < 8; ++w) tot += ERED[w * 64 + tid];
            ES[tid] = (sbase + tid == r) ? 0.f : sigm_f(tot * 0.088388348f);
        }
        __syncthreads();   // (4) ES visible

        // ---- mc += m*e ; gemm wx1 (reads ACT1) -> ACT0 ----
        #pragma unroll
        for (int n = 0; n < 4; ++n) {
            float en = ES[n * 16 + lr];
            short4v m = *(const short4v*)(ACT1 + actA(n * 16 + lr, (uW + lg * 4) * 2));
            #pragma unroll
            for (int j2 = 0; j2 < 4; ++j2)
                mc[j2] += h2f((unsigned short)m[j2]) * en;
        }
        #pragma unroll
        for (int n = 0; n < 4; ++n) {
            f32x4 cf = {0.f, 0.f, 0.f, 0.f};
            #pragma unroll
            for (int kt = 0; kt < 4; ++kt) {
                h8 bfr = *(const h8*)(ACT1 + actA(n * 16 + lr, kt * 64 + lg * 16));
                cf = __builtin_amdgcn_mfma_f32_16x16x32_f16(wf1[kt], bfr, cf, 0, 0, 0);
            }
            short4v o;
            #pragma unroll
            for (int j2 = 0; j2 < 4; ++j2)
                o[j2] = (short)f2h(silu_f(cf[j2] * EG) * S_ACT);
            *(short4v*)(ACT0 + actA(n * 16 + lr, (uW + lg * 4) * 2)) = o;
        }
        __syncthreads();   // (5) ACT0 visible, ACT1 free

        // ---- gemm wx2: ACT0 -> phi in ACT1 [u][s] ----
        #pragma unroll
        for (int n = 0; n < 4; ++n) {
            f32x4 cf = {0.f, 0.f, 0.f, 0.f};
            #pragma unroll
            for (int kt = 0; kt < 4; ++kt) {
                h8 bfr = *(const h8*)(ACT0 + actA(n * 16 + lr, kt * 64 + lg * 16));
                cf = __builtin_amdgcn_mfma_f32_16x16x32_f16(wf2[kt], bfr, cf, 0, 0, 0);
            }
            int s2 = (n * 16 + lr) * 2;
            #pragma unroll
            for (int j2 = 0; j2 < 4; ++j2)
                *(unsigned short*)(ACT1 + actP(uW + lg * 4 + j2, s2)) =
                    f2h(silu_f(cf[j2] * EG) * S_ACT);
        }
        __syncthreads();   // (6)

        // ---- G-gemm: G[u][wk] += phi[u][s] @ sh[wk][s] ----
        {
            h8 af[2];
            #pragma unroll
            for (int t = 0; t < 2; ++t)
                af[t] = *(const h8*)(ACT1 + actP(uW + lr, t * 64 + lg * 16));
            #pragma unroll
            for (int n = 0; n < 3; ++n)
                #pragma unroll
                for (int t = 0; t < 2; ++t) {
                    h8 bh = *(const h8*)(SHB + shA(n * 16 + lr, t * 64 + lg * 16));
                    g[n] = __builtin_amdgcn_mfma_f32_16x16x32_f16(af[t], bh, g[n], 0, 0, 0);
                }
        }
        __syncthreads();   // (7) end of tile
    }

    // ---- m_i: reduce mc over the 16 s-lanes, unscale 2^8, store ----
    #pragma unroll
    for (int j2 = 0; j2 < 4; ++j2) {
        float x = mc[j2];
        x += __shfl_xor(x, 1); x += __shfl_xor(x, 2);
        x += __shfl_xor(x, 4); x += __shfl_xor(x, 8);
        mc[j2] = x;
    }
    if (lr == 0) {
        float4 s;
        s.x = mc[0] * 256.f; s.y = mc[1] * 256.f;
        s.z = mc[2] * 256.f; s.w = mc[3] * 256.f;
        *(float4*)(m_i + (size_t)bx * 128 + uW + lg * 4) = s;
    }

    // ---- G -> LDS f32, then fully-coalesced packed dword dump ----
    float* Gd = (float*)ldsb;   // 6144 f32 over B1+ACT0 (free now)
    #pragma unroll
    for (int n = 0; n < 3; ++n)
        #pragma unroll
        for (int j2 = 0; j2 < 4; ++j2)
            Gd[(uW + lg * 4 + j2) * 48 + n * 16 + lr] = g[n][j2];
    __syncthreads();
    unsigned* GB32 = (unsigned*)(GB + (size_t)bx * 6144);
    #pragma unroll
    for (int k2 = 0; k2 < 6; ++k2) {
        int i = k2 * 512 + tid;          // 3072 dwords
        int u = i / 24, c = (i - u * 24) * 2;
        unsigned short a = f2h(Gd[u * 48 + c]);
        unsigned short bq = f2h(Gd[u * 48 + c + 1]);
        GB32[i] = (unsigned)a | ((unsigned)bq << 16);
    }
}

// ---------------- v_agg = wtp (x) G contraction, wtp LDS-resident ----------------
__global__ __launch_bounds__(256) void k_vagg(
    const unsigned short* __restrict__ GB, const unsigned short* __restrict__ wtpHl,
    float* __restrict__ v_agg)
{
    extern __shared__ char lds2[];
    unsigned short* WL = (unsigned short*)lds2;       // 32768 halves = 64 KB
    float* Gr  = (float*)(lds2 + 65536);              // 6144 f32 = 24 KB
    float* scr = (float*)(lds2 + 90112);              // 240 f32

    const int tid = (int)threadIdx.x;
    const int wg = (int)blockIdx.x;

    for (int i = tid; i < 4096; i += 256)
        ((short8v*)WL)[i] = ((const short8v*)wtpHl)[i];
    __syncthreads();

    const int vk = tid % 48, ug = tid / 48;
    const int vv = vk / 3, kk = vk - vv * 3;
    const int u0 = (ug * 128) / 5, u1 = ((ug + 1) * 128) / 5;

    for (int rr = 0; rr < 4; ++rr) {
        const int row = wg * 4 + rr;
        const unsigned* Gs32 = (const unsigned*)(GB + (size_t)row * 6144);
        for (int i = tid; i < 3072; i += 256) {
            unsigned d = Gs32[i];
            Gr[2 * i]     = h2f((unsigned short)(d & 0xFFFF));
            Gr[2 * i + 1] = h2f((unsigned short)(d >> 16));
        }
        __syncthreads();
        if (tid < 240) {
            float acc = 0.f;
            for (int u = u0; u < u1; ++u) {
                #pragma unroll
                for (int w = 0; w < 16; ++w)
                    acc = fmaf(h2f(WL[(u * 16 + w) * 16 + vv]), Gr[u * 48 + w * 3 + kk], acc);
            }
            scr[ug * 48 + vk] = acc;
        }
        __syncthreads();
        if (tid < 48) {
            float tot = scr[tid] + scr[48 + tid] + scr[96 + tid] + scr[144 + tid] + scr[192 + tid];
            v_agg[(size_t)row * 48 + tid] = tot * 1.1070164e-02f;  // 2^8/(sqrt(2048)*511)
        }
        __syncthreads();
    }
}

// ---------------- per-node update: ph MLP, residuals, f16 h mirror, next-layer pR ----------------
__global__ __launch_bounds__(128) void k_node_upd(
    const float* __restrict__ m_i, const float* __restrict__ v_agg,
    const float* __restrict__ wh1, const float* __restrict__ wh2,
    const float* __restrict__ wh_out, const float* __restrict__ we1n,
    float* __restrict__ h, unsigned short* __restrict__ hfm,
    float* __restrict__ v, float* __restrict__ pR)
{
    const int nx = (int)blockIdx.x;
    const int tid = (int)threadIdx.x;
    __shared__ float cat[192], t1[128], t2[128], hl2[64];
    if (tid < 128) cat[tid] = m_i[(size_t)nx * 128 + tid];
    if (tid < 64) cat[128 + tid] = h[(size_t)nx * 64 + tid];
    __syncthreads();
    {
        float acc = 0.f;
        for (int j = 0; j < 192; ++j) acc = fmaf(cat[j], wh1[j * 128 + tid], acc);
        t1[tid] = silu_f(acc * 0.072168784f);
    }
    __syncthreads();
    {
        float acc = 0.f;
        for (int j = 0; j < 128; ++j) acc = fmaf(t1[j], wh2[j * 128 + tid], acc);
        t2[tid] = silu_f(acc * 0.088388348f);
    }
    __syncthreads();
    if (tid < 64) {
        float acc = 0.f;
        for (int j = 0; j < 128; ++j) acc = fmaf(t2[j], wh_out[j * 64 + tid], acc);
        float hn = acc * 0.088388348f + cat[128 + tid];
        h[(size_t)nx * 64 + tid] = hn;
        hfm[(size_t)nx * 64 + tid] = f2h(hn);
        hl2[tid] = hn;
    }
    if (tid < 48) v[(size_t)nx * 48 + tid] += v_agg[(size_t)nx * 48 + tid];
    __syncthreads();
    // next layer's pR = h_new @ we1_next recv rows
    {
        float c = 0.f;
        for (int f = 0; f < 64; ++f)
            c = fmaf(hl2[f], we1n[(80 + f) * 128 + tid], c);
        pR[(size_t)nx * 128 + tid] = c;
    }
}

// ---------------- readout ----------------
__global__ __launch_bounds__(64) void k_readout(
    const float* __restrict__ v, const float* __restrict__ h,
    const float* __restrict__ vec_in, const float* __restrict__ wsM,
    const float* __restrict__ wvM, const float* __restrict__ w_out,
    const float* __restrict__ b_out, float* __restrict__ out)
{
    const int nx = (int)blockIdx.x;
    const int j = (int)threadIdx.x;
    __shared__ float sm[64];
    const float* hn = h + (size_t)nx * 64;
    float acc = 0.f;
    for (int f = 0; f < 64; ++f) acc = fmaf(hn[f], wsM[f * 64 + j], acc);
    acc *= 0.125f;
    float mx = acc;
    #pragma unroll
    for (int off = 32; off; off >>= 1) mx = fmaxf(mx, __shfl_xor(mx, off));
    float e = __expf(acc - mx);
    float ssum = e;
    #pragma unroll
    for (int off = 32; off; off >>= 1) ssum += __shfl_xor(ssum, off);
    sm[j] = e / ssum;
    __syncthreads();
    float o = b_out[j];
    for (int i = 0; i < 64; ++i) o = fmaf(sm[i], w_out[i * 64 + j], o);
    out[2 * 512 * 24 + (size_t)nx * 64 + j] = o;
    if (j < 24) {
        int w = j / 3, k = j - w * 3;
        float a2 = 0.f;
        #pragma unroll
        for (int c = 0; c < 16; ++c)
            a2 = fmaf(v[(size_t)nx * 48 + c * 3 + k], wvM[c * 8 + w], a2);
        out[(size_t)nx * 24 + j] = a2 * 0.25f - vec_in[(size_t)nx * 3 + k];
    }
}

// ---------------- launch ----------------
extern "C" void kernel_launch(void* const* d_in, const int* in_sizes, int n_in,
                              void* d_out, int out_size, void* d_ws, size_t ws_size,
                              hipStream_t stream)
{
    (void)in_sizes; (void)n_in; (void)out_size; (void)ws_size;
    const float* x      = (const float*)d_in[0];
    const float* we1    = (const float*)d_in[1];
    const float* we2    = (const float*)d_in[2];
    const float* wx1    = (const float*)d_in[3];
    const float* wx2    = (const float*)d_in[4];
    const float* winf   = (const float*)d_in[5];
    const float* wtp    = (const float*)d_in[6];
    const float* wh1    = (const float*)d_in[7];
    const float* wh2    = (const float*)d_in[8];
    const float* wh_out = (const float*)d_in[9];
    const float* wsM    = (const float*)d_in[10];
    const float* wvM    = (const float*)d_in[11];
    const float* w_out  = (const float*)d_in[12];
    const float* b_out  = (const float*)d_in[13];
    float* out = (float*)d_out;
    float* W = (float*)d_ws;

    float* VEC_IN = W;                                       // 3072 used
    float* V      = W + 4096;                                // 49152
    float* H      = W + 53248;                               // 65536
    float* PR     = W + 118784;                              // 131072
    float* MI     = W + 249856;                              // 131072
    float* VAGG   = W + 380928;                              // 49152
    unsigned short* GB   = (unsigned short*)(W + 430080);    // 6,291,456 halves (12 MB)
    unsigned short* HF16 = (unsigned short*)(W + 3575808);   // 65536 halves
    unsigned short* WT   = (unsigned short*)(W + 3608576);   // 147456 halves
    unsigned short* W1Tp = (unsigned short*)(W + 3682304);   // 36864 halves
    unsigned short* WTPH = (unsigned short*)(W + 3700736);   // 98304 halves

    hipFuncSetAttribute((const void*)k_edge,
                        hipFuncAttributeMaxDynamicSharedMemorySize, 57600);
    hipFuncSetAttribute((const void*)k_vagg,
                        hipFuncAttributeMaxDynamicSharedMemorySize, 91072);

    k_init<<<2, 256, 0, stream>>>(x, VEC_IN, V, H, HF16);
    k_prep<<<1168, 256, 0, stream>>>(we1, we2, wx1, wx2, wtp, WT, W1Tp, WTPH, PR);
    for (int l = 0; l < 3; ++l) {
        k_edge<<<1024, 512, 57600, stream>>>(V, PR, HF16,
            WT + l * 49152, W1Tp + l * 12288, winf + l * 128, MI, GB);
        k_vagg<<<256, 256, 91072, stream>>>(GB, WTPH + l * 32768, VAGG);
        k_node_upd<<<1024, 128, 0, stream>>>(MI, VAGG, wh1 + l * 24576,
            wh2 + l * 16384, wh_out + l * 8192, we1 + ((l + 1) % 3) * 18432,
            H, HF16, V, PR);
    }
    k_readout<<<1024, 64, 0, stream>>>(V, H, VEC_IN, wsM, wvM, w_out, b_out, out);
}

// Round 7
// 1013.416 us; speedup vs baseline: 6.4823x; 1.1030x over previous
//
#include <hip/hip_runtime.h>

#define NN 512

typedef short short4v __attribute__((ext_vector_type(4)));
typedef short short8v __attribute__((ext_vector_type(8)));
typedef float f32x4 __attribute__((ext_vector_type(4)));
typedef _Float16 h8 __attribute__((ext_vector_type(8)));

__device__ __forceinline__ float silu_f(float x) { return x / (1.0f + __expf(-x)); }
__device__ __forceinline__ float sigm_f(float x) { return 1.0f / (1.0f + __expf(-x)); }
__device__ __forceinline__ unsigned short f2h(float f) {
    union { _Float16 h; unsigned short s; } u; u.h = (_Float16)f; return u.s;
}
__device__ __forceinline__ float h2f(unsigned short s) {
    union { unsigned short s; _Float16 h; } u; u.s = s; return (float)u.h;
}

// LDS byte-address helpers (XOR swizzle: bank-conflict-free MFMA frag reads)
__device__ __forceinline__ int b1A(int s, int kbyte) {   // [s 64][K 96] f16, 192B rows
    return s * 192 + (kbyte ^ ((s & 3) << 4));
}
__device__ __forceinline__ int actA(int s, int kbyte) {  // [s 64][k 128] f16, 256B rows
    return s * 256 + (kbyte ^ ((s & 7) << 4));
}
__device__ __forceinline__ int actP(int u, int sbyte) {  // [u 128][s 64] f16, 128B rows
    return u * 128 + (sbyte ^ ((u & 7) << 4));
}
__device__ __forceinline__ int shA(int wk, int sbyte) {  // [wk 48][s 64] f16, 128B rows
    return wk * 128 + (sbyte ^ ((wk & 7) << 4));
}

// ---------------- init: mean-center x, broadcast v0, h0 = 1 (f32 + f16) ----------------
__global__ void k_init(const float* __restrict__ x, float* __restrict__ vec_in,
                       float* __restrict__ v, float* __restrict__ h,
                       unsigned short* __restrict__ hf)
{
    const int b = (int)blockIdx.x;
    const int tid = (int)threadIdx.x;
    __shared__ float red[3 * 256];
    float s0 = 0.f, s1 = 0.f, s2 = 0.f;
    for (int n = tid; n < NN; n += 256) {
        s0 += x[(b * NN + n) * 3 + 0];
        s1 += x[(b * NN + n) * 3 + 1];
        s2 += x[(b * NN + n) * 3 + 2];
    }
    red[tid] = s0; red[256 + tid] = s1; red[512 + tid] = s2;
    __syncthreads();
    for (int off = 128; off; off >>= 1) {
        if (tid < off) {
            red[tid] += red[tid + off];
            red[256 + tid] += red[256 + tid + off];
            red[512 + tid] += red[512 + tid + off];
        }
        __syncthreads();
    }
    const float m0 = red[0] * (1.f / 512.f);
    const float m1 = red[256] * (1.f / 512.f);
    const float m2 = red[512] * (1.f / 512.f);
    for (int n = tid; n < NN; n += 256) {
        const size_t base = (size_t)b * NN + n;
        float d0 = x[base * 3 + 0] - m0;
        float d1 = x[base * 3 + 1] - m1;
        float d2 = x[base * 3 + 2] - m2;
        vec_in[base * 3 + 0] = d0;
        vec_in[base * 3 + 1] = d1;
        vec_in[base * 3 + 2] = d2;
        #pragma unroll
        for (int c = 0; c < 16; ++c) {
            v[base * 48 + c * 3 + 0] = d0;
            v[base * 48 + c * 3 + 1] = d1;
            v[base * 48 + c * 3 + 2] = d2;
        }
    }
    for (int q = tid; q < NN * 64; q += 256) {
        h[(size_t)b * NN * 64 + q] = 1.0f;
        hf[(size_t)b * NN * 64 + q] = 0x3C00;  // f16 1.0
    }
}

// ------- prep: f16 weights + layer-0 pR (h = 1) ----------------------------------------
__global__ __launch_bounds__(256) void k_prep(
    const float* __restrict__ we1, const float* __restrict__ we2,
    const float* __restrict__ wx1, const float* __restrict__ wx2,
    const float* __restrict__ wtp,
    unsigned short* __restrict__ WT, unsigned short* __restrict__ W1Tp,
    unsigned short* __restrict__ WTPH, float* __restrict__ pR)
{
    int idx = (int)blockIdx.x * 256 + (int)threadIdx.x;
    if (idx < 147456) {                      // 3 layers x 3 gemms x 128x128, transposed
        int l = idx / 49152, r2 = idx % 49152;
        int g = r2 / 16384;
        int u = (r2 >> 7) & 127, k = r2 & 127;
        const float* src = (g == 0 ? we2 : g == 1 ? wx1 : wx2) + l * 16384;
        WT[idx] = f2h(src[k * 128 + u]);
        return;
    }
    int j = idx - 147456;
    if (j < 36864) {                         // 3 x 128 x 96: [l2(16) x1024 | h_send(64) | 0]
        int l = j / 12288, r2 = j % 12288;
        int u = r2 / 96, k = r2 % 96;
        float val = 0.f;
        if (k < 80) val = we1[l * 18432 + k * 128 + u] * (k < 16 ? 1024.0f : 1.0f);
        W1Tp[j] = f2h(val);
        return;
    }
    int q = j - 36864;
    if (q < 98304) { WTPH[q] = f2h(wtp[q]); return; }   // 3 x 2048 x 16 copy
    int t = q - 98304;
    if (t < 16384) {                         // layer-0 pR: h = 1 -> row-sum of recv rows
        int u = t & 127, g = t >> 7;         // g in [0,128), covers 8 nodes each
        float s = 0.f;
        for (int f = 0; f < 64; ++f) s += we1[(80 + f) * 128 + u];
        #pragma unroll
        for (int p = 0; p < 8; ++p) pR[(size_t)(g * 8 + p) * 128 + u] = s;
    }
}

// ---------------- edge kernel: 8 waves, 52KB LDS -> 3 WGs/CU ----------------
__global__ __launch_bounds__(512) void k_edge(
    const float* __restrict__ v, const float* __restrict__ pR,
    const unsigned short* __restrict__ hf, const unsigned short* __restrict__ WTl,
    const unsigned short* __restrict__ W1Tl, const float* __restrict__ winf,
    float* __restrict__ m_i, unsigned short* __restrict__ GB)
{
    extern __shared__ char ldsb[];
    char* B1   = ldsb;                      // 12288: [s][K=96] f16 swz (l2|h|0)
    char* ACT0 = ldsb + 12288;              // 16384
    char* ACT1 = ldsb + 28672;              // 16384 (also phi [u][s])
    char* SHB  = ldsb + 45056;              // 6144: [wk 48][s 64]
    float* ERED = (float*)(ldsb + 51200);   // 8 x 64 f32; ES aliases first 64

    const int tid = (int)threadIdx.x;
    const int bx = (int)blockIdx.x;
    const int b = bx >> 9, r = bx & 511;
    const int wv = tid >> 6, l = tid & 63;
    const int lr = l & 15, lg = l >> 4;
    const int uW = wv * 16;                 // wave's 16-row u-slice
    const int sg = tid >> 3, sub = tid & 7; // geometry: sender row, 1/8 slice

    const float S_L2  = 0x1p-10f;
    const float S_ACT = 0x1p-8f;
    const float EG    = 0x1p+8f * 0.088388348f;   // 2^8 / sqrt(128)

    const float* vb = v + (size_t)b * NN * 48;
    const unsigned short* hb = hf + (size_t)b * NN * 64;

    // ---- persistent weight slices (compiler may sink; L2-resident either way) ----
    h8 w1f[3], wf0[4], wf1[4], wf2[4];
    #pragma unroll
    for (int kt = 0; kt < 3; ++kt)
        w1f[kt] = *(const h8*)(W1Tl + (uW + lr) * 96 + kt * 32 + lg * 8);
    #pragma unroll
    for (int kt = 0; kt < 4; ++kt) {
        wf0[kt] = *(const h8*)(WTl +         (uW + lr) * 128 + kt * 32 + lg * 8);
        wf1[kt] = *(const h8*)(WTl + 16384 + (uW + lr) * 128 + kt * 32 + lg * 8);
        wf2[kt] = *(const h8*)(WTl + 32768 + (uW + lr) * 128 + kt * 32 + lg * 8);
    }
    f32x4 pRv   = *(const f32x4*)(pR + (size_t)bx * 128 + uW + lg * 4);
    f32x4 winfv = *(const f32x4*)(winf + uW + lg * 4);
    float vr6[6];
    #pragma unroll
    for (int q = 0; q < 3; ++q)
        *(float2*)&vr6[q * 2] = *(const float2*)(vb + r * 48 + sub * 6 + q * 2);

    // zero B1 K-pad cols 80..96 (bytes 160..192), written once
    *(float*)(B1 + sg * 192 + ((160 + sub * 4) ^ ((sg & 3) << 4))) = 0.f;

    f32x4 g[3];
    f32x4 mc = {0.f, 0.f, 0.f, 0.f};
    #pragma unroll
    for (int n = 0; n < 3; ++n) g[n] = f32x4{0.f, 0.f, 0.f, 0.f};

    for (int T = 0; T < 8; ++T) {
        const int sbase = T * 64;
        const int sid = sbase + sg;

        // ---- geometry + h staging (self-edge: sh=0 naturally, e masked) ----
        {
            float sv[6];
            #pragma unroll
            for (int q = 0; q < 3; ++q)
                *(float2*)&sv[q * 2] = *(const float2*)(vb + sid * 48 + sub * 6 + q * 2);
            h8 hv = *(const h8*)(hb + sid * 64 + sub * 8);
            unsigned short lh[2];
            #pragma unroll
            for (int cl = 0; cl < 2; ++cl) {
                float d0 = vr6[cl * 3 + 0] - sv[cl * 3 + 0];
                float d1 = vr6[cl * 3 + 1] - sv[cl * 3 + 1];
                float d2 = vr6[cl * 3 + 2] - sv[cl * 3 + 2];
                float l2 = d0 * d0 + d1 * d1 + d2 * d2;
                float len = sqrtf(fmaxf(l2, 1e-20f));
                float fs = 1.7320508f / (1.0f + len);
                int wk = (sub * 2 + cl) * 3;
                *(unsigned short*)(SHB + shA(wk + 0, sg * 2)) = f2h(d0 * fs);
                *(unsigned short*)(SHB + shA(wk + 1, sg * 2)) = f2h(d1 * fs);
                *(unsigned short*)(SHB + shA(wk + 2, sg * 2)) = f2h(d2 * fs);
                lh[cl] = f2h(l2 * S_L2);
            }
            *(unsigned*)(B1 + sg * 192 + ((sub * 4) ^ ((sg & 3) << 4))) =
                (unsigned)lh[0] | ((unsigned)lh[1] << 16);
            *(h8*)(B1 + sg * 192 + ((32 + sub * 16) ^ ((sg & 3) << 4))) = hv;
        }
        __syncthreads();   // (1)

        // ---- stage 1: a1 = silu((l2@we1l2 + h_s@we1h + pR)/12), K=96 MFMA ----
        #pragma unroll
        for (int n = 0; n < 4; ++n) {
            f32x4 acc = pRv;
            #pragma unroll
            for (int kt = 0; kt < 3; ++kt) {
                h8 bl = *(const h8*)(B1 + b1A(n * 16 + lr, kt * 64 + lg * 16));
                acc = __builtin_amdgcn_mfma_f32_16x16x32_f16(w1f[kt], bl, acc, 0, 0, 0);
            }
            short4v o;
            #pragma unroll
            for (int j2 = 0; j2 < 4; ++j2)
                o[j2] = (short)f2h(silu_f(acc[j2] * (1.0f / 12.0f)) * S_ACT);
            *(short4v*)(ACT0 + actA(n * 16 + lr, (uW + lg * 4) * 2)) = o;
        }
        __syncthreads();   // (2)

        float pe[4];
        // ---- gemm we2: ACT0 -> ACT1 (m_ij) + phi_inf partials ----
        #pragma unroll
        for (int n = 0; n < 4; ++n) {
            f32x4 cf = {0.f, 0.f, 0.f, 0.f};
            #pragma unroll
            for (int kt = 0; kt < 4; ++kt) {
                h8 bfr = *(const h8*)(ACT0 + actA(n * 16 + lr, kt * 64 + lg * 16));
                cf = __builtin_amdgcn_mfma_f32_16x16x32_f16(wf0[kt], bfr, cf, 0, 0, 0);
            }
            float p = 0.f;
            short4v o;
            #pragma unroll
            for (int j2 = 0; j2 < 4; ++j2) {
                float a = silu_f(cf[j2] * EG);
                p += a * winfv[j2];
                o[j2] = (short)f2h(a * S_ACT);
            }
            pe[n] = p;
            *(short4v*)(ACT1 + actA(n * 16 + lr, (uW + lg * 4) * 2)) = o;
        }
        // gate partials (register-only path, no barrier needed yet)
        #pragma unroll
        for (int n = 0; n < 4; ++n) {
            pe[n] += __shfl_xor(pe[n], 16);
            pe[n] += __shfl_xor(pe[n], 32);
        }
        if (l < 16) {
            #pragma unroll
            for (int n = 0; n < 4; ++n) ERED[wv * 64 + n * 16 + l] = pe[n];
        }
        __syncthreads();   // (3) ACT1 + ERED visible
        if (tid < 64) {
            float tot = 0.f;
            #pragma unroll
            for (int w = 0; w < 8; ++w) tot += ERED[w * 64 + tid];
            float es = (sbase + tid == r) ? 0.f : sigm_f(tot * 0.088388348f);
            ERED[tid] = es;    // ES aliases ERED[0..63]; column-private overwrite
        }
        __syncthreads();   // (4) ES visible

        // ---- mc += m*e ; gemm wx1 (reads ACT1) -> ACT0 ----
        #pragma unroll
        for (int n = 0; n < 4; ++n) {
            float en = ERED[n * 16 + lr];
            short4v m = *(const short4v*)(ACT1 + actA(n * 16 + lr, (uW + lg * 4) * 2));
            #pragma unroll
            for (int j2 = 0; j2 < 4; ++j2)
                mc[j2] += h2f((unsigned short)m[j2]) * en;
        }
        #pragma unroll
        for (int n = 0; n < 4; ++n) {
            f32x4 cf = {0.f, 0.f, 0.f, 0.f};
            #pragma unroll
            for (int kt = 0; kt < 4; ++kt) {
                h8 bfr = *(const h8*)(ACT1 + actA(n * 16 + lr, kt * 64 + lg * 16));
                cf = __builtin_amdgcn_mfma_f32_16x16x32_f16(wf1[kt], bfr, cf, 0, 0, 0);
            }
            short4v o;
            #pragma unroll
            for (int j2 = 0; j2 < 4; ++j2)
                o[j2] = (short)f2h(silu_f(cf[j2] * EG) * S_ACT);
            *(short4v*)(ACT0 + actA(n * 16 + lr, (uW + lg * 4) * 2)) = o;
        }
        __syncthreads();   // (5) ACT0 visible, ACT1 free

        // ---- gemm wx2: ACT0 -> phi in ACT1 [u][s] ----
        #pragma unroll
        for (int n = 0; n < 4; ++n) {
            f32x4 cf = {0.f, 0.f, 0.f, 0.f};
            #pragma unroll
            for (int kt = 0; kt < 4; ++kt) {
                h8 bfr = *(const h8*)(ACT0 + actA(n * 16 + lr, kt * 64 + lg * 16));
                cf = __builtin_amdgcn_mfma_f32_16x16x32_f16(wf2[kt], bfr, cf, 0, 0, 0);
            }
            int s2 = (n * 16 + lr) * 2;
            #pragma unroll
            for (int j2 = 0; j2 < 4; ++j2)
                *(unsigned short*)(ACT1 + actP(uW + lg * 4 + j2, s2)) =
                    f2h(silu_f(cf[j2] * EG) * S_ACT);
        }
        __syncthreads();   // (6)

        // ---- G-gemm: G[u][wk] += phi[u][s] @ sh[wk][s] ----
        {
            h8 af[2];
            #pragma unroll
            for (int t = 0; t < 2; ++t)
                af[t] = *(const h8*)(ACT1 + actP(uW + lr, t * 64 + lg * 16));
            #pragma unroll
            for (int n = 0; n < 3; ++n)
                #pragma unroll
                for (int t = 0; t < 2; ++t) {
                    h8 bh = *(const h8*)(SHB + shA(n * 16 + lr, t * 64 + lg * 16));
                    g[n] = __builtin_amdgcn_mfma_f32_16x16x32_f16(af[t], bh, g[n], 0, 0, 0);
                }
        }
        __syncthreads();   // (7) end of tile
    }

    // ---- m_i: reduce mc over the 16 s-lanes, unscale 2^8, store ----
    #pragma unroll
    for (int j2 = 0; j2 < 4; ++j2) {
        float x = mc[j2];
        x += __shfl_xor(x, 1); x += __shfl_xor(x, 2);
        x += __shfl_xor(x, 4); x += __shfl_xor(x, 8);
        mc[j2] = x;
    }
    if (lr == 0) {
        float4 s;
        s.x = mc[0] * 256.f; s.y = mc[1] * 256.f;
        s.z = mc[2] * 256.f; s.w = mc[3] * 256.f;
        *(float4*)(m_i + (size_t)bx * 128 + uW + lg * 4) = s;
    }

    // ---- G -> LDS f32, then fully-coalesced packed dword dump ----
    float* Gd = (float*)ldsb;   // 6144 f32 over B1+ACT0 (free now)
    #pragma unroll
    for (int n = 0; n < 3; ++n)
        #pragma unroll
        for (int j2 = 0; j2 < 4; ++j2)
            Gd[(uW + lg * 4 + j2) * 48 + n * 16 + lr] = g[n][j2];
    __syncthreads();
    unsigned* GB32 = (unsigned*)(GB + (size_t)bx * 6144);
    #pragma unroll
    for (int k2 = 0; k2 < 6; ++k2) {
        int i = k2 * 512 + tid;          // 3072 dwords
        int u = i / 24, c = (i - u * 24) * 2;
        unsigned short a = f2h(Gd[u * 48 + c]);
        unsigned short bq = f2h(Gd[u * 48 + c + 1]);
        GB32[i] = (unsigned)a | ((unsigned)bq << 16);
    }
}

// ---------------- v_agg = wtp (x) G contraction, wtp LDS-resident ----------------
__global__ __launch_bounds__(256) void k_vagg(
    const unsigned short* __restrict__ GB, const unsigned short* __restrict__ wtpHl,
    float* __restrict__ v_agg)
{
    extern __shared__ char lds2[];
    unsigned short* WL = (unsigned short*)lds2;       // 32768 halves = 64 KB
    float* Gr  = (float*)(lds2 + 65536);              // 6144 f32 = 24 KB
    float* scr = (float*)(lds2 + 90112);              // 240 f32

    const int tid = (int)threadIdx.x;
    const int wg = (int)blockIdx.x;

    for (int i = tid; i < 4096; i += 256)
        ((short8v*)WL)[i] = ((const short8v*)wtpHl)[i];
    __syncthreads();

    const int vk = tid % 48, ug = tid / 48;
    const int vv = vk / 3, kk = vk - vv * 3;
    const int u0 = (ug * 128) / 5, u1 = ((ug + 1) * 128) / 5;

    for (int rr = 0; rr < 4; ++rr) {
        const int row = wg * 4 + rr;
        const unsigned* Gs32 = (const unsigned*)(GB + (size_t)row * 6144);
        for (int i = tid; i < 3072; i += 256) {
            unsigned d = Gs32[i];
            Gr[2 * i]     = h2f((unsigned short)(d & 0xFFFF));
            Gr[2 * i + 1] = h2f((unsigned short)(d >> 16));
        }
        __syncthreads();
        if (tid < 240) {
            float acc = 0.f;
            for (int u = u0; u < u1; ++u) {
                #pragma unroll
                for (int w = 0; w < 16; ++w)
                    acc = fmaf(h2f(WL[(u * 16 + w) * 16 + vv]), Gr[u * 48 + w * 3 + kk], acc);
            }
            scr[ug * 48 + vk] = acc;
        }
        __syncthreads();
        if (tid < 48) {
            float tot = scr[tid] + scr[48 + tid] + scr[96 + tid] + scr[144 + tid] + scr[192 + tid];
            v_agg[(size_t)row * 48 + tid] = tot * 1.1070164e-02f;  // 2^8/(sqrt(2048)*511)
        }
        __syncthreads();
    }
}

// ---------------- per-node update: ph MLP, residuals, f16 h mirror, next-layer pR ----------------
__global__ __launch_bounds__(128) void k_node_upd(
    const float* __restrict__ m_i, const float* __restrict__ v_agg,
    const float* __restrict__ wh1, const float* __restrict__ wh2,
    const float* __restrict__ wh_out, const float* __restrict__ we1n,
    float* __restrict__ h, unsigned short* __restrict__ hfm,
    float* __restrict__ v, float* __restrict__ pR)
{
    const int nx = (int)blockIdx.x;
    const int tid = (int)threadIdx.x;
    __shared__ float cat[192], t1[128], t2[128], hl2[64];
    if (tid < 128) cat[tid] = m_i[(size_t)nx * 128 + tid];
    if (tid < 64) cat[128 + tid] = h[(size_t)nx * 64 + tid];
    __syncthreads();
    {
        float acc = 0.f;
        for (int j = 0; j < 192; ++j) acc = fmaf(cat[j], wh1[j * 128 + tid], acc);
        t1[tid] = silu_f(acc * 0.072168784f);
    }
    __syncthreads();
    {
        float acc = 0.f;
        for (int j = 0; j < 128; ++j) acc = fmaf(t1[j], wh2[j * 128 + tid], acc);
        t2[tid] = silu_f(acc * 0.088388348f);
    }
    __syncthreads();
    if (tid < 64) {
        float acc = 0.f;
        for (int j = 0; j < 128; ++j) acc = fmaf(t2[j], wh_out[j * 64 + tid], acc);
        float hn = acc * 0.088388348f + cat[128 + tid];
        h[(size_t)nx * 64 + tid] = hn;
        hfm[(size_t)nx * 64 + tid] = f2h(hn);
        hl2[tid] = hn;
    }
    if (tid < 48) v[(size_t)nx * 48 + tid] += v_agg[(size_t)nx * 48 + tid];
    __syncthreads();
    // next layer's pR = h_new @ we1_next recv rows
    {
        float c = 0.f;
        for (int f = 0; f < 64; ++f)
            c = fmaf(hl2[f], we1n[(80 + f) * 128 + tid], c);
        pR[(size_t)nx * 128 + tid] = c;
    }
}

// ---------------- readout ----------------
__global__ __launch_bounds__(64) void k_readout(
    const float* __restrict__ v, const float* __restrict__ h,
    const float* __restrict__ vec_in, const float* __restrict__ wsM,
    const float* __restrict__ wvM, const float* __restrict__ w_out,
    const float* __restrict__ b_out, float* __restrict__ out)
{
    const int nx = (int)blockIdx.x;
    const int j = (int)threadIdx.x;
    __shared__ float sm[64];
    const float* hn = h + (size_t)nx * 64;
    float acc = 0.f;
    for (int f = 0; f < 64; ++f) acc = fmaf(hn[f], wsM[f * 64 + j], acc);
    acc *= 0.125f;
    float mx = acc;
    #pragma unroll
    for (int off = 32; off; off >>= 1) mx = fmaxf(mx, __shfl_xor(mx, off));
    float e = __expf(acc - mx);
    float ssum = e;
    #pragma unroll
    for (int off = 32; off; off >>= 1) ssum += __shfl_xor(ssum, off);
    sm[j] = e / ssum;
    __syncthreads();
    float o = b_out[j];
    for (int i = 0; i < 64; ++i) o = fmaf(sm[i], w_out[i * 64 + j], o);
    out[2 * 512 * 24 + (size_t)nx * 64 + j] = o;
    if (j < 24) {
        int w = j / 3, k = j - w * 3;
        float a2 = 0.f;
        #pragma unroll
        for (int c = 0; c < 16; ++c)
            a2 = fmaf(v[(size_t)nx * 48 + c * 3 + k], wvM[c * 8 + w], a2);
        out[(size_t)nx * 24 + j] = a2 * 0.25f - vec_in[(size_t)nx * 3 + k];
    }
}

// ---------------- launch ----------------
extern "C" void kernel_launch(void* const* d_in, const int* in_sizes, int n_in,
                              void* d_out, int out_size, void* d_ws, size_t ws_size,
                              hipStream_t stream)
{
    (void)in_sizes; (void)n_in; (void)out_size; (void)ws_size;
    const float* x      = (const float*)d_in[0];
    const float* we1    = (const float*)d_in[1];
    const float* we2    = (const float*)d_in[2];
    const float* wx1    = (const float*)d_in[3];
    const float* wx2    = (const float*)d_in[4];
    const float* winf   = (const float*)d_in[5];
    const float* wtp    = (const float*)d_in[6];
    const float* wh1    = (const float*)d_in[7];
    const float* wh2    = (const float*)d_in[8];
    const float* wh_out = (const float*)d_in[9];
    const float* wsM    = (const float*)d_in[10];
    const float* wvM    = (const float*)d_in[11];
    const float* w_out  = (const float*)d_in[12];
    const float* b_out  = (const float*)d_in[13];
    float* out = (float*)d_out;
    float* W = (float*)d_ws;

    float* VEC_IN = W;                                       // 3072 used
    float* V      = W + 4096;                                // 49152
    float* H      = W + 53248;                               // 65536
    float* PR     = W + 118784;                              // 131072
    float* MI     = W + 249856;                              // 131072
    float* VAGG   = W + 380928;                              // 49152
    unsigned short* GB   = (unsigned short*)(W + 430080);    // 6,291,456 halves (12 MB)
    unsigned short* HF16 = (unsigned short*)(W + 3575808);   // 65536 halves
    unsigned short* WT   = (unsigned short*)(W + 3608576);   // 147456 halves
    unsigned short* W1Tp = (unsigned short*)(W + 3682304);   // 36864 halves
    unsigned short* WTPH = (unsigned short*)(W + 3700736);   // 98304 halves

    hipFuncSetAttribute((const void*)k_edge,
                        hipFuncAttributeMaxDynamicSharedMemorySize, 53248);
    hipFuncSetAttribute((const void*)k_vagg,
                        hipFuncAttributeMaxDynamicSharedMemorySize, 91072);

    k_init<<<2, 256, 0, stream>>>(x, VEC_IN, V, H, HF16);
    k_prep<<<1168, 256, 0, stream>>>(we1, we2, wx1, wx2, wtp, WT, W1Tp, WTPH, PR);
    for (int l = 0; l < 3; ++l) {
        k_edge<<<1024, 512, 53248, stream>>>(V, PR, HF16,
            WT + l * 49152, W1Tp + l * 12288, winf + l * 128, MI, GB);
        k_vagg<<<256, 256, 91072, stream>>>(GB, WTPH + l * 32768, VAGG);
        k_node_upd<<<1024, 128, 0, stream>>>(MI, VAGG, wh1 + l * 24576,
            wh2 + l * 16384, wh_out + l * 8192, we1 + ((l + 1) % 3) * 18432,
            H, HF16, V, PR);
    }
    k_readout<<<1024, 64, 0, stream>>>(V, H, VEC_IN, wsM, wvM, w_out, b_out, out);
}

// Round 12
// 786.743 us; speedup vs baseline: 8.3499x; 1.2881x over previous
//
#include <hip/hip_runtime.h>

#define NN 512

typedef short short4v __attribute__((ext_vector_type(4)));
typedef short short8v __attribute__((ext_vector_type(8)));
typedef float f32x4 __attribute__((ext_vector_type(4)));
typedef _Float16 h8 __attribute__((ext_vector_type(8)));
typedef __fp16 fp16x2 __attribute__((ext_vector_type(2)));

__device__ __forceinline__ float fast_rcp(float x) { return __builtin_amdgcn_rcpf(x); }
__device__ __forceinline__ float silu_fast(float y) { return y * fast_rcp(1.0f + __expf(-y)); }
__device__ __forceinline__ float sigm_fast(float y) { return fast_rcp(1.0f + __expf(-y)); }
__device__ __forceinline__ unsigned short f2h(float f) {
    union { _Float16 h; unsigned short s; } u; u.h = (_Float16)f; return u.s;
}
__device__ __forceinline__ float h2f(unsigned short s) {
    union { unsigned short s; _Float16 h; } u; u.s = s; return (float)u.h;
}
__device__ __forceinline__ unsigned pk2(float a, float b) {
    union { fp16x2 h; unsigned u; } c; c.h = __builtin_amdgcn_cvt_pkrtz(a, b); return c.u;
}

// LDS byte-address helpers (XOR swizzle: bank-conflict-free MFMA frag reads)
__device__ __forceinline__ int b1A(int s, int kbyte) {   // [s 64][K 96] f16, 192B rows
    return s * 192 + (kbyte ^ ((s & 3) << 4));
}
__device__ __forceinline__ int actA(int s, int kbyte) {  // [s 64][k 128] f16, 256B rows
    return s * 256 + (kbyte ^ ((s & 7) << 4));
}
__device__ __forceinline__ int actP(int u, int sbyte) {  // [u 128][s 64] f16, 128B rows
    return u * 128 + (sbyte ^ ((u & 7) << 4));
}
__device__ __forceinline__ int shA(int wk, int sbyte) {  // [wk 48][s 64] f16, 128B rows
    return wk * 128 + (sbyte ^ ((wk & 7) << 4));
}

// ---------------- init: mean-center x, broadcast v0, h0 = 1 (f32 + f16) ----------------
__global__ void k_init(const float* __restrict__ x, float* __restrict__ vec_in,
                       float* __restrict__ v, float* __restrict__ h,
                       unsigned short* __restrict__ hf)
{
    const int b = (int)blockIdx.x;
    const int tid = (int)threadIdx.x;
    __shared__ float red[3 * 256];
    float s0 = 0.f, s1 = 0.f, s2 = 0.f;
    for (int n = tid; n < NN; n += 256) {
        s0 += x[(b * NN + n) * 3 + 0];
        s1 += x[(b * NN + n) * 3 + 1];
        s2 += x[(b * NN + n) * 3 + 2];
    }
    red[tid] = s0; red[256 + tid] = s1; red[512 + tid] = s2;
    __syncthreads();
    for (int off = 128; off; off >>= 1) {
        if (tid < off) {
            red[tid] += red[tid + off];
            red[256 + tid] += red[256 + tid + off];
            red[512 + tid] += red[512 + tid + off];
        }
        __syncthreads();
    }
    const float m0 = red[0] * (1.f / 512.f);
    const float m1 = red[256] * (1.f / 512.f);
    const float m2 = red[512] * (1.f / 512.f);
    for (int n = tid; n < NN; n += 256) {
        const size_t base = (size_t)b * NN + n;
        float d0 = x[base * 3 + 0] - m0;
        float d1 = x[base * 3 + 1] - m1;
        float d2 = x[base * 3 + 2] - m2;
        vec_in[base * 3 + 0] = d0;
        vec_in[base * 3 + 1] = d1;
        vec_in[base * 3 + 2] = d2;
        #pragma unroll
        for (int c = 0; c < 16; ++c) {
            v[base * 48 + c * 3 + 0] = d0;
            v[base * 48 + c * 3 + 1] = d1;
            v[base * 48 + c * 3 + 2] = d2;
        }
    }
    for (int q = tid; q < NN * 64; q += 256) {
        h[(size_t)b * NN * 64 + q] = 1.0f;
        hf[(size_t)b * NN * 64 + q] = 0x3C00;  // f16 1.0
    }
}

// ------- prep: f16 weights + layer-0 pR (h = 1) ----------------------------------------
__global__ __launch_bounds__(256) void k_prep(
    const float* __restrict__ we1, const float* __restrict__ we2,
    const float* __restrict__ wx1, const float* __restrict__ wx2,
    const float* __restrict__ wtp,
    unsigned short* __restrict__ WT, unsigned short* __restrict__ W1Tp,
    unsigned short* __restrict__ WTPH, float* __restrict__ pR)
{
    int idx = (int)blockIdx.x * 256 + (int)threadIdx.x;
    if (idx < 147456) {                      // 3 layers x 3 gemms x 128x128, transposed
        int l = idx / 49152, r2 = idx % 49152;
        int g = r2 / 16384;
        int u = (r2 >> 7) & 127, k = r2 & 127;
        const float* src = (g == 0 ? we2 : g == 1 ? wx1 : wx2) + l * 16384;
        WT[idx] = f2h(src[k * 128 + u]);
        return;
    }
    int j = idx - 147456;
    if (j < 36864) {                         // 3 x 128 x 96: [l2(16) x1024 | h_send(64) | 0]
        int l = j / 12288, r2 = j % 12288;
        int u = r2 / 96, k = r2 % 96;
        float val = 0.f;
        if (k < 80) val = we1[l * 18432 + k * 128 + u] * (k < 16 ? 1024.0f : 1.0f);
        W1Tp[j] = f2h(val);
        return;
    }
    int q = j - 36864;
    if (q < 98304) { WTPH[q] = f2h(wtp[q]); return; }   // 3 x 2048 x 16 copy
    int t = q - 98304;
    if (t < 16384) {                         // layer-0 pR: h = 1 -> row-sum of recv rows
        int u = t & 127, g = t >> 7;         // g in [0,128), covers 8 nodes each
        float s = 0.f;
        for (int f = 0; f < 64; ++f) s += we1[(80 + f) * 128 + u];
        #pragma unroll
        for (int p = 0; p < 8; ++p) pR[(size_t)(g * 8 + p) * 128 + u] = s;
    }
}

// ---------------- edge kernel: 8 waves, fast-math epilogues, 6 barriers/tile ----------------
__global__ __launch_bounds__(512) void k_edge(
    const float* __restrict__ v, const float* __restrict__ pR,
    const unsigned short* __restrict__ hf, const unsigned short* __restrict__ WTl,
    const unsigned short* __restrict__ W1Tl, const float* __restrict__ winf,
    float* __restrict__ m_i, unsigned short* __restrict__ GB)
{
    extern __shared__ char ldsb[];
    char* B1   = ldsb;                      // 12288: [s][K=96] f16 swz (l2|h|0)
    char* ACT0 = ldsb + 12288;              // 16384
    char* ACT1 = ldsb + 28672;              // 16384 (also phi [u][s])
    char* SHB  = ldsb + 45056;              // 6144: [wk 48][s 64]
    float* ERED = (float*)(ldsb + 51200);   // 8 x 64 f32

    const int tid = (int)threadIdx.x;
    const int bx = (int)blockIdx.x;
    const int b = bx >> 9, r = bx & 511;
    const int wv = tid >> 6, l = tid & 63;
    const int lr = l & 15, lg = l >> 4;
    const int uW = wv * 16;                 // wave's 16-row u-slice
    const int sg = tid >> 3, sub = tid & 7; // geometry: sender row, 1/8 slice

    const float S_L2  = 0x1p-10f;
    const float S_ACT = 0x1p-8f;
    const float E1    = 1.0f / 12.0f;       // x1024 already folded into W1Tp weights
    const float EG    = 0x1p+8f * 0.088388348f;   // 2^8 / sqrt(128)

    const float* vb = v + (size_t)b * NN * 48;
    const unsigned short* hb = hf + (size_t)b * NN * 64;

    // ---- persistent weight slices ----
    h8 w1f[3], wf0[4], wf1[4], wf2[4];
    #pragma unroll
    for (int kt = 0; kt < 3; ++kt)
        w1f[kt] = *(const h8*)(W1Tl + (uW + lr) * 96 + kt * 32 + lg * 8);
    #pragma unroll
    for (int kt = 0; kt < 4; ++kt) {
        wf0[kt] = *(const h8*)(WTl +         (uW + lr) * 128 + kt * 32 + lg * 8);
        wf1[kt] = *(const h8*)(WTl + 16384 + (uW + lr) * 128 + kt * 32 + lg * 8);
        wf2[kt] = *(const h8*)(WTl + 32768 + (uW + lr) * 128 + kt * 32 + lg * 8);
    }
    f32x4 pRv   = *(const f32x4*)(pR + (size_t)bx * 128 + uW + lg * 4);
    f32x4 winfv = *(const f32x4*)(winf + uW + lg * 4);
    float vr6[6];
    #pragma unroll
    for (int q = 0; q < 3; ++q)
        *(float2*)&vr6[q * 2] = *(const float2*)(vb + r * 48 + sub * 6 + q * 2);

    // zero B1 K-pad cols 80..96 (bytes 160..192), written once
    *(float*)(B1 + sg * 192 + ((160 + sub * 4) ^ ((sg & 3) << 4))) = 0.f;

    f32x4 g[3];
    f32x4 mc = {0.f, 0.f, 0.f, 0.f};
    #pragma unroll
    for (int n = 0; n < 3; ++n) g[n] = f32x4{0.f, 0.f, 0.f, 0.f};

    for (int T = 0; T < 8; ++T) {
        const int sbase = T * 64;
        const int sid = sbase + sg;

        // ---- geometry + h staging (self-edge: sh=0 naturally, e masked) ----
        {
            float sv[6];
            #pragma unroll
            for (int q = 0; q < 3; ++q)
                *(float2*)&sv[q * 2] = *(const float2*)(vb + sid * 48 + sub * 6 + q * 2);
            h8 hv = *(const h8*)(hb + sid * 64 + sub * 8);
            unsigned short lh[2];
            #pragma unroll
            for (int cl = 0; cl < 2; ++cl) {
                float d0 = vr6[cl * 3 + 0] - sv[cl * 3 + 0];
                float d1 = vr6[cl * 3 + 1] - sv[cl * 3 + 1];
                float d2 = vr6[cl * 3 + 2] - sv[cl * 3 + 2];
                float l2 = d0 * d0 + d1 * d1 + d2 * d2;
                float len = __builtin_amdgcn_sqrtf(fmaxf(l2, 1e-20f));
                float fs = 1.7320508f * fast_rcp(1.0f + len);
                int wk = (sub * 2 + cl) * 3;
                *(unsigned short*)(SHB + shA(wk + 0, sg * 2)) = f2h(d0 * fs);
                *(unsigned short*)(SHB + shA(wk + 1, sg * 2)) = f2h(d1 * fs);
                *(unsigned short*)(SHB + shA(wk + 2, sg * 2)) = f2h(d2 * fs);
                lh[cl] = f2h(l2 * S_L2);
            }
            *(unsigned*)(B1 + sg * 192 + ((sub * 4) ^ ((sg & 3) << 4))) =
                (unsigned)lh[0] | ((unsigned)lh[1] << 16);
            *(h8*)(B1 + sg * 192 + ((32 + sub * 16) ^ ((sg & 3) << 4))) = hv;
        }
        __syncthreads();   // (1)

        // ---- stage 1: a1 = silu((l2@we1l2 + h_s@we1h + pR)/12), K=96 MFMA ----
        #pragma unroll
        for (int n = 0; n < 4; ++n) {
            f32x4 acc = pRv;
            #pragma unroll
            for (int kt = 0; kt < 3; ++kt) {
                h8 bl = *(const h8*)(B1 + b1A(n * 16 + lr, kt * 64 + lg * 16));
                acc = __builtin_amdgcn_mfma_f32_16x16x32_f16(w1f[kt], bl, acc, 0, 0, 0);
            }
            uint2 st;
            st.x = pk2(silu_fast(acc[0] * E1) * S_ACT, silu_fast(acc[1] * E1) * S_ACT);
            st.y = pk2(silu_fast(acc[2] * E1) * S_ACT, silu_fast(acc[3] * E1) * S_ACT);
            *(uint2*)(ACT0 + actA(n * 16 + lr, (uW + lg * 4) * 2)) = st;
        }
        __syncthreads();   // (2)

        float pe[4];
        float aReg[4][4];   // we2 outputs kept live for the gate's mc accumulation
        // ---- gemm we2: ACT0 -> ACT1 (m_ij) + phi_inf partials ----
        #pragma unroll
        for (int n = 0; n < 4; ++n) {
            f32x4 cf = {0.f, 0.f, 0.f, 0.f};
            #pragma unroll
            for (int kt = 0; kt < 4; ++kt) {
                h8 bfr = *(const h8*)(ACT0 + actA(n * 16 + lr, kt * 64 + lg * 16));
                cf = __builtin_amdgcn_mfma_f32_16x16x32_f16(wf0[kt], bfr, cf, 0, 0, 0);
            }
            float p = 0.f;
            #pragma unroll
            for (int j2 = 0; j2 < 4; ++j2) {
                float a = silu_fast(cf[j2] * EG);
                aReg[n][j2] = a;
                p += a * winfv[j2];
            }
            pe[n] = p;
            uint2 st;
            st.x = pk2(aReg[n][0] * S_ACT, aReg[n][1] * S_ACT);
            st.y = pk2(aReg[n][2] * S_ACT, aReg[n][3] * S_ACT);
            *(uint2*)(ACT1 + actA(n * 16 + lr, (uW + lg * 4) * 2)) = st;
        }
        // cross-lane gate partials -> ERED
        #pragma unroll
        for (int n = 0; n < 4; ++n) {
            pe[n] += __shfl_xor(pe[n], 16);
            pe[n] += __shfl_xor(pe[n], 32);
        }
        if (l < 16) {
            #pragma unroll
            for (int n = 0; n < 4; ++n) ERED[wv * 64 + n * 16 + l] = pe[n];
        }
        __syncthreads();   // (3) ACT1 + ERED visible

        // ---- per-thread gate: e[s] from ERED (broadcast reads); mc from registers ----
        #pragma unroll
        for (int n = 0; n < 4; ++n) {
            float tot = 0.f;
            #pragma unroll
            for (int w = 0; w < 8; ++w) tot += ERED[w * 64 + n * 16 + lr];
            float en = (sbase + n * 16 + lr == r) ? 0.f : sigm_fast(tot * 0.088388348f);
            #pragma unroll
            for (int j2 = 0; j2 < 4; ++j2)
                mc[j2] += aReg[n][j2] * en;
        }
        // ---- gemm wx1 (reads ACT1) -> ACT0 ----
        #pragma unroll
        for (int n = 0; n < 4; ++n) {
            f32x4 cf = {0.f, 0.f, 0.f, 0.f};
            #pragma unroll
            for (int kt = 0; kt < 4; ++kt) {
                h8 bfr = *(const h8*)(ACT1 + actA(n * 16 + lr, kt * 64 + lg * 16));
                cf = __builtin_amdgcn_mfma_f32_16x16x32_f16(wf1[kt], bfr, cf, 0, 0, 0);
            }
            uint2 st;
            st.x = pk2(silu_fast(cf[0] * EG) * S_ACT, silu_fast(cf[1] * EG) * S_ACT);
            st.y = pk2(silu_fast(cf[2] * EG) * S_ACT, silu_fast(cf[3] * EG) * S_ACT);
            *(uint2*)(ACT0 + actA(n * 16 + lr, (uW + lg * 4) * 2)) = st;
        }
        __syncthreads();   // (4) ACT0 visible, ACT1 free

        // ---- gemm wx2: ACT0 -> phi in ACT1 [u][s] ----
        #pragma unroll
        for (int n = 0; n < 4; ++n) {
            f32x4 cf = {0.f, 0.f, 0.f, 0.f};
            #pragma unroll
            for (int kt = 0; kt < 4; ++kt) {
                h8 bfr = *(const h8*)(ACT0 + actA(n * 16 + lr, kt * 64 + lg * 16));
                cf = __builtin_amdgcn_mfma_f32_16x16x32_f16(wf2[kt], bfr, cf, 0, 0, 0);
            }
            int s2 = (n * 16 + lr) * 2;
            #pragma unroll
            for (int j2 = 0; j2 < 4; ++j2)
                *(unsigned short*)(ACT1 + actP(uW + lg * 4 + j2, s2)) =
                    f2h(silu_fast(cf[j2] * EG) * S_ACT);
        }
        __syncthreads();   // (5)

        // ---- G-gemm: G[u][wk] += phi[u][s] @ sh[wk][s] ----
        {
            h8 af[2];
            #pragma unroll
            for (int t = 0; t < 2; ++t)
                af[t] = *(const h8*)(ACT1 + actP(uW + lr, t * 64 + lg * 16));
            #pragma unroll
            for (int n = 0; n < 3; ++n)
                #pragma unroll
                for (int t = 0; t < 2; ++t) {
                    h8 bh = *(const h8*)(SHB + shA(n * 16 + lr, t * 64 + lg * 16));
                    g[n] = __builtin_amdgcn_mfma_f32_16x16x32_f16(af[t], bh, g[n], 0, 0, 0);
                }
        }
        __syncthreads();   // (6) end of tile
    }

    // ---- m_i: reduce mc over the 16 s-lanes, store (mc is RAW m*e — no unscale) ----
    #pragma unroll
    for (int j2 = 0; j2 < 4; ++j2) {
        float x = mc[j2];
        x += __shfl_xor(x, 1); x += __shfl_xor(x, 2);
        x += __shfl_xor(x, 4); x += __shfl_xor(x, 8);
        mc[j2] = x;
    }
    if (lr == 0) {
        float4 s;
        s.x = mc[0]; s.y = mc[1]; s.z = mc[2]; s.w = mc[3];   // FIX: aReg is raw, no x256
        *(float4*)(m_i + (size_t)bx * 128 + uW + lg * 4) = s;
    }

    // ---- G -> LDS f32, then fully-coalesced packed dword dump ----
    float* Gd = (float*)ldsb;   // 6144 f32 over B1+ACT0 (free now)
    #pragma unroll
    for (int n = 0; n < 3; ++n)
        #pragma unroll
        for (int j2 = 0; j2 < 4; ++j2)
            Gd[(uW + lg * 4 + j2) * 48 + n * 16 + lr] = g[n][j2];
    __syncthreads();
    unsigned* GB32 = (unsigned*)(GB + (size_t)bx * 6144);
    #pragma unroll
    for (int k2 = 0; k2 < 6; ++k2) {
        int i = k2 * 512 + tid;          // 3072 dwords
        int u = i / 24, c = (i - u * 24) * 2;
        GB32[i] = pk2(Gd[u * 48 + c], Gd[u * 48 + c + 1]);
    }
}

// ---------------- v_agg = wtp (x) G contraction, wtp LDS-resident ----------------
__global__ __launch_bounds__(256) void k_vagg(
    const unsigned short* __restrict__ GB, const unsigned short* __restrict__ wtpHl,
    float* __restrict__ v_agg)
{
    extern __shared__ char lds2[];
    unsigned short* WL = (unsigned short*)lds2;       // 32768 halves = 64 KB
    float* Gr  = (float*)(lds2 + 65536);              // 6144 f32 = 24 KB
    float* scr = (float*)(lds2 + 90112);              // 240 f32

    const int tid = (int)threadIdx.x;
    const int wg = (int)blockIdx.x;

    for (int i = tid; i < 4096; i += 256)
        ((short8v*)WL)[i] = ((const short8v*)wtpHl)[i];
    __syncthreads();

    const int vk = tid % 48, ug = tid / 48;
    const int vv = vk / 3, kk = vk - vv * 3;
    const int u0 = (ug * 128) / 5, u1 = ((ug + 1) * 128) / 5;

    for (int rr = 0; rr < 4; ++rr) {
        const int row = wg * 4 + rr;
        const unsigned* Gs32 = (const unsigned*)(GB + (size_t)row * 6144);
        for (int i = tid; i < 3072; i += 256) {
            unsigned d = Gs32[i];
            Gr[2 * i]     = h2f((unsigned short)(d & 0xFFFF));
            Gr[2 * i + 1] = h2f((unsigned short)(d >> 16));
        }
        __syncthreads();
        if (tid < 240) {
            float acc = 0.f;
            for (int u = u0; u < u1; ++u) {
                #pragma unroll
                for (int w = 0; w < 16; ++w)
                    acc = fmaf(h2f(WL[(u * 16 + w) * 16 + vv]), Gr[u * 48 + w * 3 + kk], acc);
            }
            scr[ug * 48 + vk] = acc;
        }
        __syncthreads();
        if (tid < 48) {
            float tot = scr[tid] + scr[48 + tid] + scr[96 + tid] + scr[144 + tid] + scr[192 + tid];
            v_agg[(size_t)row * 48 + tid] = tot * 1.1070164e-02f;  // 2^8/(sqrt(2048)*511)
        }
        __syncthreads();
    }
}

// ---------------- per-node update: ph MLP, residuals, f16 h mirror, next-layer pR ----------------
__global__ __launch_bounds__(128) void k_node_upd(
    const float* __restrict__ m_i, const float* __restrict__ v_agg,
    const float* __restrict__ wh1, const float* __restrict__ wh2,
    const float* __restrict__ wh_out, const float* __restrict__ we1n,
    float* __restrict__ h, unsigned short* __restrict__ hfm,
    float* __restrict__ v, float* __restrict__ pR)
{
    const int nx = (int)blockIdx.x;
    const int tid = (int)threadIdx.x;
    __shared__ float cat[192], t1[128], t2[128], hl2[64];
    if (tid < 128) cat[tid] = m_i[(size_t)nx * 128 + tid];
    if (tid < 64) cat[128 + tid] = h[(size_t)nx * 64 + tid];
    __syncthreads();
    {
        float acc = 0.f;
        for (int j = 0; j < 192; ++j) acc = fmaf(cat[j], wh1[j * 128 + tid], acc);
        t1[tid] = silu_fast(acc * 0.072168784f);
    }
    __syncthreads();
    {
        float acc = 0.f;
        for (int j = 0; j < 128; ++j) acc = fmaf(t1[j], wh2[j * 128 + tid], acc);
        t2[tid] = silu_fast(acc * 0.088388348f);
    }
    __syncthreads();
    if (tid < 64) {
        float acc = 0.f;
        for (int j = 0; j < 128; ++j) acc = fmaf(t2[j], wh_out[j * 64 + tid], acc);
        float hn = acc * 0.088388348f + cat[128 + tid];
        h[(size_t)nx * 64 + tid] = hn;
        hfm[(size_t)nx * 64 + tid] = f2h(hn);
        hl2[tid] = hn;
    }
    if (tid < 48) v[(size_t)nx * 48 + tid] += v_agg[(size_t)nx * 48 + tid];
    __syncthreads();
    // next layer's pR = h_new @ we1_next recv rows
    {
        float c = 0.f;
        for (int f = 0; f < 64; ++f)
            c = fmaf(hl2[f], we1n[(80 + f) * 128 + tid], c);
        pR[(size_t)nx * 128 + tid] = c;
    }
}

// ---------------- readout ----------------
__global__ __launch_bounds__(64) void k_readout(
    const float* __restrict__ v, const float* __restrict__ h,
    const float* __restrict__ vec_in, const float* __restrict__ wsM,
    const float* __restrict__ wvM, const float* __restrict__ w_out,
    const float* __restrict__ b_out, float* __restrict__ out)
{
    const int nx = (int)blockIdx.x;
    const int j = (int)threadIdx.x;
    __shared__ float sm[64];
    const float* hn = h + (size_t)nx * 64;
    float acc = 0.f;
    for (int f = 0; f < 64; ++f) acc = fmaf(hn[f], wsM[f * 64 + j], acc);
    acc *= 0.125f;
    float mx = acc;
    #pragma unroll
    for (int off = 32; off; off >>= 1) mx = fmaxf(mx, __shfl_xor(mx, off));
    float e = __expf(acc - mx);
    float ssum = e;
    #pragma unroll
    for (int off = 32; off; off >>= 1) ssum += __shfl_xor(ssum, off);
    sm[j] = e / ssum;
    __syncthreads();
    float o = b_out[j];
    for (int i = 0; i < 64; ++i) o = fmaf(sm[i], w_out[i * 64 + j], o);
    out[2 * 512 * 24 + (size_t)nx * 64 + j] = o;
    if (j < 24) {
        int w = j / 3, k = j - w * 3;
        float a2 = 0.f;
        #pragma unroll
        for (int c = 0; c < 16; ++c)
            a2 = fmaf(v[(size_t)nx * 48 + c * 3 + k], wvM[c * 8 + w], a2);
        out[(size_t)nx * 24 + j] = a2 * 0.25f - vec_in[(size_t)nx * 3 + k];
    }
}

// ---------------- launch ----------------
extern "C" void kernel_launch(void* const* d_in, const int* in_sizes, int n_in,
                              void* d_out, int out_size, void* d_ws, size_t ws_size,
                              hipStream_t stream)
{
    (void)in_sizes; (void)n_in; (void)out_size; (void)ws_size;
    const float* x      = (const float*)d_in[0];
    const float* we1    = (const float*)d_in[1];
    const float* we2    = (const float*)d_in[2];
    const float* wx1    = (const float*)d_in[3];
    const float* wx2    = (const float*)d_in[4];
    const float* winf   = (const float*)d_in[5];
    const float* wtp    = (const float*)d_in[6];
    const float* wh1    = (const float*)d_in[7];
    const float* wh2    = (const float*)d_in[8];
    const float* wh_out = (const float*)d_in[9];
    const float* wsM    = (const float*)d_in[10];
    const float* wvM    = (const float*)d_in[11];
    const float* w_out  = (const float*)d_in[12];
    const float* b_out  = (const float*)d_in[13];
    float* out = (float*)d_out;
    float* W = (float*)d_ws;

    float* VEC_IN = W;                                       // 3072 used
    float* V      = W + 4096;                                // 49152
    float* H      = W + 53248;                               // 65536
    float* PR     = W + 118784;                              // 131072
    float* MI     = W + 249856;                              // 131072
    float* VAGG   = W + 380928;                              // 49152
    unsigned short* GB   = (unsigned short*)(W + 430080);    // 6,291,456 halves (12 MB)
    unsigned short* HF16 = (unsigned short*)(W + 3575808);   // 65536 halves
    unsigned short* WT   = (unsigned short*)(W + 3608576);   // 147456 halves
    unsigned short* W1Tp = (unsigned short*)(W + 3682304);   // 36864 halves
    unsigned short* WTPH = (unsigned short*)(W + 3700736);   // 98304 halves

    hipFuncSetAttribute((const void*)k_edge,
                        hipFuncAttributeMaxDynamicSharedMemorySize, 53248);
    hipFuncSetAttribute((const void*)k_vagg,
                        hipFuncAttributeMaxDynamicSharedMemorySize, 91072);

    k_init<<<2, 256, 0, stream>>>(x, VEC_IN, V, H, HF16);
    k_prep<<<1168, 256, 0, stream>>>(we1, we2, wx1, wx2, wtp, WT, W1Tp, WTPH, PR);
    for (int l = 0; l < 3; ++l) {
        k_edge<<<1024, 512, 53248, stream>>>(V, PR, HF16,
            WT + l * 49152, W1Tp + l * 12288, winf + l * 128, MI, GB);
        k_vagg<<<256, 256, 91072, stream>>>(GB, WTPH + l * 32768, VAGG);
        k_node_upd<<<1024, 128, 0, stream>>>(MI, VAGG, wh1 + l * 24576,
            wh2 + l * 16384, wh_out + l * 8192, we1 + ((l + 1) % 3) * 18432,
            H, HF16, V, PR);
    }
    k_readout<<<1024, 64, 0, stream>>>(V, H, VEC_IN, wsM, wvM, w_out, b_out, out);
}

// Round 13
// 750.857 us; speedup vs baseline: 8.7490x; 1.0478x over previous
//
#include <hip/hip_runtime.h>

#define NN 512

typedef short short4v __attribute__((ext_vector_type(4)));
typedef short short8v __attribute__((ext_vector_type(8)));
typedef float f32x4 __attribute__((ext_vector_type(4)));
typedef _Float16 h8 __attribute__((ext_vector_type(8)));
typedef __fp16 fp16x2 __attribute__((ext_vector_type(2)));

__device__ __forceinline__ float fast_rcp(float x) { return __builtin_amdgcn_rcpf(x); }
__device__ __forceinline__ float silu_fast(float y) { return y * fast_rcp(1.0f + __expf(-y)); }
__device__ __forceinline__ float sigm_fast(float y) { return fast_rcp(1.0f + __expf(-y)); }
__device__ __forceinline__ unsigned short f2h(float f) {
    union { _Float16 h; unsigned short s; } u; u.h = (_Float16)f; return u.s;
}
__device__ __forceinline__ float h2f(unsigned short s) {
    union { unsigned short s; _Float16 h; } u; u.s = s; return (float)u.h;
}
__device__ __forceinline__ unsigned pk2(float a, float b) {
    union { fp16x2 h; unsigned u; } c; c.h = __builtin_amdgcn_cvt_pkrtz(a, b); return c.u;
}

// LDS byte-address helpers (XOR swizzle: bank-conflict-free MFMA frag reads)
__device__ __forceinline__ int b1A(int s, int kbyte) {   // [s 64][K 96] f16, 192B rows
    return s * 192 + (kbyte ^ ((s & 3) << 4));
}
__device__ __forceinline__ int actA(int s, int kbyte) {  // [s 64][k 128] f16, 256B rows
    return s * 256 + (kbyte ^ ((s & 7) << 4));
}
__device__ __forceinline__ int actP(int u, int sbyte) {  // [u 128][s 64] f16, 128B rows
    return u * 128 + (sbyte ^ ((u & 7) << 4));
}
__device__ __forceinline__ int shA(int wk, int sbyte) {  // [wk 48][s 64] f16, 128B rows
    return wk * 128 + (sbyte ^ ((wk & 7) << 4));
}

// ---------------- init: mean-center x, broadcast v0, h0 = 1 (f32 + f16) ----------------
__global__ void k_init(const float* __restrict__ x, float* __restrict__ vec_in,
                       float* __restrict__ v, float* __restrict__ h,
                       unsigned short* __restrict__ hf)
{
    const int b = (int)blockIdx.x;
    const int tid = (int)threadIdx.x;
    __shared__ float red[3 * 256];
    float s0 = 0.f, s1 = 0.f, s2 = 0.f;
    for (int n = tid; n < NN; n += 256) {
        s0 += x[(b * NN + n) * 3 + 0];
        s1 += x[(b * NN + n) * 3 + 1];
        s2 += x[(b * NN + n) * 3 + 2];
    }
    red[tid] = s0; red[256 + tid] = s1; red[512 + tid] = s2;
    __syncthreads();
    for (int off = 128; off; off >>= 1) {
        if (tid < off) {
            red[tid] += red[tid + off];
            red[256 + tid] += red[256 + tid + off];
            red[512 + tid] += red[512 + tid + off];
        }
        __syncthreads();
    }
    const float m0 = red[0] * (1.f / 512.f);
    const float m1 = red[256] * (1.f / 512.f);
    const float m2 = red[512] * (1.f / 512.f);
    for (int n = tid; n < NN; n += 256) {
        const size_t base = (size_t)b * NN + n;
        float d0 = x[base * 3 + 0] - m0;
        float d1 = x[base * 3 + 1] - m1;
        float d2 = x[base * 3 + 2] - m2;
        vec_in[base * 3 + 0] = d0;
        vec_in[base * 3 + 1] = d1;
        vec_in[base * 3 + 2] = d2;
        #pragma unroll
        for (int c = 0; c < 16; ++c) {
            v[base * 48 + c * 3 + 0] = d0;
            v[base * 48 + c * 3 + 1] = d1;
            v[base * 48 + c * 3 + 2] = d2;
        }
    }
    for (int q = tid; q < NN * 64; q += 256) {
        h[(size_t)b * NN * 64 + q] = 1.0f;
        hf[(size_t)b * NN * 64 + q] = 0x3C00;  // f16 1.0
    }
}

// ------- prep: f16 weights + layer-0 pR (h = 1) + f16 winf ------------------------------
__global__ __launch_bounds__(256) void k_prep(
    const float* __restrict__ we1, const float* __restrict__ we2,
    const float* __restrict__ wx1, const float* __restrict__ wx2,
    const float* __restrict__ wtp, const float* __restrict__ winf,
    unsigned short* __restrict__ WT, unsigned short* __restrict__ W1Tp,
    unsigned short* __restrict__ WTPH, float* __restrict__ pR,
    unsigned short* __restrict__ WINFH)
{
    int idx = (int)blockIdx.x * 256 + (int)threadIdx.x;
    if (idx < 147456) {                      // 3 layers x 3 gemms x 128x128, transposed
        int l = idx / 49152, r2 = idx % 49152;
        int g = r2 / 16384;
        int u = (r2 >> 7) & 127, k = r2 & 127;
        const float* src = (g == 0 ? we2 : g == 1 ? wx1 : wx2) + l * 16384;
        WT[idx] = f2h(src[k * 128 + u]);
        return;
    }
    int j = idx - 147456;
    if (j < 36864) {                         // 3 x 128 x 96: [l2(16) x1024 | h_send(64) | 0]
        int l = j / 12288, r2 = j % 12288;
        int u = r2 / 96, k = r2 % 96;
        float val = 0.f;
        if (k < 80) val = we1[l * 18432 + k * 128 + u] * (k < 16 ? 1024.0f : 1.0f);
        W1Tp[j] = f2h(val);
        return;
    }
    int q = j - 36864;
    if (q < 98304) { WTPH[q] = f2h(wtp[q]); return; }   // 3 x 2048 x 16 copy
    int t = q - 98304;
    if (t < 16384) {                         // layer-0 pR: h = 1 -> row-sum of recv rows
        int u = t & 127, g = t >> 7;         // g in [0,128), covers 8 nodes each
        float s = 0.f;
        for (int f = 0; f < 64; ++f) s += we1[(80 + f) * 128 + u];
        #pragma unroll
        for (int p = 0; p < 8; ++p) pR[(size_t)(g * 8 + p) * 128 + u] = s;
        return;
    }
    int w = t - 16384;
    if (w < 384) WINFH[w] = f2h(winf[w]);    // 3 x 128 f16 winf
}

// -------- edge kernel: 8 waves, MFMA gate fused in wx1, 5 barriers/tile, prefetch --------
__global__ __launch_bounds__(512) void k_edge(
    const float* __restrict__ v, const float* __restrict__ pR,
    const unsigned short* __restrict__ hf, const unsigned short* __restrict__ WTl,
    const unsigned short* __restrict__ W1Tl, const unsigned short* __restrict__ winfH,
    float* __restrict__ m_i, unsigned short* __restrict__ GB)
{
    extern __shared__ char ldsb[];
    char* B1   = ldsb;                      // 12288: [s][K=96] f16 swz (l2|h|0)
    char* ACT0 = ldsb + 12288;              // 16384
    char* ACT1 = ldsb + 28672;              // 16384 (also phi [u][s])
    char* SHB  = ldsb + 45056;              // 6144: [wk 48][s 64]

    const int tid = (int)threadIdx.x;
    const int bx = (int)blockIdx.x;
    const int b = bx >> 9, r = bx & 511;
    const int wv = tid >> 6, l = tid & 63;
    const int lr = l & 15, lg = l >> 4;
    const int uW = wv * 16;                 // wave's 16-row u-slice
    const int sg = tid >> 3, sub = tid & 7; // geometry: sender row, 1/8 slice

    const float S_L2  = 0x1p-10f;
    const float S_ACT = 0x1p-8f;
    const float E1    = 1.0f / 12.0f;       // x1024 already folded into W1Tp weights
    const float EG    = 0x1p+8f * 0.088388348f;   // 2^8 / sqrt(128)

    const float* vb = v + (size_t)b * NN * 48;
    const unsigned short* hb = hf + (size_t)b * NN * 64;

    // ---- persistent weight slices ----
    h8 w1f[3], wf0[4], wf1[4], wf2[4], wgf[4];
    #pragma unroll
    for (int kt = 0; kt < 3; ++kt)
        w1f[kt] = *(const h8*)(W1Tl + (uW + lr) * 96 + kt * 32 + lg * 8);
    #pragma unroll
    for (int kt = 0; kt < 4; ++kt) {
        wf0[kt] = *(const h8*)(WTl +         (uW + lr) * 128 + kt * 32 + lg * 8);
        wf1[kt] = *(const h8*)(WTl + 16384 + (uW + lr) * 128 + kt * 32 + lg * 8);
        wf2[kt] = *(const h8*)(WTl + 32768 + (uW + lr) * 128 + kt * 32 + lg * 8);
        wgf[kt] = *(const h8*)(winfH + kt * 32 + lg * 8);   // winf A-frag (rows identical)
    }
    f32x4 pRv = *(const f32x4*)(pR + (size_t)bx * 128 + uW + lg * 4);
    float vr6[6];
    #pragma unroll
    for (int q = 0; q < 3; ++q)
        *(float2*)&vr6[q * 2] = *(const float2*)(vb + r * 48 + sub * 6 + q * 2);

    // zero B1 K-pad cols 80..96 (bytes 160..192), written once
    *(float*)(B1 + sg * 192 + ((160 + sub * 4) ^ ((sg & 3) << 4))) = 0.f;

    f32x4 g[3];
    f32x4 mc = {0.f, 0.f, 0.f, 0.f};
    #pragma unroll
    for (int n = 0; n < 3; ++n) g[n] = f32x4{0.f, 0.f, 0.f, 0.f};

    // ---- prefetch tile 0 geometry operands ----
    float svp[6]; h8 hvp;
    #pragma unroll
    for (int q = 0; q < 3; ++q)
        *(float2*)&svp[q * 2] = *(const float2*)(vb + sg * 48 + sub * 6 + q * 2);
    hvp = *(const h8*)(hb + sg * 64 + sub * 8);

    for (int T = 0; T < 8; ++T) {
        const int sbase = T * 64;

        // ---- geometry (from prefetched regs) + h staging ----
        {
            unsigned short lh[2];
            #pragma unroll
            for (int cl = 0; cl < 2; ++cl) {
                float d0 = vr6[cl * 3 + 0] - svp[cl * 3 + 0];
                float d1 = vr6[cl * 3 + 1] - svp[cl * 3 + 1];
                float d2 = vr6[cl * 3 + 2] - svp[cl * 3 + 2];
                float l2 = d0 * d0 + d1 * d1 + d2 * d2;
                float len = __builtin_amdgcn_sqrtf(fmaxf(l2, 1e-20f));
                float fs = 1.7320508f * fast_rcp(1.0f + len);
                int wk = (sub * 2 + cl) * 3;
                *(unsigned short*)(SHB + shA(wk + 0, sg * 2)) = f2h(d0 * fs);
                *(unsigned short*)(SHB + shA(wk + 1, sg * 2)) = f2h(d1 * fs);
                *(unsigned short*)(SHB + shA(wk + 2, sg * 2)) = f2h(d2 * fs);
                lh[cl] = f2h(l2 * S_L2);
            }
            *(unsigned*)(B1 + sg * 192 + ((sub * 4) ^ ((sg & 3) << 4))) =
                (unsigned)lh[0] | ((unsigned)lh[1] << 16);
            *(h8*)(B1 + sg * 192 + ((32 + sub * 16) ^ ((sg & 3) << 4))) = hvp;
            // issue next tile's loads; they complete under the GEMM phases
            if (T < 7) {
                const int sidn = sbase + 64 + sg;
                #pragma unroll
                for (int q = 0; q < 3; ++q)
                    *(float2*)&svp[q * 2] = *(const float2*)(vb + sidn * 48 + sub * 6 + q * 2);
                hvp = *(const h8*)(hb + sidn * 64 + sub * 8);
            }
        }
        __syncthreads();   // (1)

        // ---- stage 1: a1 = silu((l2@we1l2 + h_s@we1h + pR)/12), K=96 MFMA ----
        #pragma unroll
        for (int n = 0; n < 4; ++n) {
            f32x4 acc = pRv;
            #pragma unroll
            for (int kt = 0; kt < 3; ++kt) {
                h8 bl = *(const h8*)(B1 + b1A(n * 16 + lr, kt * 64 + lg * 16));
                acc = __builtin_amdgcn_mfma_f32_16x16x32_f16(w1f[kt], bl, acc, 0, 0, 0);
            }
            uint2 st;
            st.x = pk2(silu_fast(acc[0] * E1) * S_ACT, silu_fast(acc[1] * E1) * S_ACT);
            st.y = pk2(silu_fast(acc[2] * E1) * S_ACT, silu_fast(acc[3] * E1) * S_ACT);
            *(uint2*)(ACT0 + actA(n * 16 + lr, (uW + lg * 4) * 2)) = st;
        }
        __syncthreads();   // (2)

        float aReg[4][4];   // we2 outputs kept live for the gate's mc accumulation
        // ---- gemm we2: ACT0 -> ACT1 (m_ij) ----
        #pragma unroll
        for (int n = 0; n < 4; ++n) {
            f32x4 cf = {0.f, 0.f, 0.f, 0.f};
            #pragma unroll
            for (int kt = 0; kt < 4; ++kt) {
                h8 bfr = *(const h8*)(ACT0 + actA(n * 16 + lr, kt * 64 + lg * 16));
                cf = __builtin_amdgcn_mfma_f32_16x16x32_f16(wf0[kt], bfr, cf, 0, 0, 0);
            }
            uint2 st;
            #pragma unroll
            for (int j2 = 0; j2 < 4; ++j2) aReg[n][j2] = silu_fast(cf[j2] * EG);
            st.x = pk2(aReg[n][0] * S_ACT, aReg[n][1] * S_ACT);
            st.y = pk2(aReg[n][2] * S_ACT, aReg[n][3] * S_ACT);
            *(uint2*)(ACT1 + actA(n * 16 + lr, (uW + lg * 4) * 2)) = st;
        }
        __syncthreads();   // (3) ACT1 visible

        // ---- gemm wx1 + fused MFMA gate (reuses B-frags): ACT1 -> ACT0; mc += a*e ----
        #pragma unroll
        for (int n = 0; n < 4; ++n) {
            f32x4 cf = {0.f, 0.f, 0.f, 0.f};
            f32x4 cg = {0.f, 0.f, 0.f, 0.f};
            #pragma unroll
            for (int kt = 0; kt < 4; ++kt) {
                h8 bfr = *(const h8*)(ACT1 + actA(n * 16 + lr, kt * 64 + lg * 16));
                cf = __builtin_amdgcn_mfma_f32_16x16x32_f16(wf1[kt], bfr, cf, 0, 0, 0);
                cg = __builtin_amdgcn_mfma_f32_16x16x32_f16(wgf[kt], bfr, cg, 0, 0, 0);
            }
            uint2 st;
            st.x = pk2(silu_fast(cf[0] * EG) * S_ACT, silu_fast(cf[1] * EG) * S_ACT);
            st.y = pk2(silu_fast(cf[2] * EG) * S_ACT, silu_fast(cf[3] * EG) * S_ACT);
            *(uint2*)(ACT0 + actA(n * 16 + lr, (uW + lg * 4) * 2)) = st;
            // gate: cg rows identical (winf replicated); cg holds S_ACT-scaled sum
            float en = (sbase + n * 16 + lr == r) ? 0.f : sigm_fast(cg[0] * EG);
            #pragma unroll
            for (int j2 = 0; j2 < 4; ++j2)
                mc[j2] += aReg[n][j2] * en;
        }
        __syncthreads();   // (4) ACT0 visible, ACT1 free

        // ---- gemm wx2: ACT0 -> phi in ACT1 [u][s] (own-wave rows; no barrier needed) ----
        #pragma unroll
        for (int n = 0; n < 4; ++n) {
            f32x4 cf = {0.f, 0.f, 0.f, 0.f};
            #pragma unroll
            for (int kt = 0; kt < 4; ++kt) {
                h8 bfr = *(const h8*)(ACT0 + actA(n * 16 + lr, kt * 64 + lg * 16));
                cf = __builtin_amdgcn_mfma_f32_16x16x32_f16(wf2[kt], bfr, cf, 0, 0, 0);
            }
            int s2 = (n * 16 + lr) * 2;
            #pragma unroll
            for (int j2 = 0; j2 < 4; ++j2)
                *(unsigned short*)(ACT1 + actP(uW + lg * 4 + j2, s2)) =
                    f2h(silu_fast(cf[j2] * EG) * S_ACT);
        }
        // no block barrier: G-gemm reads only this wave's own phi rows (lgkmcnt suffices)

        // ---- G-gemm: G[u][wk] += phi[u][s] @ sh[wk][s] ----
        {
            h8 af[2];
            #pragma unroll
            for (int t = 0; t < 2; ++t)
                af[t] = *(const h8*)(ACT1 + actP(uW + lr, t * 64 + lg * 16));
            #pragma unroll
            for (int n = 0; n < 3; ++n)
                #pragma unroll
                for (int t = 0; t < 2; ++t) {
                    h8 bh = *(const h8*)(SHB + shA(n * 16 + lr, t * 64 + lg * 16));
                    g[n] = __builtin_amdgcn_mfma_f32_16x16x32_f16(af[t], bh, g[n], 0, 0, 0);
                }
        }
        __syncthreads();   // (5) end of tile: B1/SHB/ACT* reused next tile
    }

    // ---- m_i: reduce mc over the 16 s-lanes, store (mc is raw m*e) ----
    #pragma unroll
    for (int j2 = 0; j2 < 4; ++j2) {
        float x = mc[j2];
        x += __shfl_xor(x, 1); x += __shfl_xor(x, 2);
        x += __shfl_xor(x, 4); x += __shfl_xor(x, 8);
        mc[j2] = x;
    }
    if (lr == 0) {
        float4 s;
        s.x = mc[0]; s.y = mc[1]; s.z = mc[2]; s.w = mc[3];
        *(float4*)(m_i + (size_t)bx * 128 + uW + lg * 4) = s;
    }

    // ---- G -> LDS f32, then fully-coalesced packed dword dump ----
    float* Gd = (float*)ldsb;   // 6144 f32 over B1+ACT0 (free now)
    #pragma unroll
    for (int n = 0; n < 3; ++n)
        #pragma unroll
        for (int j2 = 0; j2 < 4; ++j2)
            Gd[(uW + lg * 4 + j2) * 48 + n * 16 + lr] = g[n][j2];
    __syncthreads();
    unsigned* GB32 = (unsigned*)(GB + (size_t)bx * 6144);
    #pragma unroll
    for (int k2 = 0; k2 < 6; ++k2) {
        int i = k2 * 512 + tid;          // 3072 dwords
        int u = i / 24, c = (i - u * 24) * 2;
        GB32[i] = pk2(Gd[u * 48 + c], Gd[u * 48 + c + 1]);
    }
}

// ---------------- v_agg = wtp (x) G contraction, wtp LDS-resident ----------------
__global__ __launch_bounds__(256) void k_vagg(
    const unsigned short* __restrict__ GB, const unsigned short* __restrict__ wtpHl,
    float* __restrict__ v_agg)
{
    extern __shared__ char lds2[];
    unsigned short* WL = (unsigned short*)lds2;       // 32768 halves = 64 KB
    float* Gr  = (float*)(lds2 + 65536);              // 6144 f32 = 24 KB
    float* scr = (float*)(lds2 + 90112);              // 240 f32

    const int tid = (int)threadIdx.x;
    const int wg = (int)blockIdx.x;

    for (int i = tid; i < 4096; i += 256)
        ((short8v*)WL)[i] = ((const short8v*)wtpHl)[i];
    __syncthreads();

    const int vk = tid % 48, ug = tid / 48;
    const int vv = vk / 3, kk = vk - vv * 3;
    const int u0 = (ug * 128) / 5, u1 = ((ug + 1) * 128) / 5;

    for (int rr = 0; rr < 4; ++rr) {
        const int row = wg * 4 + rr;
        const unsigned* Gs32 = (const unsigned*)(GB + (size_t)row * 6144);
        for (int i = tid; i < 3072; i += 256) {
            unsigned d = Gs32[i];
            Gr[2 * i]     = h2f((unsigned short)(d & 0xFFFF));
            Gr[2 * i + 1] = h2f((unsigned short)(d >> 16));
        }
        __syncthreads();
        if (tid < 240) {
            float acc = 0.f;
            for (int u = u0; u < u1; ++u) {
                #pragma unroll
                for (int w = 0; w < 16; ++w)
                    acc = fmaf(h2f(WL[(u * 16 + w) * 16 + vv]), Gr[u * 48 + w * 3 + kk], acc);
            }
            scr[ug * 48 + vk] = acc;
        }
        __syncthreads();
        if (tid < 48) {
            float tot = scr[tid] + scr[48 + tid] + scr[96 + tid] + scr[144 + tid] + scr[192 + tid];
            v_agg[(size_t)row * 48 + tid] = tot * 1.1070164e-02f;  // 2^8/(sqrt(2048)*511)
        }
        __syncthreads();
    }
}

// ---------------- per-node update: ph MLP, residuals, f16 h mirror, next-layer pR ----------------
__global__ __launch_bounds__(128) void k_node_upd(
    const float* __restrict__ m_i, const float* __restrict__ v_agg,
    const float* __restrict__ wh1, const float* __restrict__ wh2,
    const float* __restrict__ wh_out, const float* __restrict__ we1n,
    float* __restrict__ h, unsigned short* __restrict__ hfm,
    float* __restrict__ v, float* __restrict__ pR)
{
    const int nx = (int)blockIdx.x;
    const int tid = (int)threadIdx.x;
    __shared__ float cat[192], t1[128], t2[128], hl2[64];
    if (tid < 128) cat[tid] = m_i[(size_t)nx * 128 + tid];
    if (tid < 64) cat[128 + tid] = h[(size_t)nx * 64 + tid];
    __syncthreads();
    {
        float acc = 0.f;
        for (int j = 0; j < 192; ++j) acc = fmaf(cat[j], wh1[j * 128 + tid], acc);
        t1[tid] = silu_fast(acc * 0.072168784f);
    }
    __syncthreads();
    {
        float acc = 0.f;
        for (int j = 0; j < 128; ++j) acc = fmaf(t1[j], wh2[j * 128 + tid], acc);
        t2[tid] = silu_fast(acc * 0.088388348f);
    }
    __syncthreads();
    if (tid < 64) {
        float acc = 0.f;
        for (int j = 0; j < 128; ++j) acc = fmaf(t2[j], wh_out[j * 64 + tid], acc);
        float hn = acc * 0.088388348f + cat[128 + tid];
        h[(size_t)nx * 64 + tid] = hn;
        hfm[(size_t)nx * 64 + tid] = f2h(hn);
        hl2[tid] = hn;
    }
    if (tid < 48) v[(size_t)nx * 48 + tid] += v_agg[(size_t)nx * 48 + tid];
    __syncthreads();
    // next layer's pR = h_new @ we1_next recv rows
    {
        float c = 0.f;
        for (int f = 0; f < 64; ++f)
            c = fmaf(hl2[f], we1n[(80 + f) * 128 + tid], c);
        pR[(size_t)nx * 128 + tid] = c;
    }
}

// ---------------- readout ----------------
__global__ __launch_bounds__(64) void k_readout(
    const float* __restrict__ v, const float* __restrict__ h,
    const float* __restrict__ vec_in, const float* __restrict__ wsM,
    const float* __restrict__ wvM, const float* __restrict__ w_out,
    const float* __restrict__ b_out, float* __restrict__ out)
{
    const int nx = (int)blockIdx.x;
    const int j = (int)threadIdx.x;
    __shared__ float sm[64];
    const float* hn = h + (size_t)nx * 64;
    float acc = 0.f;
    for (int f = 0; f < 64; ++f) acc = fmaf(hn[f], wsM[f * 64 + j], acc);
    acc *= 0.125f;
    float mx = acc;
    #pragma unroll
    for (int off = 32; off; off >>= 1) mx = fmaxf(mx, __shfl_xor(mx, off));
    float e = __expf(acc - mx);
    float ssum = e;
    #pragma unroll
    for (int off = 32; off; off >>= 1) ssum += __shfl_xor(ssum, off);
    sm[j] = e / ssum;
    __syncthreads();
    float o = b_out[j];
    for (int i = 0; i < 64; ++i) o = fmaf(sm[i], w_out[i * 64 + j], o);
    out[2 * 512 * 24 + (size_t)nx * 64 + j] = o;
    if (j < 24) {
        int w = j / 3, k = j - w * 3;
        float a2 = 0.f;
        #pragma unroll
        for (int c = 0; c < 16; ++c)
            a2 = fmaf(v[(size_t)nx * 48 + c * 3 + k], wvM[c * 8 + w], a2);
        out[(size_t)nx * 24 + j] = a2 * 0.25f - vec_in[(size_t)nx * 3 + k];
    }
}

// ---------------- launch ----------------
extern "C" void kernel_launch(void* const* d_in, const int* in_sizes, int n_in,
                              void* d_out, int out_size, void* d_ws, size_t ws_size,
                              hipStream_t stream)
{
    (void)in_sizes; (void)n_in; (void)out_size; (void)ws_size;
    const float* x      = (const float*)d_in[0];
    const float* we1    = (const float*)d_in[1];
    const float* we2    = (const float*)d_in[2];
    const float* wx1    = (const float*)d_in[3];
    const float* wx2    = (const float*)d_in[4];
    const float* winf   = (const float*)d_in[5];
    const float* wtp    = (const float*)d_in[6];
    const float* wh1    = (const float*)d_in[7];
    const float* wh2    = (const float*)d_in[8];
    const float* wh_out = (const float*)d_in[9];
    const float* wsM    = (const float*)d_in[10];
    const float* wvM    = (const float*)d_in[11];
    const float* w_out  = (const float*)d_in[12];
    const float* b_out  = (const float*)d_in[13];
    float* out = (float*)d_out;
    float* W = (float*)d_ws;

    float* VEC_IN = W;                                       // 3072 used
    float* V      = W + 4096;                                // 49152
    float* H      = W + 53248;                               // 65536
    float* PR     = W + 118784;                              // 131072
    float* MI     = W + 249856;                              // 131072
    float* VAGG   = W + 380928;                              // 49152
    unsigned short* GB    = (unsigned short*)(W + 430080);   // 6,291,456 halves (12 MB)
    unsigned short* HF16  = (unsigned short*)(W + 3575808);  // 65536 halves
    unsigned short* WT    = (unsigned short*)(W + 3608576);  // 147456 halves
    unsigned short* W1Tp  = (unsigned short*)(W + 3682304);  // 36864 halves
    unsigned short* WTPH  = (unsigned short*)(W + 3700736);  // 98304 halves
    unsigned short* WINFH = (unsigned short*)(W + 3749888);  // 384 halves

    hipFuncSetAttribute((const void*)k_edge,
                        hipFuncAttributeMaxDynamicSharedMemorySize, 51200);
    hipFuncSetAttribute((const void*)k_vagg,
                        hipFuncAttributeMaxDynamicSharedMemorySize, 91072);

    k_init<<<2, 256, 0, stream>>>(x, VEC_IN, V, H, HF16);
    k_prep<<<1170, 256, 0, stream>>>(we1, we2, wx1, wx2, wtp, winf,
                                     WT, W1Tp, WTPH, PR, WINFH);
    for (int l = 0; l < 3; ++l) {
        k_edge<<<1024, 512, 51200, stream>>>(V, PR, HF16,
            WT + l * 49152, W1Tp + l * 12288, WINFH + l * 128, MI, GB);
        k_vagg<<<256, 256, 91072, stream>>>(GB, WTPH + l * 32768, VAGG);
        k_node_upd<<<1024, 128, 0, stream>>>(MI, VAGG, wh1 + l * 24576,
            wh2 + l * 16384, wh_out + l * 8192, we1 + ((l + 1) % 3) * 18432,
            H, HF16, V, PR);
    }
    k_readout<<<1024, 64, 0, stream>>>(V, H, VEC_IN, wsM, wvM, w_out, b_out, out);
}